// Round 1
// baseline (3329.282 us; speedup 1.0000x reference)
//
#include <hip/hip_runtime.h>
#include <hip/hip_bf16.h>
#include <math.h>

#define DF 128
#define LEAKY(x) ((x) > 0.f ? (x) : 0.01f * (x))

__global__ void deg_count_k(const int* __restrict__ dst, int* __restrict__ cnt, int nE) {
  int e = blockIdx.x * 256 + threadIdx.x;
  if (e < nE) atomicAdd(&cnt[dst[e]], 1);
}

__global__ void make_dis_k(const int* __restrict__ cnt, float* __restrict__ dis, int n) {
  int i = blockIdx.x * 256 + threadIdx.x;
  if (i < n) dis[i] = 1.0f / sqrtf((float)cnt[i] + 1.0f);
}

// out[r][c] = sum_k A[r][k] * W[k][c], A: n x 128, W: 128 x 128
template<int ROWS>
__global__ void gemm_k(const float* __restrict__ A, const float* __restrict__ W,
                       float* __restrict__ out, int n) {
  __shared__ float Wl[64 * DF];          // 32 KB k-tile of W
  const int c  = threadIdx.x & (DF - 1);
  const int rh = threadIdx.x >> 7;       // 0/1
  const int r0 = blockIdx.x * ROWS;
  float acc[ROWS / 2];
#pragma unroll
  for (int i = 0; i < ROWS / 2; ++i) acc[i] = 0.f;
  for (int kt = 0; kt < 2; ++kt) {
    __syncthreads();
#pragma unroll 4
    for (int i = threadIdx.x; i < 64 * DF; i += 256) Wl[i] = W[kt * 64 * DF + i];
    __syncthreads();
#pragma unroll
    for (int rr = 0; rr < ROWS / 2; ++rr) {
      int r = r0 + rr * 2 + rh;
      if (r >= n) break;
      const float* a = A + (size_t)r * DF + kt * 64;
      float al = acc[rr];
#pragma unroll
      for (int k = 0; k < 64; ++k) al = fmaf(a[k], Wl[k * DF + c], al);
      acc[rr] = al;
    }
  }
#pragma unroll
  for (int rr = 0; rr < ROWS / 2; ++rr) {
    int r = r0 + rr * 2 + rh;
    if (r < n) out[(size_t)r * DF + c] = acc[rr];
  }
}

// agg[dst] += xw[src] * (dis[src]*dis[dst]); 32 threads (float4 each) per edge
__global__ void scatter_k(const float4* __restrict__ xw, const int* __restrict__ src,
                          const int* __restrict__ dst, const float* __restrict__ dis,
                          float* __restrict__ agg, int nE) {
  int gid = blockIdx.x * 256 + threadIdx.x;
  int e = gid >> 5;
  if (e >= nE) return;
  int part = gid & 31;
  int s = src[e], d = dst[e];
  float en = dis[s] * dis[d];
  float4 v = xw[(size_t)s * 32 + part];
  float* o = agg + (size_t)d * DF + part * 4;
  atomicAdd(o + 0, v.x * en);
  atomicAdd(o + 1, v.y * en);
  atomicAdd(o + 2, v.z * en);
  atomicAdd(o + 3, v.w * en);
}

// H = leaky(agg + xw*snorm + b)
__global__ void finish_k(const float4* __restrict__ agg, const float4* __restrict__ xw,
                         const float* __restrict__ dis, const float* __restrict__ b,
                         float4* __restrict__ H, int n) {
  int gid = blockIdx.x * 256 + threadIdx.x;
  if (gid >= n * 32) return;
  int nidx = gid >> 5, part = gid & 31;
  float sn = dis[nidx]; sn = sn * sn;
  float4 a = agg[gid], xv = xw[gid];
  float4 bb = ((const float4*)b)[part];
  float4 r;
  r.x = a.x + xv.x * sn + bb.x;
  r.y = a.y + xv.y * sn + bb.y;
  r.z = a.z + xv.z * sn + bb.z;
  r.w = a.w + xv.w * sn + bb.w;
  r.x = LEAKY(r.x); r.y = LEAKY(r.y); r.z = LEAKY(r.z); r.w = LEAKY(r.w);
  H[gid] = r;
}

// per-column sum and sumsq over n rows -> sums[0..127]=sum, sums[128..255]=sumsq
__global__ void bn_stats_k(const float* __restrict__ H, float* __restrict__ sums, int n) {
  int c = threadIdx.x & (DF - 1);
  int half = threadIdx.x >> 7;
  float s = 0.f, q = 0.f;
  for (int r = blockIdx.x * 2 + half; r < n; r += gridDim.x * 2) {
    float v = H[(size_t)r * DF + c];
    s += v; q += v * v;
  }
  __shared__ float ls[256], lq[256];
  ls[threadIdx.x] = s; lq[threadIdx.x] = q;
  __syncthreads();
  if (half == 0) {
    atomicAdd(&sums[c], ls[c] + ls[c + DF]);
    atomicAdd(&sums[DF + c], lq[c] + lq[c + DF]);
  }
}

__global__ void bn_final_k(const float* __restrict__ sums, const float* __restrict__ gamma,
                           const float* __restrict__ beta, float* __restrict__ ss, int n) {
  int c = threadIdx.x;  // 128 threads, 1 block
  float m = sums[c] / (float)n;
  float var = sums[DF + c] / (float)n - m * m;
  if (var < 0.f) var = 0.f;
  float sc = gamma[c] / sqrtf(var + 1e-5f);
  ss[c] = sc;
  ss[DF + c] = beta[c] - m * sc;
}

// psum[g] += H[idx[i]]; pcnt[g] += 1
__global__ void pool_k(const float4* __restrict__ H, const int* __restrict__ idx,
                       const int* __restrict__ batch, float* __restrict__ psum,
                       int* __restrict__ pcnt, int ni) {
  int gid = blockIdx.x * 256 + threadIdx.x;
  if (gid >= ni * 32) return;
  int i = gid >> 5, part = gid & 31;
  int nd = idx[i];
  int g = batch[nd];
  float4 v = H[(size_t)nd * 32 + part];
  float* o = psum + (size_t)g * DF + part * 4;
  atomicAdd(o + 0, v.x);
  atomicAdd(o + 1, v.y);
  atomicAdd(o + 2, v.z);
  atomicAdd(o + 3, v.w);
  if (part == 0) atomicAdd(&pcnt[g], 1);
}

// per-graph: build comb[512], two MLP layers -> hbuf[g][128]
__global__ void head1_k(const float* __restrict__ psum, const int* __restrict__ pcnt,
                        const float* __restrict__ isum, const int* __restrict__ icnt,
                        const float* __restrict__ ss,
                        const float* __restrict__ gf_w1, const float* __restrict__ gf_b1,
                        const float* __restrict__ gf_w2, const float* __restrict__ gf_b2,
                        float* __restrict__ hbuf) {
  int g = blockIdx.x, j = threadIdx.x;  // 128 threads
  __shared__ float comb[4 * DF];
  __shared__ float t1[DF];
  int pc = pcnt[g], ic = icnt[g];
  float sc = ss[j], sh = ss[DF + j];
  float pf = pc > 0 ? (psum[(size_t)g * DF + j] / (float)pc) * sc + sh : 0.f;
  float im = ic > 0 ? (isum[(size_t)g * DF + j] / (float)ic) * sc + sh : 0.f;
  comb[j] = pf;
  comb[DF + j] = im;
  comb[2 * DF + j] = pf - im;
  comb[3 * DF + j] = pf * im;
  __syncthreads();
  float acc = gf_b1[j];
#pragma unroll 4
  for (int k = 0; k < 4 * DF; ++k) acc = fmaf(comb[k], gf_w1[(size_t)k * DF + j], acc);
  t1[j] = LEAKY(acc);
  __syncthreads();
  acc = gf_b2[j];
#pragma unroll 4
  for (int k = 0; k < DF; ++k) acc = fmaf(t1[k], gf_w2[(size_t)k * DF + j], acc);
  hbuf[(size_t)g * DF + j] = acc;
}

// BN2 over G rows of hbuf -> scale2/shift2 (single block, 128 threads)
__global__ void bn2_k(const float* __restrict__ hbuf, const float* __restrict__ gamma,
                      const float* __restrict__ beta, float* __restrict__ ss2, int G) {
  int c = threadIdx.x;
  float s = 0.f, q = 0.f;
  for (int r = 0; r < G; ++r) {
    float v = hbuf[(size_t)r * DF + c];
    s += v; q += v * v;
  }
  float m = s / (float)G;
  float var = q / (float)G - m * m;
  if (var < 0.f) var = 0.f;
  float sc = gamma[c] / sqrtf(var + 1e-5f);
  ss2[c] = sc;
  ss2[DF + c] = beta[c] - m * sc;
}

// per-graph: BN2-apply, 128->64 leaky, 64->32, 32->2; write out + prob
__global__ void head2_k(const float* __restrict__ hbuf, const float* __restrict__ ss2,
                        const float* __restrict__ fl_w1, const float* __restrict__ fl_b1,
                        const float* __restrict__ fl_w2, const float* __restrict__ fl_b2,
                        const float* __restrict__ out_w, const float* __restrict__ out_b,
                        float* __restrict__ d_out, int G) {
  int g = blockIdx.x, t = threadIdx.x;  // 128 threads
  __shared__ float hb[DF], t1[64], ov[32];
  hb[t] = hbuf[(size_t)g * DF + t] * ss2[t] + ss2[DF + t];
  __syncthreads();
  if (t < 64) {
    float acc = fl_b1[t];
#pragma unroll 4
    for (int c = 0; c < DF; ++c) acc = fmaf(hb[c], fl_w1[(size_t)c * 64 + t], acc);
    t1[t] = LEAKY(acc);
  }
  __syncthreads();
  if (t < 32) {
    float acc = fl_b2[t];
#pragma unroll 4
    for (int j = 0; j < 64; ++j) acc = fmaf(t1[j], fl_w2[(size_t)j * 32 + t], acc);
    d_out[(size_t)g * 32 + t] = acc;
    ov[t] = acc;
  }
  __syncthreads();
  if (t < 2) {
    float acc = out_b[t];
#pragma unroll
    for (int o = 0; o < 32; ++o) acc = fmaf(ov[o], out_w[(size_t)o * 2 + t], acc);
    d_out[(size_t)G * 32 + (size_t)g * 2 + t] = acc;
  }
}

extern "C" void kernel_launch(void* const* d_in, const int* in_sizes, int n_in,
                              void* d_out, int out_size, void* d_ws, size_t ws_size,
                              hipStream_t stream) {
  const float* x         = (const float*)d_in[0];
  const float* W_gnn     = (const float*)d_in[1];
  const float* b_gnn     = (const float*)d_in[2];
  const float* hbn_gamma = (const float*)d_in[3];
  const float* hbn_beta  = (const float*)d_in[4];
  const float* gf_w1     = (const float*)d_in[5];
  const float* gf_b1     = (const float*)d_in[6];
  const float* gf_w2     = (const float*)d_in[7];
  const float* gf_b2     = (const float*)d_in[8];
  const float* bn2_gamma = (const float*)d_in[9];
  const float* bn2_beta  = (const float*)d_in[10];
  const float* fl_w1     = (const float*)d_in[11];
  const float* fl_b1     = (const float*)d_in[12];
  const float* fl_w2     = (const float*)d_in[13];
  const float* fl_b2     = (const float*)d_in[14];
  const float* out_w     = (const float*)d_in[15];
  const float* out_b     = (const float*)d_in[16];
  const int* edge_index  = (const int*)d_in[17];
  const int* post_idx    = (const int*)d_in[18];
  const int* image_idx   = (const int*)d_in[19];
  const int* batch_vec   = (const int*)d_in[20];

  const int N  = in_sizes[20];
  const int E  = in_sizes[17] / 2;
  const int NP = in_sizes[18];
  const int NI = in_sizes[19];
  const int G  = out_size / 34;           // out: G*32 + prob: G*2
  const int L  = in_sizes[1] / (DF * DF);
  const int* src  = edge_index;
  const int* dstp = edge_index + E;

  char* ws = (char*)d_ws;
  size_t off = 0;
  auto alloc = [&](size_t b) { size_t o = off; off += (b + 255) & ~(size_t)255; return o; };
  float* dis  = (float*)(ws + alloc((size_t)N * 4));
  int*   degc = (int*)(ws + alloc((size_t)N * 4));
  float* xw   = (float*)(ws + alloc((size_t)N * DF * 4));
  float* agg  = (float*)(ws + alloc((size_t)N * DF * 4));
  float* H    = (float*)(ws + alloc((size_t)N * DF * 4));
  float* bns  = (float*)(ws + alloc(256 * 4));
  float* ss   = (float*)(ws + alloc(256 * 4));
  float* psum = (float*)(ws + alloc((size_t)G * DF * 4));
  float* isum = (float*)(ws + alloc((size_t)G * DF * 4));
  int*   pcnt = (int*)(ws + alloc((size_t)G * 4));
  int*   icnt = (int*)(ws + alloc((size_t)G * 4));
  float* hbuf = (float*)(ws + alloc((size_t)G * DF * 4));
  float* ss2  = (float*)(ws + alloc(256 * 4));

  // degree + dis
  hipMemsetAsync(degc, 0, (size_t)N * 4, stream);
  deg_count_k<<<(E + 255) / 256, 256, 0, stream>>>(dstp, degc, E);
  make_dis_k<<<(N + 255) / 256, 256, 0, stream>>>(degc, dis, N);

  // GNN layers
  const float* Hin = x;
  for (int l = 0; l < L; ++l) {
    gemm_k<16><<<(N + 15) / 16, 256, 0, stream>>>(Hin, W_gnn + (size_t)l * DF * DF, xw, N);
    hipMemsetAsync(agg, 0, (size_t)N * DF * 4, stream);
    scatter_k<<<(E * 32 + 255) / 256, 256, 0, stream>>>((const float4*)xw, src, dstp, dis, agg, E);
    finish_k<<<(N * 32 + 255) / 256, 256, 0, stream>>>((const float4*)agg, (const float4*)xw,
                                                       dis, b_gnn + (size_t)l * DF, (float4*)H, N);
    Hin = H;
  }

  // BN over H (fold into affine scale/shift)
  hipMemsetAsync(bns, 0, 256 * 4, stream);
  bn_stats_k<<<256, 256, 0, stream>>>(H, bns, N);
  bn_final_k<<<1, 128, 0, stream>>>(bns, hbn_gamma, hbn_beta, ss, N);

  // pooled sums
  hipMemsetAsync(psum, 0, (size_t)G * DF * 4, stream);
  hipMemsetAsync(isum, 0, (size_t)G * DF * 4, stream);
  hipMemsetAsync(pcnt, 0, (size_t)G * 4, stream);
  hipMemsetAsync(icnt, 0, (size_t)G * 4, stream);
  pool_k<<<(NP * 32 + 255) / 256, 256, 0, stream>>>((const float4*)H, post_idx, batch_vec, psum, pcnt, NP);
  pool_k<<<(NI * 32 + 255) / 256, 256, 0, stream>>>((const float4*)H, image_idx, batch_vec, isum, icnt, NI);

  // head
  head1_k<<<G, 128, 0, stream>>>(psum, pcnt, isum, icnt, ss, gf_w1, gf_b1, gf_w2, gf_b2, hbuf);
  bn2_k<<<1, 128, 0, stream>>>(hbuf, bn2_gamma, bn2_beta, ss2, G);
  head2_k<<<G, 128, 0, stream>>>(hbuf, ss2, fl_w1, fl_b1, fl_w2, fl_b2, out_w, out_b,
                                 (float*)d_out, G);
}

// Round 2
// 903.203 us; speedup vs baseline: 3.6861x; 3.6861x over previous
//
#include <hip/hip_runtime.h>
#include <hip/hip_bf16.h>
#include <math.h>

#define DF 128
#define LEAKY(x) ((x) > 0.f ? (x) : 0.01f * (x))

__global__ void deg_count_k(const int* __restrict__ dst, int* __restrict__ cnt, int nE) {
  int e = blockIdx.x * 256 + threadIdx.x;
  if (e < nE) atomicAdd(&cnt[dst[e]], 1);
}

__global__ void make_dis_k(const int* __restrict__ cnt, float* __restrict__ dis, int n) {
  int i = blockIdx.x * 256 + threadIdx.x;
  if (i < n) dis[i] = 1.0f / sqrtf((float)cnt[i] + 1.0f);
}

// single-block exclusive scan of cnt[0..n) -> rowoff[0..n], cursor copy
__global__ void scan_k(const int* __restrict__ cnt, int* __restrict__ rowoff,
                       int* __restrict__ cursor, int n) {
  const int T = 1024;
  __shared__ int buf[T];
  int chunk = (n + T - 1) / T;
  int beg = threadIdx.x * chunk;
  int end = beg + chunk; if (end > n) end = n;
  int s = 0;
  for (int i = beg; i < end; ++i) s += cnt[i];
  buf[threadIdx.x] = s;
  __syncthreads();
  for (int ofs = 1; ofs < T; ofs <<= 1) {
    int t = (threadIdx.x >= (unsigned)ofs) ? buf[threadIdx.x - ofs] : 0;
    __syncthreads();
    buf[threadIdx.x] += t;
    __syncthreads();
  }
  int run = buf[threadIdx.x] - s;  // exclusive prefix of this thread's chunk
  for (int i = beg; i < end; ++i) {
    rowoff[i] = run; cursor[i] = run;
    run += cnt[i];
  }
  if (threadIdx.x == T - 1) rowoff[n] = run;
}

__global__ void csr_fill_k(const int* __restrict__ src, const int* __restrict__ dst,
                           int* __restrict__ cursor, int* __restrict__ eidx, int nE) {
  int e = blockIdx.x * 256 + threadIdx.x;
  if (e < nE) {
    int p = atomicAdd(&cursor[dst[e]], 1);
    eidx[p] = src[e];
  }
}

// out[r][c] = sum_k A[r][k] * W[k][c], A: n x 128, W: 128 x 128
template<int ROWS>
__global__ void gemm_k(const float* __restrict__ A, const float* __restrict__ W,
                       float* __restrict__ out, int n) {
  __shared__ float Wl[64 * DF];          // 32 KB k-tile of W
  const int c  = threadIdx.x & (DF - 1);
  const int rh = threadIdx.x >> 7;       // 0/1
  const int r0 = blockIdx.x * ROWS;
  float acc[ROWS / 2];
#pragma unroll
  for (int i = 0; i < ROWS / 2; ++i) acc[i] = 0.f;
  for (int kt = 0; kt < 2; ++kt) {
    __syncthreads();
#pragma unroll 4
    for (int i = threadIdx.x; i < 64 * DF; i += 256) Wl[i] = W[kt * 64 * DF + i];
    __syncthreads();
#pragma unroll
    for (int rr = 0; rr < ROWS / 2; ++rr) {
      int r = r0 + rr * 2 + rh;
      if (r >= n) break;
      const float* a = A + (size_t)r * DF + kt * 64;
      float al = acc[rr];
#pragma unroll
      for (int k = 0; k < 64; ++k) al = fmaf(a[k], Wl[k * DF + c], al);
      acc[rr] = al;
    }
  }
#pragma unroll
  for (int rr = 0; rr < ROWS / 2; ++rr) {
    int r = r0 + rr * 2 + rh;
    if (r < n) out[(size_t)r * DF + c] = acc[rr];
  }
}

// CSR gather + self-loop + bias + leaky, fused. 32 threads (one float4 lane) per node.
__global__ void gather_k(const float4* __restrict__ xw, const int* __restrict__ rowoff,
                         const int* __restrict__ eidx, const float* __restrict__ dis,
                         const float* __restrict__ b, float4* __restrict__ H, int n) {
  int gid = blockIdx.x * 256 + threadIdx.x;
  int node = gid >> 5;
  if (node >= n) return;
  int part = gid & 31;
  int beg = rowoff[node], end = rowoff[node + 1];
  float dd = dis[node];
  float4 acc = make_float4(0.f, 0.f, 0.f, 0.f);
  for (int p = beg; p < end; ++p) {
    int s = eidx[p];
    float en = dis[s] * dd;
    float4 v = xw[(size_t)s * 32 + part];
    acc.x = fmaf(v.x, en, acc.x);
    acc.y = fmaf(v.y, en, acc.y);
    acc.z = fmaf(v.z, en, acc.z);
    acc.w = fmaf(v.w, en, acc.w);
  }
  float sn = dd * dd;
  float4 xv = xw[(size_t)node * 32 + part];
  float4 bb = ((const float4*)b)[part];
  float4 r;
  r.x = fmaf(xv.x, sn, acc.x) + bb.x;
  r.y = fmaf(xv.y, sn, acc.y) + bb.y;
  r.z = fmaf(xv.z, sn, acc.z) + bb.z;
  r.w = fmaf(xv.w, sn, acc.w) + bb.w;
  r.x = LEAKY(r.x); r.y = LEAKY(r.y); r.z = LEAKY(r.z); r.w = LEAKY(r.w);
  H[gid] = r;
}

// per-column sum and sumsq over n rows -> sums[0..127]=sum, sums[128..255]=sumsq
__global__ void bn_stats_k(const float* __restrict__ H, float* __restrict__ sums, int n) {
  int c = threadIdx.x & (DF - 1);
  int half = threadIdx.x >> 7;
  float s = 0.f, q = 0.f;
  for (int r = blockIdx.x * 2 + half; r < n; r += gridDim.x * 2) {
    float v = H[(size_t)r * DF + c];
    s += v; q += v * v;
  }
  __shared__ float ls[256], lq[256];
  ls[threadIdx.x] = s; lq[threadIdx.x] = q;
  __syncthreads();
  if (half == 0) {
    atomicAdd(&sums[c], ls[c] + ls[c + DF]);
    atomicAdd(&sums[DF + c], lq[c] + lq[c + DF]);
  }
}

__global__ void bn_final_k(const float* __restrict__ sums, const float* __restrict__ gamma,
                           const float* __restrict__ beta, float* __restrict__ ss, int n) {
  int c = threadIdx.x;  // 128 threads, 1 block
  float m = sums[c] / (float)n;
  float var = sums[DF + c] / (float)n - m * m;
  if (var < 0.f) var = 0.f;
  float sc = gamma[c] / sqrtf(var + 1e-5f);
  ss[c] = sc;
  ss[DF + c] = beta[c] - m * sc;
}

// psum[g] += H[idx[i]]; pcnt[g] += 1
__global__ void pool_k(const float4* __restrict__ H, const int* __restrict__ idx,
                       const int* __restrict__ batch, float* __restrict__ psum,
                       int* __restrict__ pcnt, int ni) {
  int gid = blockIdx.x * 256 + threadIdx.x;
  if (gid >= ni * 32) return;
  int i = gid >> 5, part = gid & 31;
  int nd = idx[i];
  int g = batch[nd];
  float4 v = H[(size_t)nd * 32 + part];
  float* o = psum + (size_t)g * DF + part * 4;
  atomicAdd(o + 0, v.x);
  atomicAdd(o + 1, v.y);
  atomicAdd(o + 2, v.z);
  atomicAdd(o + 3, v.w);
  if (part == 0) atomicAdd(&pcnt[g], 1);
}

// per-graph: build comb[512], two MLP layers -> hbuf[g][128]
__global__ void head1_k(const float* __restrict__ psum, const int* __restrict__ pcnt,
                        const float* __restrict__ isum, const int* __restrict__ icnt,
                        const float* __restrict__ ss,
                        const float* __restrict__ gf_w1, const float* __restrict__ gf_b1,
                        const float* __restrict__ gf_w2, const float* __restrict__ gf_b2,
                        float* __restrict__ hbuf) {
  int g = blockIdx.x, j = threadIdx.x;  // 128 threads
  __shared__ float comb[4 * DF];
  __shared__ float t1[DF];
  int pc = pcnt[g], ic = icnt[g];
  float sc = ss[j], sh = ss[DF + j];
  float pf = pc > 0 ? (psum[(size_t)g * DF + j] / (float)pc) * sc + sh : 0.f;
  float im = ic > 0 ? (isum[(size_t)g * DF + j] / (float)ic) * sc + sh : 0.f;
  comb[j] = pf;
  comb[DF + j] = im;
  comb[2 * DF + j] = pf - im;
  comb[3 * DF + j] = pf * im;
  __syncthreads();
  float acc = gf_b1[j];
#pragma unroll 4
  for (int k = 0; k < 4 * DF; ++k) acc = fmaf(comb[k], gf_w1[(size_t)k * DF + j], acc);
  t1[j] = LEAKY(acc);
  __syncthreads();
  acc = gf_b2[j];
#pragma unroll 4
  for (int k = 0; k < DF; ++k) acc = fmaf(t1[k], gf_w2[(size_t)k * DF + j], acc);
  hbuf[(size_t)g * DF + j] = acc;
}

// BN2 over G rows of hbuf -> scale2/shift2 (single block, 128 threads)
__global__ void bn2_k(const float* __restrict__ hbuf, const float* __restrict__ gamma,
                      const float* __restrict__ beta, float* __restrict__ ss2, int G) {
  int c = threadIdx.x;
  float s = 0.f, q = 0.f;
  for (int r = 0; r < G; ++r) {
    float v = hbuf[(size_t)r * DF + c];
    s += v; q += v * v;
  }
  float m = s / (float)G;
  float var = q / (float)G - m * m;
  if (var < 0.f) var = 0.f;
  float sc = gamma[c] / sqrtf(var + 1e-5f);
  ss2[c] = sc;
  ss2[DF + c] = beta[c] - m * sc;
}

// per-graph: BN2-apply, 128->64 leaky, 64->32, 32->2; write out + prob
__global__ void head2_k(const float* __restrict__ hbuf, const float* __restrict__ ss2,
                        const float* __restrict__ fl_w1, const float* __restrict__ fl_b1,
                        const float* __restrict__ fl_w2, const float* __restrict__ fl_b2,
                        const float* __restrict__ out_w, const float* __restrict__ out_b,
                        float* __restrict__ d_out, int G) {
  int g = blockIdx.x, t = threadIdx.x;  // 128 threads
  __shared__ float hb[DF], t1[64], ov[32];
  hb[t] = hbuf[(size_t)g * DF + t] * ss2[t] + ss2[DF + t];
  __syncthreads();
  if (t < 64) {
    float acc = fl_b1[t];
#pragma unroll 4
    for (int c = 0; c < DF; ++c) acc = fmaf(hb[c], fl_w1[(size_t)c * 64 + t], acc);
    t1[t] = LEAKY(acc);
  }
  __syncthreads();
  if (t < 32) {
    float acc = fl_b2[t];
#pragma unroll 4
    for (int j = 0; j < 64; ++j) acc = fmaf(t1[j], fl_w2[(size_t)j * 32 + t], acc);
    d_out[(size_t)g * 32 + t] = acc;
    ov[t] = acc;
  }
  __syncthreads();
  if (t < 2) {
    float acc = out_b[t];
#pragma unroll
    for (int o = 0; o < 32; ++o) acc = fmaf(ov[o], out_w[(size_t)o * 2 + t], acc);
    d_out[(size_t)G * 32 + (size_t)g * 2 + t] = acc;
  }
}

extern "C" void kernel_launch(void* const* d_in, const int* in_sizes, int n_in,
                              void* d_out, int out_size, void* d_ws, size_t ws_size,
                              hipStream_t stream) {
  const float* x         = (const float*)d_in[0];
  const float* W_gnn     = (const float*)d_in[1];
  const float* b_gnn     = (const float*)d_in[2];
  const float* hbn_gamma = (const float*)d_in[3];
  const float* hbn_beta  = (const float*)d_in[4];
  const float* gf_w1     = (const float*)d_in[5];
  const float* gf_b1     = (const float*)d_in[6];
  const float* gf_w2     = (const float*)d_in[7];
  const float* gf_b2     = (const float*)d_in[8];
  const float* bn2_gamma = (const float*)d_in[9];
  const float* bn2_beta  = (const float*)d_in[10];
  const float* fl_w1     = (const float*)d_in[11];
  const float* fl_b1     = (const float*)d_in[12];
  const float* fl_w2     = (const float*)d_in[13];
  const float* fl_b2     = (const float*)d_in[14];
  const float* out_w     = (const float*)d_in[15];
  const float* out_b     = (const float*)d_in[16];
  const int* edge_index  = (const int*)d_in[17];
  const int* post_idx    = (const int*)d_in[18];
  const int* image_idx   = (const int*)d_in[19];
  const int* batch_vec   = (const int*)d_in[20];

  const int N  = in_sizes[20];
  const int E  = in_sizes[17] / 2;
  const int NP = in_sizes[18];
  const int NI = in_sizes[19];
  const int G  = out_size / 34;           // out: G*32 + prob: G*2
  const int L  = in_sizes[1] / (DF * DF);
  const int* src  = edge_index;
  const int* dstp = edge_index + E;

  char* ws = (char*)d_ws;
  size_t off = 0;
  auto alloc = [&](size_t b) { size_t o = off; off += (b + 255) & ~(size_t)255; return o; };
  float* dis    = (float*)(ws + alloc((size_t)N * 4));
  int*   degc   = (int*)(ws + alloc((size_t)N * 4));
  int*   rowoff = (int*)(ws + alloc((size_t)(N + 1) * 4));
  int*   cursor = (int*)(ws + alloc((size_t)N * 4));
  int*   eidx   = (int*)(ws + alloc((size_t)E * 4));
  float* xw     = (float*)(ws + alloc((size_t)N * DF * 4));
  float* H      = (float*)(ws + alloc((size_t)N * DF * 4));
  float* bns    = (float*)(ws + alloc(256 * 4));
  float* ss     = (float*)(ws + alloc(256 * 4));
  float* psum   = (float*)(ws + alloc((size_t)G * DF * 4));
  float* isum   = (float*)(ws + alloc((size_t)G * DF * 4));
  int*   pcnt   = (int*)(ws + alloc((size_t)G * 4));
  int*   icnt   = (int*)(ws + alloc((size_t)G * 4));
  float* hbuf   = (float*)(ws + alloc((size_t)G * DF * 4));
  float* ss2    = (float*)(ws + alloc(256 * 4));

  // degree + dis + CSR build (reused across both layers)
  hipMemsetAsync(degc, 0, (size_t)N * 4, stream);
  deg_count_k<<<(E + 255) / 256, 256, 0, stream>>>(dstp, degc, E);
  make_dis_k<<<(N + 255) / 256, 256, 0, stream>>>(degc, dis, N);
  scan_k<<<1, 1024, 0, stream>>>(degc, rowoff, cursor, N);
  csr_fill_k<<<(E + 255) / 256, 256, 0, stream>>>(src, dstp, cursor, eidx, E);

  // GNN layers
  const float* Hin = x;
  for (int l = 0; l < L; ++l) {
    gemm_k<16><<<(N + 15) / 16, 256, 0, stream>>>(Hin, W_gnn + (size_t)l * DF * DF, xw, N);
    gather_k<<<(N * 32 + 255) / 256, 256, 0, stream>>>((const float4*)xw, rowoff, eidx, dis,
                                                       b_gnn + (size_t)l * DF, (float4*)H, N);
    Hin = H;
  }

  // BN over H (fold into affine scale/shift)
  hipMemsetAsync(bns, 0, 256 * 4, stream);
  bn_stats_k<<<256, 256, 0, stream>>>(H, bns, N);
  bn_final_k<<<1, 128, 0, stream>>>(bns, hbn_gamma, hbn_beta, ss, N);

  // pooled sums
  hipMemsetAsync(psum, 0, (size_t)G * DF * 4, stream);
  hipMemsetAsync(isum, 0, (size_t)G * DF * 4, stream);
  hipMemsetAsync(pcnt, 0, (size_t)G * 4, stream);
  hipMemsetAsync(icnt, 0, (size_t)G * 4, stream);
  pool_k<<<(NP * 32 + 255) / 256, 256, 0, stream>>>((const float4*)H, post_idx, batch_vec, psum, pcnt, NP);
  pool_k<<<(NI * 32 + 255) / 256, 256, 0, stream>>>((const float4*)H, image_idx, batch_vec, isum, icnt, NI);

  // head
  head1_k<<<G, 128, 0, stream>>>(psum, pcnt, isum, icnt, ss, gf_w1, gf_b1, gf_w2, gf_b2, hbuf);
  bn2_k<<<1, 128, 0, stream>>>(hbuf, bn2_gamma, bn2_beta, ss2, G);
  head2_k<<<G, 128, 0, stream>>>(hbuf, ss2, fl_w1, fl_b1, fl_w2, fl_b2, out_w, out_b,
                                 (float*)d_out, G);
}

// Round 3
// 695.952 us; speedup vs baseline: 4.7838x; 1.2978x over previous
//
#include <hip/hip_runtime.h>
#include <hip/hip_bf16.h>
#include <math.h>

#define DF 128
#define LEAKY(x) ((x) > 0.f ? (x) : 0.01f * (x))

typedef __attribute__((ext_vector_type(8))) short short8v;   // 8 bf16 in 4 VGPRs
typedef __attribute__((ext_vector_type(4))) float f32x4;
typedef __attribute__((ext_vector_type(4))) unsigned short u16x4;

static __device__ __forceinline__ unsigned short f2bf(float f) {
  unsigned u = __float_as_uint(f);
  unsigned r = u + 0x7fffu + ((u >> 16) & 1u);   // RNE
  return (unsigned short)(r >> 16);
}
static __device__ __forceinline__ float bf2f(unsigned short b) {
  return __uint_as_float(((unsigned)b) << 16);
}

__global__ void deg_count_k(const int* __restrict__ dst, int* __restrict__ cnt, int nE) {
  int e = blockIdx.x * 256 + threadIdx.x;
  if (e < nE) atomicAdd(&cnt[dst[e]], 1);
}

__global__ void make_dis_k(const int* __restrict__ cnt, float* __restrict__ dis, int n) {
  int i = blockIdx.x * 256 + threadIdx.x;
  if (i < n) dis[i] = 1.0f / sqrtf((float)cnt[i] + 1.0f);
}

// single-block exclusive scan of cnt[0..n) -> rowoff[0..n], cursor copy
__global__ void scan_k(const int* __restrict__ cnt, int* __restrict__ rowoff,
                       int* __restrict__ cursor, int n) {
  const int T = 1024;
  __shared__ int buf[T];
  int chunk = (n + T - 1) / T;
  int beg = threadIdx.x * chunk;
  int end = beg + chunk; if (end > n) end = n;
  int s = 0;
  for (int i = beg; i < end; ++i) s += cnt[i];
  buf[threadIdx.x] = s;
  __syncthreads();
  for (int ofs = 1; ofs < T; ofs <<= 1) {
    int t = (threadIdx.x >= (unsigned)ofs) ? buf[threadIdx.x - ofs] : 0;
    __syncthreads();
    buf[threadIdx.x] += t;
    __syncthreads();
  }
  int run = buf[threadIdx.x] - s;  // exclusive prefix of this thread's chunk
  for (int i = beg; i < end; ++i) {
    rowoff[i] = run; cursor[i] = run;
    run += cnt[i];
  }
  if (threadIdx.x == T - 1) rowoff[n] = run;
}

__global__ void csr_fill_k(const int* __restrict__ src, const int* __restrict__ dst,
                           int* __restrict__ cursor, int* __restrict__ eidx, int nE) {
  int e = blockIdx.x * 256 + threadIdx.x;
  if (e < nE) {
    int p = atomicAdd(&cursor[dst[e]], 1);
    eidx[p] = src[e];
  }
}

__global__ void castW_k(const float* __restrict__ W, unsigned short* __restrict__ Wb, int n) {
  int i = blockIdx.x * 256 + threadIdx.x;
  if (i < n) Wb[i] = f2bf(W[i]);
}

// xwb[r][c] = bf16( sum_k A[r][k] * Wb[k][c] ), A: n x 128 f32, Wb: 128 x 128 bf16.
// Block: 256 thr = 4 waves; tile 32 rows x 128 cols; wave (wr=w&1, wc=w>>1):
// rows r0+wr*16..+15, cols wc*64..+63. MFMA 16x16x32 bf16, K=128 in 4 steps.
__global__ void __launch_bounds__(256) gemm_mfma_k(const float* __restrict__ A,
                                                   const unsigned short* __restrict__ Wb,
                                                   unsigned short* __restrict__ xwb, int n) {
  const int w = threadIdx.x >> 6, l = threadIdx.x & 63;
  const int wr = w & 1, wc = w >> 1;
  const int r0 = blockIdx.x * 32 + wr * 16;
  const int row = r0 + (l & 15);
  const int kg = l >> 4;                 // 0..3
  // preload all B fragments (W is tiny, L1/L2-hot): bf[ct][ks]
  short8v bf[4][4];
#pragma unroll
  for (int ct = 0; ct < 4; ++ct) {
    int c = wc * 64 + ct * 16 + (l & 15);
#pragma unroll
    for (int ks = 0; ks < 4; ++ks) {
      int kb = ks * 32 + kg * 8;
      short8v t;
#pragma unroll
      for (int j = 0; j < 8; ++j) t[j] = (short)Wb[(size_t)(kb + j) * DF + c];
      bf[ct][ks] = t;
    }
  }
  f32x4 acc[4];
#pragma unroll
  for (int ct = 0; ct < 4; ++ct) acc[ct] = (f32x4)(0.f);
  const bool rok = row < n;
  const float* ap = A + (size_t)row * DF + kg * 8;
#pragma unroll
  for (int ks = 0; ks < 4; ++ks) {
    short8v af;
    if (rok) {
      float4 lo = *(const float4*)(ap + ks * 32);
      float4 hi = *(const float4*)(ap + ks * 32 + 4);
      af[0] = (short)f2bf(lo.x); af[1] = (short)f2bf(lo.y);
      af[2] = (short)f2bf(lo.z); af[3] = (short)f2bf(lo.w);
      af[4] = (short)f2bf(hi.x); af[5] = (short)f2bf(hi.y);
      af[6] = (short)f2bf(hi.z); af[7] = (short)f2bf(hi.w);
    } else {
      af = (short8v)0;
    }
#pragma unroll
    for (int ct = 0; ct < 4; ++ct)
      acc[ct] = __builtin_amdgcn_mfma_f32_16x16x32_bf16(af, bf[ct][ks], acc[ct], 0, 0, 0);
  }
  // C/D layout: col = lane&15 (within ct tile), row = r0 + kg*4 + reg
#pragma unroll
  for (int ct = 0; ct < 4; ++ct) {
    int c = wc * 64 + ct * 16 + (l & 15);
#pragma unroll
    for (int rg = 0; rg < 4; ++rg) {
      int r = r0 + kg * 4 + rg;
      if (r < n) xwb[(size_t)r * DF + c] = f2bf(acc[ct][rg]);
    }
  }
}

// CSR gather + self-loop + bias + leaky, fused. 32 threads (4 bf16 each) per node.
__global__ void gather_k(const unsigned short* __restrict__ xwb, const int* __restrict__ rowoff,
                         const int* __restrict__ eidx, const float* __restrict__ dis,
                         const float* __restrict__ b, float4* __restrict__ H, int n) {
  int gid = blockIdx.x * 256 + threadIdx.x;
  int node = gid >> 5;
  if (node >= n) return;
  int part = gid & 31;
  int beg = rowoff[node], end = rowoff[node + 1];
  float dd = dis[node];
  float4 acc = make_float4(0.f, 0.f, 0.f, 0.f);
  for (int p = beg; p < end; ++p) {
    int s = eidx[p];
    float en = dis[s] * dd;
    u16x4 v = *(const u16x4*)(xwb + (size_t)s * DF + part * 4);
    acc.x = fmaf(bf2f(v[0]), en, acc.x);
    acc.y = fmaf(bf2f(v[1]), en, acc.y);
    acc.z = fmaf(bf2f(v[2]), en, acc.z);
    acc.w = fmaf(bf2f(v[3]), en, acc.w);
  }
  float sn = dd * dd;
  u16x4 xv = *(const u16x4*)(xwb + (size_t)node * DF + part * 4);
  float4 bb = ((const float4*)b)[part];
  float4 r;
  r.x = fmaf(bf2f(xv[0]), sn, acc.x) + bb.x;
  r.y = fmaf(bf2f(xv[1]), sn, acc.y) + bb.y;
  r.z = fmaf(bf2f(xv[2]), sn, acc.z) + bb.z;
  r.w = fmaf(bf2f(xv[3]), sn, acc.w) + bb.w;
  r.x = LEAKY(r.x); r.y = LEAKY(r.y); r.z = LEAKY(r.z); r.w = LEAKY(r.w);
  H[gid] = r;
}

// per-column sum and sumsq over n rows -> sums[0..127]=sum, sums[128..255]=sumsq
__global__ void bn_stats_k(const float* __restrict__ H, float* __restrict__ sums, int n) {
  int c = threadIdx.x & (DF - 1);
  int half = threadIdx.x >> 7;
  float s = 0.f, q = 0.f;
  for (int r = blockIdx.x * 2 + half; r < n; r += gridDim.x * 2) {
    float v = H[(size_t)r * DF + c];
    s += v; q += v * v;
  }
  __shared__ float ls[256], lq[256];
  ls[threadIdx.x] = s; lq[threadIdx.x] = q;
  __syncthreads();
  if (half == 0) {
    atomicAdd(&sums[c], ls[c] + ls[c + DF]);
    atomicAdd(&sums[DF + c], lq[c] + lq[c + DF]);
  }
}

__global__ void bn_final_k(const float* __restrict__ sums, const float* __restrict__ gamma,
                           const float* __restrict__ beta, float* __restrict__ ss, int n) {
  int c = threadIdx.x;  // 128 threads, 1 block
  float m = sums[c] / (float)n;
  float var = sums[DF + c] / (float)n - m * m;
  if (var < 0.f) var = 0.f;
  float sc = gamma[c] / sqrtf(var + 1e-5f);
  ss[c] = sc;
  ss[DF + c] = beta[c] - m * sc;
}

// psum[g] += H[idx[i]]; pcnt[g] += 1
__global__ void pool_k(const float4* __restrict__ H, const int* __restrict__ idx,
                       const int* __restrict__ batch, float* __restrict__ psum,
                       int* __restrict__ pcnt, int ni) {
  int gid = blockIdx.x * 256 + threadIdx.x;
  if (gid >= ni * 32) return;
  int i = gid >> 5, part = gid & 31;
  int nd = idx[i];
  int g = batch[nd];
  float4 v = H[(size_t)nd * 32 + part];
  float* o = psum + (size_t)g * DF + part * 4;
  atomicAdd(o + 0, v.x);
  atomicAdd(o + 1, v.y);
  atomicAdd(o + 2, v.z);
  atomicAdd(o + 3, v.w);
  if (part == 0) atomicAdd(&pcnt[g], 1);
}

// per-graph: build comb[512], two MLP layers -> hbuf[g][128]
__global__ void head1_k(const float* __restrict__ psum, const int* __restrict__ pcnt,
                        const float* __restrict__ isum, const int* __restrict__ icnt,
                        const float* __restrict__ ss,
                        const float* __restrict__ gf_w1, const float* __restrict__ gf_b1,
                        const float* __restrict__ gf_w2, const float* __restrict__ gf_b2,
                        float* __restrict__ hbuf) {
  int g = blockIdx.x, j = threadIdx.x;  // 128 threads
  __shared__ float comb[4 * DF];
  __shared__ float t1[DF];
  int pc = pcnt[g], ic = icnt[g];
  float sc = ss[j], sh = ss[DF + j];
  float pf = pc > 0 ? (psum[(size_t)g * DF + j] / (float)pc) * sc + sh : 0.f;
  float im = ic > 0 ? (isum[(size_t)g * DF + j] / (float)ic) * sc + sh : 0.f;
  comb[j] = pf;
  comb[DF + j] = im;
  comb[2 * DF + j] = pf - im;
  comb[3 * DF + j] = pf * im;
  __syncthreads();
  float acc = gf_b1[j];
#pragma unroll 4
  for (int k = 0; k < 4 * DF; ++k) acc = fmaf(comb[k], gf_w1[(size_t)k * DF + j], acc);
  t1[j] = LEAKY(acc);
  __syncthreads();
  acc = gf_b2[j];
#pragma unroll 4
  for (int k = 0; k < DF; ++k) acc = fmaf(t1[k], gf_w2[(size_t)k * DF + j], acc);
  hbuf[(size_t)g * DF + j] = acc;
}

// BN2 over G rows of hbuf -> scale2/shift2 (single block, 128 threads)
__global__ void bn2_k(const float* __restrict__ hbuf, const float* __restrict__ gamma,
                      const float* __restrict__ beta, float* __restrict__ ss2, int G) {
  int c = threadIdx.x;
  float s = 0.f, q = 0.f;
  for (int r = 0; r < G; ++r) {
    float v = hbuf[(size_t)r * DF + c];
    s += v; q += v * v;
  }
  float m = s / (float)G;
  float var = q / (float)G - m * m;
  if (var < 0.f) var = 0.f;
  float sc = gamma[c] / sqrtf(var + 1e-5f);
  ss2[c] = sc;
  ss2[DF + c] = beta[c] - m * sc;
}

// per-graph: BN2-apply, 128->64 leaky, 64->32, 32->2; write out + prob
__global__ void head2_k(const float* __restrict__ hbuf, const float* __restrict__ ss2,
                        const float* __restrict__ fl_w1, const float* __restrict__ fl_b1,
                        const float* __restrict__ fl_w2, const float* __restrict__ fl_b2,
                        const float* __restrict__ out_w, const float* __restrict__ out_b,
                        float* __restrict__ d_out, int G) {
  int g = blockIdx.x, t = threadIdx.x;  // 128 threads
  __shared__ float hb[DF], t1[64], ov[32];
  hb[t] = hbuf[(size_t)g * DF + t] * ss2[t] + ss2[DF + t];
  __syncthreads();
  if (t < 64) {
    float acc = fl_b1[t];
#pragma unroll 4
    for (int c = 0; c < DF; ++c) acc = fmaf(hb[c], fl_w1[(size_t)c * 64 + t], acc);
    t1[t] = LEAKY(acc);
  }
  __syncthreads();
  if (t < 32) {
    float acc = fl_b2[t];
#pragma unroll 4
    for (int j = 0; j < 64; ++j) acc = fmaf(t1[j], fl_w2[(size_t)j * 32 + t], acc);
    d_out[(size_t)g * 32 + t] = acc;
    ov[t] = acc;
  }
  __syncthreads();
  if (t < 2) {
    float acc = out_b[t];
#pragma unroll
    for (int o = 0; o < 32; ++o) acc = fmaf(ov[o], out_w[(size_t)o * 2 + t], acc);
    d_out[(size_t)G * 32 + (size_t)g * 2 + t] = acc;
  }
}

extern "C" void kernel_launch(void* const* d_in, const int* in_sizes, int n_in,
                              void* d_out, int out_size, void* d_ws, size_t ws_size,
                              hipStream_t stream) {
  const float* x         = (const float*)d_in[0];
  const float* W_gnn     = (const float*)d_in[1];
  const float* b_gnn     = (const float*)d_in[2];
  const float* hbn_gamma = (const float*)d_in[3];
  const float* hbn_beta  = (const float*)d_in[4];
  const float* gf_w1     = (const float*)d_in[5];
  const float* gf_b1     = (const float*)d_in[6];
  const float* gf_w2     = (const float*)d_in[7];
  const float* gf_b2     = (const float*)d_in[8];
  const float* bn2_gamma = (const float*)d_in[9];
  const float* bn2_beta  = (const float*)d_in[10];
  const float* fl_w1     = (const float*)d_in[11];
  const float* fl_b1     = (const float*)d_in[12];
  const float* fl_w2     = (const float*)d_in[13];
  const float* fl_b2     = (const float*)d_in[14];
  const float* out_w     = (const float*)d_in[15];
  const float* out_b     = (const float*)d_in[16];
  const int* edge_index  = (const int*)d_in[17];
  const int* post_idx    = (const int*)d_in[18];
  const int* image_idx   = (const int*)d_in[19];
  const int* batch_vec   = (const int*)d_in[20];

  const int N  = in_sizes[20];
  const int E  = in_sizes[17] / 2;
  const int NP = in_sizes[18];
  const int NI = in_sizes[19];
  const int G  = out_size / 34;           // out: G*32 + prob: G*2
  const int L  = in_sizes[1] / (DF * DF);
  const int* src  = edge_index;
  const int* dstp = edge_index + E;

  char* ws = (char*)d_ws;
  size_t off = 0;
  auto alloc = [&](size_t b) { size_t o = off; off += (b + 255) & ~(size_t)255; return o; };
  float* dis    = (float*)(ws + alloc((size_t)N * 4));
  int*   degc   = (int*)(ws + alloc((size_t)N * 4));
  int*   rowoff = (int*)(ws + alloc((size_t)(N + 1) * 4));
  int*   cursor = (int*)(ws + alloc((size_t)N * 4));
  int*   eidx   = (int*)(ws + alloc((size_t)E * 4));
  unsigned short* Wb  = (unsigned short*)(ws + alloc((size_t)L * DF * DF * 2));
  unsigned short* xwb = (unsigned short*)(ws + alloc((size_t)N * DF * 2));
  float* H      = (float*)(ws + alloc((size_t)N * DF * 4));
  float* bns    = (float*)(ws + alloc(256 * 4));
  float* ss     = (float*)(ws + alloc(256 * 4));
  float* psum   = (float*)(ws + alloc((size_t)G * DF * 4));
  float* isum   = (float*)(ws + alloc((size_t)G * DF * 4));
  int*   pcnt   = (int*)(ws + alloc((size_t)G * 4));
  int*   icnt   = (int*)(ws + alloc((size_t)G * 4));
  float* hbuf   = (float*)(ws + alloc((size_t)G * DF * 4));
  float* ss2    = (float*)(ws + alloc(256 * 4));

  // degree + dis + CSR build (reused across both layers)
  hipMemsetAsync(degc, 0, (size_t)N * 4, stream);
  deg_count_k<<<(E + 255) / 256, 256, 0, stream>>>(dstp, degc, E);
  make_dis_k<<<(N + 255) / 256, 256, 0, stream>>>(degc, dis, N);
  scan_k<<<1, 1024, 0, stream>>>(degc, rowoff, cursor, N);
  csr_fill_k<<<(E + 255) / 256, 256, 0, stream>>>(src, dstp, cursor, eidx, E);
  castW_k<<<(L * DF * DF + 255) / 256, 256, 0, stream>>>(W_gnn, Wb, L * DF * DF);

  // GNN layers (bf16 MFMA gemm + bf16 gather reads, f32 accumulate)
  const float* Hin = x;
  for (int l = 0; l < L; ++l) {
    gemm_mfma_k<<<(N + 31) / 32, 256, 0, stream>>>(Hin, Wb + (size_t)l * DF * DF, xwb, N);
    gather_k<<<(N * 32 + 255) / 256, 256, 0, stream>>>(xwb, rowoff, eidx, dis,
                                                       b_gnn + (size_t)l * DF, (float4*)H, N);
    Hin = H;
  }

  // BN over H (fold into affine scale/shift)
  hipMemsetAsync(bns, 0, 256 * 4, stream);
  bn_stats_k<<<256, 256, 0, stream>>>(H, bns, N);
  bn_final_k<<<1, 128, 0, stream>>>(bns, hbn_gamma, hbn_beta, ss, N);

  // pooled sums
  hipMemsetAsync(psum, 0, (size_t)G * DF * 4, stream);
  hipMemsetAsync(isum, 0, (size_t)G * DF * 4, stream);
  hipMemsetAsync(pcnt, 0, (size_t)G * 4, stream);
  hipMemsetAsync(icnt, 0, (size_t)G * 4, stream);
  pool_k<<<(NP * 32 + 255) / 256, 256, 0, stream>>>((const float4*)H, post_idx, batch_vec, psum, pcnt, NP);
  pool_k<<<(NI * 32 + 255) / 256, 256, 0, stream>>>((const float4*)H, image_idx, batch_vec, isum, icnt, NI);

  // head
  head1_k<<<G, 128, 0, stream>>>(psum, pcnt, isum, icnt, ss, gf_w1, gf_b1, gf_w2, gf_b2, hbuf);
  bn2_k<<<1, 128, 0, stream>>>(hbuf, bn2_gamma, bn2_beta, ss2, G);
  head2_k<<<G, 128, 0, stream>>>(hbuf, ss2, fl_w1, fl_b1, fl_w2, fl_b2, out_w, out_b,
                                 (float*)d_out, G);
}

// Round 4
// 614.513 us; speedup vs baseline: 5.4178x; 1.1325x over previous
//
#include <hip/hip_runtime.h>
#include <hip/hip_bf16.h>
#include <math.h>

#define DF 128
#define LEAKY(x) ((x) > 0.f ? (x) : 0.01f * (x))

typedef __attribute__((ext_vector_type(8))) short short8v;   // 8 bf16 in 4 VGPRs
typedef __attribute__((ext_vector_type(4))) float f32x4;
typedef __attribute__((ext_vector_type(4))) unsigned short u16x4;

static __device__ __forceinline__ unsigned short f2bf(float f) {
  unsigned u = __float_as_uint(f);
  unsigned r = u + 0x7fffu + ((u >> 16) & 1u);   // RNE
  return (unsigned short)(r >> 16);
}
static __device__ __forceinline__ float bf2f(unsigned short b) {
  return __uint_as_float(((unsigned)b) << 16);
}

__global__ void deg_count_k(const int* __restrict__ dst, int* __restrict__ cnt, int nE) {
  int e = blockIdx.x * 256 + threadIdx.x;
  if (e < nE) atomicAdd(&cnt[dst[e]], 1);
}

__global__ void make_dis_k(const int* __restrict__ cnt, float* __restrict__ dis, int n) {
  int i = blockIdx.x * 256 + threadIdx.x;
  if (i < n) dis[i] = 1.0f / sqrtf((float)cnt[i] + 1.0f);
}

// ---- parallel scan: per-1024-block sums -> exclusive block offsets -> per-element scan ----
__global__ void blk_sum_k(const int* __restrict__ cnt, int* __restrict__ bsum, int n) {
  __shared__ int sh[1024];
  int idx = blockIdx.x * 1024 + threadIdx.x;
  sh[threadIdx.x] = (idx < n) ? cnt[idx] : 0;
  __syncthreads();
  for (int ofs = 512; ofs > 0; ofs >>= 1) {
    if (threadIdx.x < (unsigned)ofs) sh[threadIdx.x] += sh[threadIdx.x + ofs];
    __syncthreads();
  }
  if (threadIdx.x == 0) bsum[blockIdx.x] = sh[0];
}

// one block: exclusive scan of in[0..n) -> out[0..n], out[n] = total (n <= 1024)
__global__ void scan_small_k(const int* __restrict__ in, int* __restrict__ out, int n) {
  __shared__ int sh[1024];
  int v = (threadIdx.x < (unsigned)n) ? in[threadIdx.x] : 0;
  sh[threadIdx.x] = v;
  __syncthreads();
  for (int ofs = 1; ofs < 1024; ofs <<= 1) {
    int t = (threadIdx.x >= (unsigned)ofs) ? sh[threadIdx.x - ofs] : 0;
    __syncthreads();
    sh[threadIdx.x] += t;
    __syncthreads();
  }
  if (threadIdx.x < (unsigned)n) out[threadIdx.x] = sh[threadIdx.x] - v;
  if (threadIdx.x == 0) out[n] = sh[1023];
}

__global__ void blk_scan_k(const int* __restrict__ cnt, const int* __restrict__ boff,
                           int* __restrict__ rowoff, int* __restrict__ cursor, int n) {
  __shared__ int sh[1024];
  int idx = blockIdx.x * 1024 + threadIdx.x;
  int v = (idx < n) ? cnt[idx] : 0;
  sh[threadIdx.x] = v;
  __syncthreads();
  for (int ofs = 1; ofs < 1024; ofs <<= 1) {
    int t = (threadIdx.x >= (unsigned)ofs) ? sh[threadIdx.x - ofs] : 0;
    __syncthreads();
    sh[threadIdx.x] += t;
    __syncthreads();
  }
  if (idx < n) {
    int ex = boff[blockIdx.x] + sh[threadIdx.x] - v;
    rowoff[idx] = ex; cursor[idx] = ex;
    if (idx == n - 1) rowoff[n] = ex + v;
  }
}

__global__ void csr_fill_k(const int* __restrict__ src, const int* __restrict__ dst,
                           int* __restrict__ cursor, int* __restrict__ eidx, int nE) {
  int e = blockIdx.x * 256 + threadIdx.x;
  if (e < nE) {
    int p = atomicAdd(&cursor[dst[e]], 1);
    eidx[p] = src[e];
  }
}

__global__ void castW_k(const float* __restrict__ W, unsigned short* __restrict__ Wb, int n) {
  int i = blockIdx.x * 256 + threadIdx.x;
  if (i < n) Wb[i] = f2bf(W[i]);
}

// xwb[r][c] = bf16( sum_k A[r][k] * Wb[k][c] ), A: n x 128 f32, Wb: 128 x 128 bf16.
__global__ void __launch_bounds__(256) gemm_mfma_k(const float* __restrict__ A,
                                                   const unsigned short* __restrict__ Wb,
                                                   unsigned short* __restrict__ xwb, int n) {
  const int w = threadIdx.x >> 6, l = threadIdx.x & 63;
  const int wr = w & 1, wc = w >> 1;
  const int r0 = blockIdx.x * 32 + wr * 16;
  const int row = r0 + (l & 15);
  const int kg = l >> 4;                 // 0..3
  short8v bf[4][4];
#pragma unroll
  for (int ct = 0; ct < 4; ++ct) {
    int c = wc * 64 + ct * 16 + (l & 15);
#pragma unroll
    for (int ks = 0; ks < 4; ++ks) {
      int kb = ks * 32 + kg * 8;
      short8v t;
#pragma unroll
      for (int j = 0; j < 8; ++j) t[j] = (short)Wb[(size_t)(kb + j) * DF + c];
      bf[ct][ks] = t;
    }
  }
  f32x4 acc[4];
#pragma unroll
  for (int ct = 0; ct < 4; ++ct) acc[ct] = (f32x4)(0.f);
  const bool rok = row < n;
  const float* ap = A + (size_t)row * DF + kg * 8;
#pragma unroll
  for (int ks = 0; ks < 4; ++ks) {
    short8v af;
    if (rok) {
      float4 lo = *(const float4*)(ap + ks * 32);
      float4 hi = *(const float4*)(ap + ks * 32 + 4);
      af[0] = (short)f2bf(lo.x); af[1] = (short)f2bf(lo.y);
      af[2] = (short)f2bf(lo.z); af[3] = (short)f2bf(lo.w);
      af[4] = (short)f2bf(hi.x); af[5] = (short)f2bf(hi.y);
      af[6] = (short)f2bf(hi.z); af[7] = (short)f2bf(hi.w);
    } else {
      af = (short8v)0;
    }
#pragma unroll
    for (int ct = 0; ct < 4; ++ct)
      acc[ct] = __builtin_amdgcn_mfma_f32_16x16x32_bf16(af, bf[ct][ks], acc[ct], 0, 0, 0);
  }
#pragma unroll
  for (int ct = 0; ct < 4; ++ct) {
    int c = wc * 64 + ct * 16 + (l & 15);
#pragma unroll
    for (int rg = 0; rg < 4; ++rg) {
      int r = r0 + kg * 4 + rg;
      if (r < n) xwb[(size_t)r * DF + c] = f2bf(acc[ct][rg]);
    }
  }
}

// CSR gather + self-loop + bias + leaky, fused. 32 threads (4 bf16 each) per node.
__global__ void gather_k(const unsigned short* __restrict__ xwb, const int* __restrict__ rowoff,
                         const int* __restrict__ eidx, const float* __restrict__ dis,
                         const float* __restrict__ b, float4* __restrict__ H, int n) {
  int gid = blockIdx.x * 256 + threadIdx.x;
  int node = gid >> 5;
  if (node >= n) return;
  int part = gid & 31;
  int beg = rowoff[node], end = rowoff[node + 1];
  float dd = dis[node];
  float4 acc = make_float4(0.f, 0.f, 0.f, 0.f);
  for (int p = beg; p < end; ++p) {
    int s = eidx[p];
    float en = dis[s] * dd;
    u16x4 v = *(const u16x4*)(xwb + (size_t)s * DF + part * 4);
    acc.x = fmaf(bf2f(v[0]), en, acc.x);
    acc.y = fmaf(bf2f(v[1]), en, acc.y);
    acc.z = fmaf(bf2f(v[2]), en, acc.z);
    acc.w = fmaf(bf2f(v[3]), en, acc.w);
  }
  float sn = dd * dd;
  u16x4 xv = *(const u16x4*)(xwb + (size_t)node * DF + part * 4);
  float4 bb = ((const float4*)b)[part];
  float4 r;
  r.x = fmaf(bf2f(xv[0]), sn, acc.x) + bb.x;
  r.y = fmaf(bf2f(xv[1]), sn, acc.y) + bb.y;
  r.z = fmaf(bf2f(xv[2]), sn, acc.z) + bb.z;
  r.w = fmaf(bf2f(xv[3]), sn, acc.w) + bb.w;
  r.x = LEAKY(r.x); r.y = LEAKY(r.y); r.z = LEAKY(r.z); r.w = LEAKY(r.w);
  H[gid] = r;
}

// per-column sum and sumsq over n rows -> sums[0..127]=sum, sums[128..255]=sumsq
__global__ void bn_stats_k(const float* __restrict__ H, float* __restrict__ sums, int n) {
  int c = threadIdx.x & (DF - 1);
  int half = threadIdx.x >> 7;
  float s = 0.f, q = 0.f;
  for (int r = blockIdx.x * 2 + half; r < n; r += gridDim.x * 2) {
    float v = H[(size_t)r * DF + c];
    s += v; q += v * v;
  }
  __shared__ float ls[256], lq[256];
  ls[threadIdx.x] = s; lq[threadIdx.x] = q;
  __syncthreads();
  if (half == 0) {
    atomicAdd(&sums[c], ls[c] + ls[c + DF]);
    atomicAdd(&sums[DF + c], lq[c] + lq[c + DF]);
  }
}

__global__ void bn_final_k(const float* __restrict__ sums, const float* __restrict__ gamma,
                           const float* __restrict__ beta, float* __restrict__ ss, int n) {
  int c = threadIdx.x;  // 128 threads, 1 block
  float m = sums[c] / (float)n;
  float var = sums[DF + c] / (float)n - m * m;
  if (var < 0.f) var = 0.f;
  float sc = gamma[c] / sqrtf(var + 1e-5f);
  ss[c] = sc;
  ss[DF + c] = beta[c] - m * sc;
}

// psum[g] += H[idx[i]]; pcnt[g] += 1
__global__ void pool_k(const float4* __restrict__ H, const int* __restrict__ idx,
                       const int* __restrict__ batch, float* __restrict__ psum,
                       int* __restrict__ pcnt, int ni) {
  int gid = blockIdx.x * 256 + threadIdx.x;
  if (gid >= ni * 32) return;
  int i = gid >> 5, part = gid & 31;
  int nd = idx[i];
  int g = batch[nd];
  float4 v = H[(size_t)nd * 32 + part];
  float* o = psum + (size_t)g * DF + part * 4;
  atomicAdd(o + 0, v.x);
  atomicAdd(o + 1, v.y);
  atomicAdd(o + 2, v.z);
  atomicAdd(o + 3, v.w);
  if (part == 0) atomicAdd(&pcnt[g], 1);
}

// per-graph: build comb[512], two MLP layers -> hbuf[g][128]
__global__ void head1_k(const float* __restrict__ psum, const int* __restrict__ pcnt,
                        const float* __restrict__ isum, const int* __restrict__ icnt,
                        const float* __restrict__ ss,
                        const float* __restrict__ gf_w1, const float* __restrict__ gf_b1,
                        const float* __restrict__ gf_w2, const float* __restrict__ gf_b2,
                        float* __restrict__ hbuf) {
  int g = blockIdx.x, j = threadIdx.x;  // 128 threads
  __shared__ float comb[4 * DF];
  __shared__ float t1[DF];
  int pc = pcnt[g], ic = icnt[g];
  float sc = ss[j], sh = ss[DF + j];
  float pf = pc > 0 ? (psum[(size_t)g * DF + j] / (float)pc) * sc + sh : 0.f;
  float im = ic > 0 ? (isum[(size_t)g * DF + j] / (float)ic) * sc + sh : 0.f;
  comb[j] = pf;
  comb[DF + j] = im;
  comb[2 * DF + j] = pf - im;
  comb[3 * DF + j] = pf * im;
  __syncthreads();
  float acc = gf_b1[j];
#pragma unroll 4
  for (int k = 0; k < 4 * DF; ++k) acc = fmaf(comb[k], gf_w1[(size_t)k * DF + j], acc);
  t1[j] = LEAKY(acc);
  __syncthreads();
  acc = gf_b2[j];
#pragma unroll 4
  for (int k = 0; k < DF; ++k) acc = fmaf(t1[k], gf_w2[(size_t)k * DF + j], acc);
  hbuf[(size_t)g * DF + j] = acc;
}

// BN2 over G rows of hbuf -> scale2/shift2 (single block, 128 threads)
__global__ void bn2_k(const float* __restrict__ hbuf, const float* __restrict__ gamma,
                      const float* __restrict__ beta, float* __restrict__ ss2, int G) {
  int c = threadIdx.x;
  float s = 0.f, q = 0.f;
  for (int r = 0; r < G; ++r) {
    float v = hbuf[(size_t)r * DF + c];
    s += v; q += v * v;
  }
  float m = s / (float)G;
  float var = q / (float)G - m * m;
  if (var < 0.f) var = 0.f;
  float sc = gamma[c] / sqrtf(var + 1e-5f);
  ss2[c] = sc;
  ss2[DF + c] = beta[c] - m * sc;
}

// per-graph: BN2-apply, 128->64 leaky, 64->32, 32->2; write out + prob
__global__ void head2_k(const float* __restrict__ hbuf, const float* __restrict__ ss2,
                        const float* __restrict__ fl_w1, const float* __restrict__ fl_b1,
                        const float* __restrict__ fl_w2, const float* __restrict__ fl_b2,
                        const float* __restrict__ out_w, const float* __restrict__ out_b,
                        float* __restrict__ d_out, int G) {
  int g = blockIdx.x, t = threadIdx.x;  // 128 threads
  __shared__ float hb[DF], t1[64], ov[32];
  hb[t] = hbuf[(size_t)g * DF + t] * ss2[t] + ss2[DF + t];
  __syncthreads();
  if (t < 64) {
    float acc = fl_b1[t];
#pragma unroll 4
    for (int c = 0; c < DF; ++c) acc = fmaf(hb[c], fl_w1[(size_t)c * 64 + t], acc);
    t1[t] = LEAKY(acc);
  }
  __syncthreads();
  if (t < 32) {
    float acc = fl_b2[t];
#pragma unroll 4
    for (int j = 0; j < 64; ++j) acc = fmaf(t1[j], fl_w2[(size_t)j * 32 + t], acc);
    d_out[(size_t)g * 32 + t] = acc;
    ov[t] = acc;
  }
  __syncthreads();
  if (t < 2) {
    float acc = out_b[t];
#pragma unroll
    for (int o = 0; o < 32; ++o) acc = fmaf(ov[o], out_w[(size_t)o * 2 + t], acc);
    d_out[(size_t)G * 32 + (size_t)g * 2 + t] = acc;
  }
}

extern "C" void kernel_launch(void* const* d_in, const int* in_sizes, int n_in,
                              void* d_out, int out_size, void* d_ws, size_t ws_size,
                              hipStream_t stream) {
  const float* x         = (const float*)d_in[0];
  const float* W_gnn     = (const float*)d_in[1];
  const float* b_gnn     = (const float*)d_in[2];
  const float* hbn_gamma = (const float*)d_in[3];
  const float* hbn_beta  = (const float*)d_in[4];
  const float* gf_w1     = (const float*)d_in[5];
  const float* gf_b1     = (const float*)d_in[6];
  const float* gf_w2     = (const float*)d_in[7];
  const float* gf_b2     = (const float*)d_in[8];
  const float* bn2_gamma = (const float*)d_in[9];
  const float* bn2_beta  = (const float*)d_in[10];
  const float* fl_w1     = (const float*)d_in[11];
  const float* fl_b1     = (const float*)d_in[12];
  const float* fl_w2     = (const float*)d_in[13];
  const float* fl_b2     = (const float*)d_in[14];
  const float* out_w     = (const float*)d_in[15];
  const float* out_b     = (const float*)d_in[16];
  const int* edge_index  = (const int*)d_in[17];
  const int* post_idx    = (const int*)d_in[18];
  const int* image_idx   = (const int*)d_in[19];
  const int* batch_vec   = (const int*)d_in[20];

  const int N  = in_sizes[20];
  const int E  = in_sizes[17] / 2;
  const int NP = in_sizes[18];
  const int NI = in_sizes[19];
  const int G  = out_size / 34;           // out: G*32 + prob: G*2
  const int L  = in_sizes[1] / (DF * DF);
  const int* src  = edge_index;
  const int* dstp = edge_index + E;
  const int NB = (N + 1023) / 1024;       // scan blocks

  char* ws = (char*)d_ws;
  size_t off = 0;
  auto alloc = [&](size_t b) { size_t o = off; off += (b + 255) & ~(size_t)255; return o; };
  float* dis    = (float*)(ws + alloc((size_t)N * 4));
  int*   degc   = (int*)(ws + alloc((size_t)N * 4));
  int*   rowoff = (int*)(ws + alloc((size_t)(N + 1) * 4));
  int*   cursor = (int*)(ws + alloc((size_t)N * 4));
  int*   eidx   = (int*)(ws + alloc((size_t)E * 4));
  int*   bsum   = (int*)(ws + alloc((size_t)(NB + 1) * 4));
  int*   boff   = (int*)(ws + alloc((size_t)(NB + 1) * 4));
  unsigned short* Wb  = (unsigned short*)(ws + alloc((size_t)L * DF * DF * 2));
  unsigned short* xwb = (unsigned short*)(ws + alloc((size_t)N * DF * 2));
  float* H      = (float*)(ws + alloc((size_t)N * DF * 4));
  float* bns    = (float*)(ws + alloc(256 * 4));
  float* ss     = (float*)(ws + alloc(256 * 4));
  float* psum   = (float*)(ws + alloc((size_t)G * DF * 4));
  float* isum   = (float*)(ws + alloc((size_t)G * DF * 4));
  int*   pcnt   = (int*)(ws + alloc((size_t)G * 4));
  int*   icnt   = (int*)(ws + alloc((size_t)G * 4));
  float* hbuf   = (float*)(ws + alloc((size_t)G * DF * 4));
  float* ss2    = (float*)(ws + alloc(256 * 4));

  // degree + dis + CSR build (reused across both layers)
  hipMemsetAsync(degc, 0, (size_t)N * 4, stream);
  deg_count_k<<<(E + 255) / 256, 256, 0, stream>>>(dstp, degc, E);
  make_dis_k<<<(N + 255) / 256, 256, 0, stream>>>(degc, dis, N);
  blk_sum_k<<<NB, 1024, 0, stream>>>(degc, bsum, N);
  scan_small_k<<<1, 1024, 0, stream>>>(bsum, boff, NB);
  blk_scan_k<<<NB, 1024, 0, stream>>>(degc, boff, rowoff, cursor, N);
  csr_fill_k<<<(E + 255) / 256, 256, 0, stream>>>(src, dstp, cursor, eidx, E);
  castW_k<<<(L * DF * DF + 255) / 256, 256, 0, stream>>>(W_gnn, Wb, L * DF * DF);

  // GNN layers (bf16 MFMA gemm + bf16 gather reads, f32 accumulate)
  const float* Hin = x;
  for (int l = 0; l < L; ++l) {
    gemm_mfma_k<<<(N + 31) / 32, 256, 0, stream>>>(Hin, Wb + (size_t)l * DF * DF, xwb, N);
    gather_k<<<(N * 32 + 255) / 256, 256, 0, stream>>>(xwb, rowoff, eidx, dis,
                                                       b_gnn + (size_t)l * DF, (float4*)H, N);
    Hin = H;
  }

  // BN over H (fold into affine scale/shift)
  hipMemsetAsync(bns, 0, 256 * 4, stream);
  bn_stats_k<<<256, 256, 0, stream>>>(H, bns, N);
  bn_final_k<<<1, 128, 0, stream>>>(bns, hbn_gamma, hbn_beta, ss, N);

  // pooled sums
  hipMemsetAsync(psum, 0, (size_t)G * DF * 4, stream);
  hipMemsetAsync(isum, 0, (size_t)G * DF * 4, stream);
  hipMemsetAsync(pcnt, 0, (size_t)G * 4, stream);
  hipMemsetAsync(icnt, 0, (size_t)G * 4, stream);
  pool_k<<<(NP * 32 + 255) / 256, 256, 0, stream>>>((const float4*)H, post_idx, batch_vec, psum, pcnt, NP);
  pool_k<<<(NI * 32 + 255) / 256, 256, 0, stream>>>((const float4*)H, image_idx, batch_vec, isum, icnt, NI);

  // head
  head1_k<<<G, 128, 0, stream>>>(psum, pcnt, isum, icnt, ss, gf_w1, gf_b1, gf_w2, gf_b2, hbuf);
  bn2_k<<<1, 128, 0, stream>>>(hbuf, bn2_gamma, bn2_beta, ss2, G);
  head2_k<<<G, 128, 0, stream>>>(hbuf, ss2, fl_w1, fl_b1, fl_w2, fl_b2, out_w, out_b,
                                 (float*)d_out, G);
}

// Round 5
// 528.997 us; speedup vs baseline: 6.2936x; 1.1617x over previous
//
#include <hip/hip_runtime.h>
#include <hip/hip_bf16.h>
#include <math.h>

#define DF 128
#define PSPLIT 4
#define LEAKY(x) ((x) > 0.f ? (x) : 0.01f * (x))

typedef __attribute__((ext_vector_type(8))) short short8v;   // 8 bf16 in 4 VGPRs
typedef __attribute__((ext_vector_type(4))) float f32x4;
typedef __attribute__((ext_vector_type(4))) unsigned short u16x4;

static __device__ __forceinline__ unsigned short f2bf(float f) {
  unsigned u = __float_as_uint(f);
  unsigned r = u + 0x7fffu + ((u >> 16) & 1u);   // RNE
  return (unsigned short)(r >> 16);
}
static __device__ __forceinline__ float bf2f(unsigned short b) {
  return __uint_as_float(((unsigned)b) << 16);
}

__global__ void deg_count_k(const int* __restrict__ dst, int* __restrict__ cnt, int nE) {
  int e = blockIdx.x * 256 + threadIdx.x;
  if (e < nE) atomicAdd(&cnt[dst[e]], 1);
}

__global__ void make_dis_k(const int* __restrict__ cnt, float* __restrict__ dis, int n) {
  int i = blockIdx.x * 256 + threadIdx.x;
  if (i < n) dis[i] = 1.0f / sqrtf((float)cnt[i] + 1.0f);
}

// ---- parallel scan: per-1024-block sums -> exclusive block offsets -> per-element scan ----
__global__ void blk_sum_k(const int* __restrict__ cnt, int* __restrict__ bsum, int n) {
  __shared__ int sh[1024];
  int idx = blockIdx.x * 1024 + threadIdx.x;
  sh[threadIdx.x] = (idx < n) ? cnt[idx] : 0;
  __syncthreads();
  for (int ofs = 512; ofs > 0; ofs >>= 1) {
    if (threadIdx.x < (unsigned)ofs) sh[threadIdx.x] += sh[threadIdx.x + ofs];
    __syncthreads();
  }
  if (threadIdx.x == 0) bsum[blockIdx.x] = sh[0];
}

// one block: exclusive scan of in[0..n) -> out[0..n], out[n] = total (n <= 1024)
__global__ void scan_small_k(const int* __restrict__ in, int* __restrict__ out, int n) {
  __shared__ int sh[1024];
  int v = (threadIdx.x < (unsigned)n) ? in[threadIdx.x] : 0;
  sh[threadIdx.x] = v;
  __syncthreads();
  for (int ofs = 1; ofs < 1024; ofs <<= 1) {
    int t = (threadIdx.x >= (unsigned)ofs) ? sh[threadIdx.x - ofs] : 0;
    __syncthreads();
    sh[threadIdx.x] += t;
    __syncthreads();
  }
  if (threadIdx.x < (unsigned)n) out[threadIdx.x] = sh[threadIdx.x] - v;
  if (threadIdx.x == 0) out[n] = sh[1023];
}

// same but also writes a cursor copy
__global__ void scan_small2_k(const int* __restrict__ in, int* __restrict__ out,
                              int* __restrict__ cur, int n) {
  __shared__ int sh[1024];
  int v = (threadIdx.x < (unsigned)n) ? in[threadIdx.x] : 0;
  sh[threadIdx.x] = v;
  __syncthreads();
  for (int ofs = 1; ofs < 1024; ofs <<= 1) {
    int t = (threadIdx.x >= (unsigned)ofs) ? sh[threadIdx.x - ofs] : 0;
    __syncthreads();
    sh[threadIdx.x] += t;
    __syncthreads();
  }
  if (threadIdx.x < (unsigned)n) {
    int ex = sh[threadIdx.x] - v;
    out[threadIdx.x] = ex;
    cur[threadIdx.x] = ex;
  }
  if (threadIdx.x == 0) out[n] = sh[1023];
}

__global__ void blk_scan_k(const int* __restrict__ cnt, const int* __restrict__ boff,
                           int* __restrict__ rowoff, int* __restrict__ cursor, int n) {
  __shared__ int sh[1024];
  int idx = blockIdx.x * 1024 + threadIdx.x;
  int v = (idx < n) ? cnt[idx] : 0;
  sh[threadIdx.x] = v;
  __syncthreads();
  for (int ofs = 1; ofs < 1024; ofs <<= 1) {
    int t = (threadIdx.x >= (unsigned)ofs) ? sh[threadIdx.x - ofs] : 0;
    __syncthreads();
    sh[threadIdx.x] += t;
    __syncthreads();
  }
  if (idx < n) {
    int ex = boff[blockIdx.x] + sh[threadIdx.x] - v;
    rowoff[idx] = ex; cursor[idx] = ex;
    if (idx == n - 1) rowoff[n] = ex + v;
  }
}

__global__ void csr_fill_k(const int* __restrict__ src, const int* __restrict__ dst,
                           int* __restrict__ cursor, int* __restrict__ eidx, int nE) {
  int e = blockIdx.x * 256 + threadIdx.x;
  if (e < nE) {
    int p = atomicAdd(&cursor[dst[e]], 1);
    eidx[p] = src[e];
  }
}

__global__ void castW_k(const float* __restrict__ W, unsigned short* __restrict__ Wb, int n) {
  int i = blockIdx.x * 256 + threadIdx.x;
  if (i < n) Wb[i] = f2bf(W[i]);
}

// xwb[r][c] = bf16( sum_k A[r][k] * Wb[k][c] ), A: n x 128 f32, Wb: 128 x 128 bf16.
__global__ void __launch_bounds__(256) gemm_mfma_k(const float* __restrict__ A,
                                                   const unsigned short* __restrict__ Wb,
                                                   unsigned short* __restrict__ xwb, int n) {
  const int w = threadIdx.x >> 6, l = threadIdx.x & 63;
  const int wr = w & 1, wc = w >> 1;
  const int r0 = blockIdx.x * 32 + wr * 16;
  const int row = r0 + (l & 15);
  const int kg = l >> 4;                 // 0..3
  short8v bf[4][4];
#pragma unroll
  for (int ct = 0; ct < 4; ++ct) {
    int c = wc * 64 + ct * 16 + (l & 15);
#pragma unroll
    for (int ks = 0; ks < 4; ++ks) {
      int kb = ks * 32 + kg * 8;
      short8v t;
#pragma unroll
      for (int j = 0; j < 8; ++j) t[j] = (short)Wb[(size_t)(kb + j) * DF + c];
      bf[ct][ks] = t;
    }
  }
  f32x4 acc[4];
#pragma unroll
  for (int ct = 0; ct < 4; ++ct) acc[ct] = (f32x4)(0.f);
  const bool rok = row < n;
  const float* ap = A + (size_t)row * DF + kg * 8;
#pragma unroll
  for (int ks = 0; ks < 4; ++ks) {
    short8v af;
    if (rok) {
      float4 lo = *(const float4*)(ap + ks * 32);
      float4 hi = *(const float4*)(ap + ks * 32 + 4);
      af[0] = (short)f2bf(lo.x); af[1] = (short)f2bf(lo.y);
      af[2] = (short)f2bf(lo.z); af[3] = (short)f2bf(lo.w);
      af[4] = (short)f2bf(hi.x); af[5] = (short)f2bf(hi.y);
      af[6] = (short)f2bf(hi.z); af[7] = (short)f2bf(hi.w);
    } else {
      af = (short8v)0;
    }
#pragma unroll
    for (int ct = 0; ct < 4; ++ct)
      acc[ct] = __builtin_amdgcn_mfma_f32_16x16x32_bf16(af, bf[ct][ks], acc[ct], 0, 0, 0);
  }
#pragma unroll
  for (int ct = 0; ct < 4; ++ct) {
    int c = wc * 64 + ct * 16 + (l & 15);
#pragma unroll
    for (int rg = 0; rg < 4; ++rg) {
      int r = r0 + kg * 4 + rg;
      if (r < n) xwb[(size_t)r * DF + c] = f2bf(acc[ct][rg]);
    }
  }
}

// CSR gather + self-loop + bias + leaky, fused. 32 threads (4 bf16 each) per node.
__global__ void gather_k(const unsigned short* __restrict__ xwb, const int* __restrict__ rowoff,
                         const int* __restrict__ eidx, const float* __restrict__ dis,
                         const float* __restrict__ b, float4* __restrict__ H, int n) {
  int gid = blockIdx.x * 256 + threadIdx.x;
  int node = gid >> 5;
  if (node >= n) return;
  int part = gid & 31;
  int beg = rowoff[node], end = rowoff[node + 1];
  float dd = dis[node];
  float4 acc = make_float4(0.f, 0.f, 0.f, 0.f);
  for (int p = beg; p < end; ++p) {
    int s = eidx[p];
    float en = dis[s] * dd;
    u16x4 v = *(const u16x4*)(xwb + (size_t)s * DF + part * 4);
    acc.x = fmaf(bf2f(v[0]), en, acc.x);
    acc.y = fmaf(bf2f(v[1]), en, acc.y);
    acc.z = fmaf(bf2f(v[2]), en, acc.z);
    acc.w = fmaf(bf2f(v[3]), en, acc.w);
  }
  float sn = dd * dd;
  u16x4 xv = *(const u16x4*)(xwb + (size_t)node * DF + part * 4);
  float4 bb = ((const float4*)b)[part];
  float4 r;
  r.x = fmaf(bf2f(xv[0]), sn, acc.x) + bb.x;
  r.y = fmaf(bf2f(xv[1]), sn, acc.y) + bb.y;
  r.z = fmaf(bf2f(xv[2]), sn, acc.z) + bb.z;
  r.w = fmaf(bf2f(xv[3]), sn, acc.w) + bb.w;
  r.x = LEAKY(r.x); r.y = LEAKY(r.y); r.z = LEAKY(r.z); r.w = LEAKY(r.w);
  H[gid] = r;
}

// per-column sum and sumsq over n rows -> sums[0..127]=sum, sums[128..255]=sumsq
__global__ void bn_stats_k(const float* __restrict__ H, float* __restrict__ sums, int n) {
  int c = threadIdx.x & (DF - 1);
  int half = threadIdx.x >> 7;
  float s = 0.f, q = 0.f;
  for (int r = blockIdx.x * 2 + half; r < n; r += gridDim.x * 2) {
    float v = H[(size_t)r * DF + c];
    s += v; q += v * v;
  }
  __shared__ float ls[256], lq[256];
  ls[threadIdx.x] = s; lq[threadIdx.x] = q;
  __syncthreads();
  if (half == 0) {
    atomicAdd(&sums[c], ls[c] + ls[c + DF]);
    atomicAdd(&sums[DF + c], lq[c] + lq[c + DF]);
  }
}

__global__ void bn_final_k(const float* __restrict__ sums, const float* __restrict__ gamma,
                           const float* __restrict__ beta, float* __restrict__ ss, int n) {
  int c = threadIdx.x;  // 128 threads, 1 block
  float m = sums[c] / (float)n;
  float var = sums[DF + c] / (float)n - m * m;
  if (var < 0.f) var = 0.f;
  float sc = gamma[c] / sqrtf(var + 1e-5f);
  ss[c] = sc;
  ss[DF + c] = beta[c] - m * sc;
}

// ---- pooling: group indices by graph, then gather ----
__global__ void pool_cnt_k(const int* __restrict__ idx, const int* __restrict__ batch,
                           int* __restrict__ cnt, int ni) {
  int i = blockIdx.x * 256 + threadIdx.x;
  if (i < ni) atomicAdd(&cnt[batch[idx[i]]], 1);
}

__global__ void pool_fill_k(const int* __restrict__ idx, const int* __restrict__ batch,
                            int* __restrict__ cursor, int* __restrict__ mlist, int ni) {
  int i = blockIdx.x * 256 + threadIdx.x;
  if (i < ni) {
    int nd = idx[i];
    int p = atomicAdd(&cursor[batch[nd]], 1);
    mlist[p] = nd;
  }
}

// grid: (G*PSPLIT, 2). Each block: partial sum of graph g's member rows -> one atomic per col.
__global__ void pool_gather_k(const float4* __restrict__ H,
                              const int* __restrict__ goff_p, const int* __restrict__ mlist_p,
                              const int* __restrict__ goff_i, const int* __restrict__ mlist_i,
                              float* __restrict__ psum, float* __restrict__ isum) {
  int g = blockIdx.x / PSPLIT, sub = blockIdx.x % PSPLIT;
  const int* goff  = blockIdx.y ? goff_i  : goff_p;
  const int* mlist = blockIdx.y ? mlist_i : mlist_p;
  float* out       = blockIdx.y ? isum    : psum;
  int part = threadIdx.x & 31, slot = threadIdx.x >> 5;  // 8 row slots
  int beg = goff[g], end = goff[g + 1];
  float4 acc = make_float4(0.f, 0.f, 0.f, 0.f);
  for (int j = beg + sub * 8 + slot; j < end; j += PSPLIT * 8) {
    float4 v = H[(size_t)mlist[j] * 32 + part];
    acc.x += v.x; acc.y += v.y; acc.z += v.z; acc.w += v.w;
  }
  __shared__ float4 sh[256];
  sh[threadIdx.x] = acc;
  __syncthreads();
  for (int ofs = 128; ofs >= 32; ofs >>= 1) {
    if (threadIdx.x < (unsigned)ofs) {
      float4 o = sh[threadIdx.x + ofs];
      float4 a = sh[threadIdx.x];
      a.x += o.x; a.y += o.y; a.z += o.z; a.w += o.w;
      sh[threadIdx.x] = a;
    }
    __syncthreads();
  }
  if (threadIdx.x < 32) {
    float4 a = sh[threadIdx.x];
    float* o = out + (size_t)g * DF + part * 4;
    atomicAdd(o + 0, a.x);
    atomicAdd(o + 1, a.y);
    atomicAdd(o + 2, a.z);
    atomicAdd(o + 3, a.w);
  }
}

// per-graph: build comb[512], two MLP layers -> hbuf[g][128]
__global__ void head1_k(const float* __restrict__ psum, const int* __restrict__ pcnt,
                        const float* __restrict__ isum, const int* __restrict__ icnt,
                        const float* __restrict__ ss,
                        const float* __restrict__ gf_w1, const float* __restrict__ gf_b1,
                        const float* __restrict__ gf_w2, const float* __restrict__ gf_b2,
                        float* __restrict__ hbuf) {
  int g = blockIdx.x, j = threadIdx.x;  // 128 threads
  __shared__ float comb[4 * DF];
  __shared__ float t1[DF];
  int pc = pcnt[g], ic = icnt[g];
  float sc = ss[j], sh = ss[DF + j];
  float pf = pc > 0 ? (psum[(size_t)g * DF + j] / (float)pc) * sc + sh : 0.f;
  float im = ic > 0 ? (isum[(size_t)g * DF + j] / (float)ic) * sc + sh : 0.f;
  comb[j] = pf;
  comb[DF + j] = im;
  comb[2 * DF + j] = pf - im;
  comb[3 * DF + j] = pf * im;
  __syncthreads();
  float acc = gf_b1[j];
#pragma unroll 4
  for (int k = 0; k < 4 * DF; ++k) acc = fmaf(comb[k], gf_w1[(size_t)k * DF + j], acc);
  t1[j] = LEAKY(acc);
  __syncthreads();
  acc = gf_b2[j];
#pragma unroll 4
  for (int k = 0; k < DF; ++k) acc = fmaf(t1[k], gf_w2[(size_t)k * DF + j], acc);
  hbuf[(size_t)g * DF + j] = acc;
}

// BN2 over G rows of hbuf -> scale2/shift2 (single block, 128 threads)
__global__ void bn2_k(const float* __restrict__ hbuf, const float* __restrict__ gamma,
                      const float* __restrict__ beta, float* __restrict__ ss2, int G) {
  int c = threadIdx.x;
  float s = 0.f, q = 0.f;
  for (int r = 0; r < G; ++r) {
    float v = hbuf[(size_t)r * DF + c];
    s += v; q += v * v;
  }
  float m = s / (float)G;
  float var = q / (float)G - m * m;
  if (var < 0.f) var = 0.f;
  float sc = gamma[c] / sqrtf(var + 1e-5f);
  ss2[c] = sc;
  ss2[DF + c] = beta[c] - m * sc;
}

// per-graph: BN2-apply, 128->64 leaky, 64->32, 32->2; write out + prob
__global__ void head2_k(const float* __restrict__ hbuf, const float* __restrict__ ss2,
                        const float* __restrict__ fl_w1, const float* __restrict__ fl_b1,
                        const float* __restrict__ fl_w2, const float* __restrict__ fl_b2,
                        const float* __restrict__ out_w, const float* __restrict__ out_b,
                        float* __restrict__ d_out, int G) {
  int g = blockIdx.x, t = threadIdx.x;  // 128 threads
  __shared__ float hb[DF], t1[64], ov[32];
  hb[t] = hbuf[(size_t)g * DF + t] * ss2[t] + ss2[DF + t];
  __syncthreads();
  if (t < 64) {
    float acc = fl_b1[t];
#pragma unroll 4
    for (int c = 0; c < DF; ++c) acc = fmaf(hb[c], fl_w1[(size_t)c * 64 + t], acc);
    t1[t] = LEAKY(acc);
  }
  __syncthreads();
  if (t < 32) {
    float acc = fl_b2[t];
#pragma unroll 4
    for (int j = 0; j < 64; ++j) acc = fmaf(t1[j], fl_w2[(size_t)j * 32 + t], acc);
    d_out[(size_t)g * 32 + t] = acc;
    ov[t] = acc;
  }
  __syncthreads();
  if (t < 2) {
    float acc = out_b[t];
#pragma unroll
    for (int o = 0; o < 32; ++o) acc = fmaf(ov[o], out_w[(size_t)o * 2 + t], acc);
    d_out[(size_t)G * 32 + (size_t)g * 2 + t] = acc;
  }
}

extern "C" void kernel_launch(void* const* d_in, const int* in_sizes, int n_in,
                              void* d_out, int out_size, void* d_ws, size_t ws_size,
                              hipStream_t stream) {
  const float* x         = (const float*)d_in[0];
  const float* W_gnn     = (const float*)d_in[1];
  const float* b_gnn     = (const float*)d_in[2];
  const float* hbn_gamma = (const float*)d_in[3];
  const float* hbn_beta  = (const float*)d_in[4];
  const float* gf_w1     = (const float*)d_in[5];
  const float* gf_b1     = (const float*)d_in[6];
  const float* gf_w2     = (const float*)d_in[7];
  const float* gf_b2     = (const float*)d_in[8];
  const float* bn2_gamma = (const float*)d_in[9];
  const float* bn2_beta  = (const float*)d_in[10];
  const float* fl_w1     = (const float*)d_in[11];
  const float* fl_b1     = (const float*)d_in[12];
  const float* fl_w2     = (const float*)d_in[13];
  const float* fl_b2     = (const float*)d_in[14];
  const float* out_w     = (const float*)d_in[15];
  const float* out_b     = (const float*)d_in[16];
  const int* edge_index  = (const int*)d_in[17];
  const int* post_idx    = (const int*)d_in[18];
  const int* image_idx   = (const int*)d_in[19];
  const int* batch_vec   = (const int*)d_in[20];

  const int N  = in_sizes[20];
  const int E  = in_sizes[17] / 2;
  const int NP = in_sizes[18];
  const int NI = in_sizes[19];
  const int G  = out_size / 34;           // out: G*32 + prob: G*2
  const int L  = in_sizes[1] / (DF * DF);
  const int* src  = edge_index;
  const int* dstp = edge_index + E;
  const int NB = (N + 1023) / 1024;       // scan blocks

  char* ws = (char*)d_ws;
  size_t off = 0;
  auto alloc = [&](size_t b) { size_t o = off; off += (b + 255) & ~(size_t)255; return o; };
  float* dis    = (float*)(ws + alloc((size_t)N * 4));
  int*   degc   = (int*)(ws + alloc((size_t)N * 4));
  int*   rowoff = (int*)(ws + alloc((size_t)(N + 1) * 4));
  int*   cursor = (int*)(ws + alloc((size_t)N * 4));
  int*   eidx   = (int*)(ws + alloc((size_t)E * 4));
  int*   bsum   = (int*)(ws + alloc((size_t)(NB + 1) * 4));
  int*   boff   = (int*)(ws + alloc((size_t)(NB + 1) * 4));
  unsigned short* Wb  = (unsigned short*)(ws + alloc((size_t)L * DF * DF * 2));
  unsigned short* xwb = (unsigned short*)(ws + alloc((size_t)N * DF * 2));
  float* H      = (float*)(ws + alloc((size_t)N * DF * 4));
  float* bns    = (float*)(ws + alloc(256 * 4));
  float* ss     = (float*)(ws + alloc(256 * 4));
  float* psum   = (float*)(ws + alloc((size_t)G * DF * 4));
  float* isum   = (float*)(ws + alloc((size_t)G * DF * 4));
  int*   pcnt   = (int*)(ws + alloc((size_t)G * 4));
  int*   icnt   = (int*)(ws + alloc((size_t)G * 4));
  int*   poff   = (int*)(ws + alloc((size_t)(G + 1) * 4));
  int*   ioff   = (int*)(ws + alloc((size_t)(G + 1) * 4));
  int*   pcur   = (int*)(ws + alloc((size_t)G * 4));
  int*   icur   = (int*)(ws + alloc((size_t)G * 4));
  int*   plist  = (int*)(ws + alloc((size_t)NP * 4));
  int*   ilist  = (int*)(ws + alloc((size_t)NI * 4));
  float* hbuf   = (float*)(ws + alloc((size_t)G * DF * 4));
  float* ss2    = (float*)(ws + alloc(256 * 4));

  // degree + dis + CSR build (reused across both layers)
  hipMemsetAsync(degc, 0, (size_t)N * 4, stream);
  deg_count_k<<<(E + 255) / 256, 256, 0, stream>>>(dstp, degc, E);
  make_dis_k<<<(N + 255) / 256, 256, 0, stream>>>(degc, dis, N);
  blk_sum_k<<<NB, 1024, 0, stream>>>(degc, bsum, N);
  scan_small_k<<<1, 1024, 0, stream>>>(bsum, boff, NB);
  blk_scan_k<<<NB, 1024, 0, stream>>>(degc, boff, rowoff, cursor, N);
  csr_fill_k<<<(E + 255) / 256, 256, 0, stream>>>(src, dstp, cursor, eidx, E);
  castW_k<<<(L * DF * DF + 255) / 256, 256, 0, stream>>>(W_gnn, Wb, L * DF * DF);

  // pool index grouping (independent of H; do it early)
  hipMemsetAsync(pcnt, 0, (size_t)G * 4, stream);
  hipMemsetAsync(icnt, 0, (size_t)G * 4, stream);
  pool_cnt_k<<<(NP + 255) / 256, 256, 0, stream>>>(post_idx, batch_vec, pcnt, NP);
  pool_cnt_k<<<(NI + 255) / 256, 256, 0, stream>>>(image_idx, batch_vec, icnt, NI);
  scan_small2_k<<<1, 1024, 0, stream>>>(pcnt, poff, pcur, G);
  scan_small2_k<<<1, 1024, 0, stream>>>(icnt, ioff, icur, G);
  pool_fill_k<<<(NP + 255) / 256, 256, 0, stream>>>(post_idx, batch_vec, pcur, plist, NP);
  pool_fill_k<<<(NI + 255) / 256, 256, 0, stream>>>(image_idx, batch_vec, icur, ilist, NI);

  // GNN layers (bf16 MFMA gemm + bf16 gather reads, f32 accumulate)
  const float* Hin = x;
  for (int l = 0; l < L; ++l) {
    gemm_mfma_k<<<(N + 31) / 32, 256, 0, stream>>>(Hin, Wb + (size_t)l * DF * DF, xwb, N);
    gather_k<<<(N * 32 + 255) / 256, 256, 0, stream>>>(xwb, rowoff, eidx, dis,
                                                       b_gnn + (size_t)l * DF, (float4*)H, N);
    Hin = H;
  }

  // BN over H (fold into affine scale/shift)
  hipMemsetAsync(bns, 0, 256 * 4, stream);
  bn_stats_k<<<256, 256, 0, stream>>>(H, bns, N);
  bn_final_k<<<1, 128, 0, stream>>>(bns, hbn_gamma, hbn_beta, ss, N);

  // pooled sums via grouped gather
  hipMemsetAsync(psum, 0, (size_t)G * DF * 4, stream);
  hipMemsetAsync(isum, 0, (size_t)G * DF * 4, stream);
  dim3 pg(G * PSPLIT, 2);
  pool_gather_k<<<pg, 256, 0, stream>>>((const float4*)H, poff, plist, ioff, ilist, psum, isum);

  // head
  head1_k<<<G, 128, 0, stream>>>(psum, pcnt, isum, icnt, ss, gf_w1, gf_b1, gf_w2, gf_b2, hbuf);
  bn2_k<<<1, 128, 0, stream>>>(hbuf, bn2_gamma, bn2_beta, ss2, G);
  head2_k<<<G, 128, 0, stream>>>(hbuf, ss2, fl_w1, fl_b1, fl_w2, fl_b2, out_w, out_b,
                                 (float*)d_out, G);
}

// Round 6
// 423.273 us; speedup vs baseline: 7.8656x; 1.2498x over previous
//
#include <hip/hip_runtime.h>
#include <hip/hip_bf16.h>
#include <math.h>

#define DF 128
#define PSPLIT 4
#define LEAKY(x) ((x) > 0.f ? (x) : 0.01f * (x))

typedef __attribute__((ext_vector_type(8))) short short8v;   // 8 bf16 in 4 VGPRs
typedef __attribute__((ext_vector_type(4))) float f32x4;
typedef __attribute__((ext_vector_type(4))) unsigned short u16x4;
typedef __attribute__((ext_vector_type(8))) unsigned short u16x8;

static __device__ __forceinline__ unsigned short f2bf(float f) {
  unsigned u = __float_as_uint(f);
  unsigned r = u + 0x7fffu + ((u >> 16) & 1u);   // RNE
  return (unsigned short)(r >> 16);
}
static __device__ __forceinline__ float bf2f(unsigned short b) {
  return __uint_as_float(((unsigned)b) << 16);
}

__global__ void deg_count_k(const int* __restrict__ dst, int* __restrict__ cnt, int nE) {
  int e = blockIdx.x * 256 + threadIdx.x;
  if (e < nE) atomicAdd(&cnt[dst[e]], 1);
}

__global__ void make_dis_k(const int* __restrict__ cnt, float* __restrict__ dis, int n) {
  int i = blockIdx.x * 256 + threadIdx.x;
  if (i < n) dis[i] = 1.0f / sqrtf((float)cnt[i] + 1.0f);
}

// ---- parallel scan: per-1024-block sums -> exclusive block offsets -> per-element scan ----
__global__ void blk_sum_k(const int* __restrict__ cnt, int* __restrict__ bsum, int n) {
  __shared__ int sh[1024];
  int idx = blockIdx.x * 1024 + threadIdx.x;
  sh[threadIdx.x] = (idx < n) ? cnt[idx] : 0;
  __syncthreads();
  for (int ofs = 512; ofs > 0; ofs >>= 1) {
    if (threadIdx.x < (unsigned)ofs) sh[threadIdx.x] += sh[threadIdx.x + ofs];
    __syncthreads();
  }
  if (threadIdx.x == 0) bsum[blockIdx.x] = sh[0];
}

// one block: exclusive scan of in[0..n) -> out[0..n], out[n] = total (n <= 1024)
__global__ void scan_small_k(const int* __restrict__ in, int* __restrict__ out, int n) {
  __shared__ int sh[1024];
  int v = (threadIdx.x < (unsigned)n) ? in[threadIdx.x] : 0;
  sh[threadIdx.x] = v;
  __syncthreads();
  for (int ofs = 1; ofs < 1024; ofs <<= 1) {
    int t = (threadIdx.x >= (unsigned)ofs) ? sh[threadIdx.x - ofs] : 0;
    __syncthreads();
    sh[threadIdx.x] += t;
    __syncthreads();
  }
  if (threadIdx.x < (unsigned)n) out[threadIdx.x] = sh[threadIdx.x] - v;
  if (threadIdx.x == 0) out[n] = sh[1023];
}

// same but also writes a cursor copy
__global__ void scan_small2_k(const int* __restrict__ in, int* __restrict__ out,
                              int* __restrict__ cur, int n) {
  __shared__ int sh[1024];
  int v = (threadIdx.x < (unsigned)n) ? in[threadIdx.x] : 0;
  sh[threadIdx.x] = v;
  __syncthreads();
  for (int ofs = 1; ofs < 1024; ofs <<= 1) {
    int t = (threadIdx.x >= (unsigned)ofs) ? sh[threadIdx.x - ofs] : 0;
    __syncthreads();
    sh[threadIdx.x] += t;
    __syncthreads();
  }
  if (threadIdx.x < (unsigned)n) {
    int ex = sh[threadIdx.x] - v;
    out[threadIdx.x] = ex;
    cur[threadIdx.x] = ex;
  }
  if (threadIdx.x == 0) out[n] = sh[1023];
}

__global__ void blk_scan_k(const int* __restrict__ cnt, const int* __restrict__ boff,
                           int* __restrict__ rowoff, int* __restrict__ cursor, int n) {
  __shared__ int sh[1024];
  int idx = blockIdx.x * 1024 + threadIdx.x;
  int v = (idx < n) ? cnt[idx] : 0;
  sh[threadIdx.x] = v;
  __syncthreads();
  for (int ofs = 1; ofs < 1024; ofs <<= 1) {
    int t = (threadIdx.x >= (unsigned)ofs) ? sh[threadIdx.x - ofs] : 0;
    __syncthreads();
    sh[threadIdx.x] += t;
    __syncthreads();
  }
  if (idx < n) {
    int ex = boff[blockIdx.x] + sh[threadIdx.x] - v;
    rowoff[idx] = ex; cursor[idx] = ex;
    if (idx == n - 1) rowoff[n] = ex + v;
  }
}

// CSR fill with per-edge norm precompute
__global__ void csr_fill_k(const int* __restrict__ src, const int* __restrict__ dst,
                           const float* __restrict__ dis, int* __restrict__ cursor,
                           int* __restrict__ eidx, float* __restrict__ enorm, int nE) {
  int e = blockIdx.x * 256 + threadIdx.x;
  if (e < nE) {
    int s = src[e], d = dst[e];
    int p = atomicAdd(&cursor[d], 1);
    eidx[p] = s;
    enorm[p] = dis[s] * dis[d];
  }
}

// W -> bf16 in MFMA-fragment order: per layer, o = (((wc*4+ct)*4+ks)*64 + l)*8 + j
// maps to row = ks*32 + (l>>4)*8 + j, col = wc*64 + ct*16 + (l&15).
__global__ void castW_k(const float* __restrict__ W, unsigned short* __restrict__ Wb, int total) {
  int i = blockIdx.x * 256 + threadIdx.x;
  if (i >= total) return;
  int layer = i >> 14, o = i & 16383;
  int j = o & 7, l = (o >> 3) & 63, ks = (o >> 9) & 3, ct = (o >> 11) & 3, wc = (o >> 13) & 1;
  int row = ks * 32 + (l >> 4) * 8 + j;
  int col = wc * 64 + ct * 16 + (l & 15);
  Wb[i] = f2bf(W[((size_t)layer << 14) + row * DF + col]);
}

// xwb[r][c] = bf16( sum_k A[r][k] * W[k][c] ); A from f32 (layer0) or bf16 Hb.
template<bool BF16A>
__global__ void __launch_bounds__(256) gemm_mfma_k(const float* __restrict__ A,
                                                   const unsigned short* __restrict__ Ab,
                                                   const unsigned short* __restrict__ Wb,
                                                   unsigned short* __restrict__ xwb, int n) {
  const int w = threadIdx.x >> 6, l = threadIdx.x & 63;
  const int wr = w & 1, wc = w >> 1;
  const int r0 = blockIdx.x * 32 + wr * 16;
  const int row = r0 + (l & 15);
  const int kg = l >> 4;                 // 0..3
  short8v bf[4][4];
  const unsigned short* wp = Wb + (size_t)wc * 8192 + (size_t)l * 8;
#pragma unroll
  for (int ct = 0; ct < 4; ++ct)
#pragma unroll
    for (int ks = 0; ks < 4; ++ks)
      bf[ct][ks] = *(const short8v*)(wp + ((ct * 4 + ks) << 9));
  const bool rok = row < n;
  short8v af[4];
  if constexpr (BF16A) {
    const unsigned short* ap = Ab + (size_t)row * DF + kg * 8;
#pragma unroll
    for (int ks = 0; ks < 4; ++ks)
      af[ks] = rok ? *(const short8v*)(ap + ks * 32) : (short8v)0;
  } else {
    const float* ap = A + (size_t)row * DF + kg * 8;
#pragma unroll
    for (int ks = 0; ks < 4; ++ks) {
      if (rok) {
        float4 lo = *(const float4*)(ap + ks * 32);
        float4 hi = *(const float4*)(ap + ks * 32 + 4);
        short8v t;
        t[0] = (short)f2bf(lo.x); t[1] = (short)f2bf(lo.y);
        t[2] = (short)f2bf(lo.z); t[3] = (short)f2bf(lo.w);
        t[4] = (short)f2bf(hi.x); t[5] = (short)f2bf(hi.y);
        t[6] = (short)f2bf(hi.z); t[7] = (short)f2bf(hi.w);
        af[ks] = t;
      } else af[ks] = (short8v)0;
    }
  }
  f32x4 acc[4];
#pragma unroll
  for (int ct = 0; ct < 4; ++ct) acc[ct] = (f32x4)(0.f);
#pragma unroll
  for (int ks = 0; ks < 4; ++ks)
#pragma unroll
    for (int ct = 0; ct < 4; ++ct)
      acc[ct] = __builtin_amdgcn_mfma_f32_16x16x32_bf16(af[ks], bf[ct][ks], acc[ct], 0, 0, 0);
#pragma unroll
  for (int ct = 0; ct < 4; ++ct) {
    int c = wc * 64 + ct * 16 + (l & 15);
#pragma unroll
    for (int rg = 0; rg < 4; ++rg) {
      int r = r0 + kg * 4 + rg;
      if (r < n) xwb[(size_t)r * DF + c] = f2bf(acc[ct][rg]);
    }
  }
}

// CSR gather + self-loop + bias + leaky. 16 lanes/node, u16x8 loads, edge loop unrolled x4.
__global__ void gather_k(const unsigned short* __restrict__ xwb, const int* __restrict__ rowoff,
                         const int* __restrict__ eidx, const float* __restrict__ enorm,
                         const float* __restrict__ dis, const float* __restrict__ b,
                         unsigned short* __restrict__ Hb, int n) {
  int gid = blockIdx.x * 256 + threadIdx.x;
  int node = gid >> 4;
  if (node >= n) return;
  int part = gid & 15;
  int beg = rowoff[node], end = rowoff[node + 1];
  float acc[8];
#pragma unroll
  for (int j = 0; j < 8; ++j) acc[j] = 0.f;
  int p = beg;
  for (; p + 3 < end; p += 4) {
    int s0 = eidx[p], s1 = eidx[p + 1], s2 = eidx[p + 2], s3 = eidx[p + 3];
    float e0 = enorm[p], e1 = enorm[p + 1], e2 = enorm[p + 2], e3 = enorm[p + 3];
    u16x8 v0 = *(const u16x8*)(xwb + (size_t)s0 * DF + part * 8);
    u16x8 v1 = *(const u16x8*)(xwb + (size_t)s1 * DF + part * 8);
    u16x8 v2 = *(const u16x8*)(xwb + (size_t)s2 * DF + part * 8);
    u16x8 v3 = *(const u16x8*)(xwb + (size_t)s3 * DF + part * 8);
#pragma unroll
    for (int j = 0; j < 8; ++j) {
      acc[j] = fmaf(bf2f(v0[j]), e0, acc[j]);
      acc[j] = fmaf(bf2f(v1[j]), e1, acc[j]);
      acc[j] = fmaf(bf2f(v2[j]), e2, acc[j]);
      acc[j] = fmaf(bf2f(v3[j]), e3, acc[j]);
    }
  }
  for (; p < end; ++p) {
    int s = eidx[p];
    float e = enorm[p];
    u16x8 v = *(const u16x8*)(xwb + (size_t)s * DF + part * 8);
#pragma unroll
    for (int j = 0; j < 8; ++j) acc[j] = fmaf(bf2f(v[j]), e, acc[j]);
  }
  float dd = dis[node], sn = dd * dd;
  u16x8 xv = *(const u16x8*)(xwb + (size_t)node * DF + part * 8);
  const float* bp = b + part * 8;
  u16x8 o;
#pragma unroll
  for (int j = 0; j < 8; ++j) {
    float r = fmaf(bf2f(xv[j]), sn, acc[j]) + bp[j];
    r = LEAKY(r);
    o[j] = f2bf(r);
  }
  *(u16x8*)(Hb + (size_t)node * DF + part * 8) = o;
}

// per-column sum and sumsq over n rows of bf16 H -> sums[0..127]=sum, sums[128..255]=sumsq
__global__ void bn_stats_k(const unsigned short* __restrict__ Hb, float* __restrict__ sums, int n) {
  int c = threadIdx.x & (DF - 1);
  int half = threadIdx.x >> 7;
  float s = 0.f, q = 0.f;
  for (int r = blockIdx.x * 2 + half; r < n; r += gridDim.x * 2) {
    float v = bf2f(Hb[(size_t)r * DF + c]);
    s += v; q += v * v;
  }
  __shared__ float ls[256], lq[256];
  ls[threadIdx.x] = s; lq[threadIdx.x] = q;
  __syncthreads();
  if (half == 0) {
    atomicAdd(&sums[c], ls[c] + ls[c + DF]);
    atomicAdd(&sums[DF + c], lq[c] + lq[c + DF]);
  }
}

__global__ void bn_final_k(const float* __restrict__ sums, const float* __restrict__ gamma,
                           const float* __restrict__ beta, float* __restrict__ ss, int n) {
  int c = threadIdx.x;  // 128 threads, 1 block
  float m = sums[c] / (float)n;
  float var = sums[DF + c] / (float)n - m * m;
  if (var < 0.f) var = 0.f;
  float sc = gamma[c] / sqrtf(var + 1e-5f);
  ss[c] = sc;
  ss[DF + c] = beta[c] - m * sc;
}

// ---- pooling: group indices by graph, then gather ----
__global__ void pool_cnt_k(const int* __restrict__ idx, const int* __restrict__ batch,
                           int* __restrict__ cnt, int ni) {
  int i = blockIdx.x * 256 + threadIdx.x;
  if (i < ni) atomicAdd(&cnt[batch[idx[i]]], 1);
}

__global__ void pool_fill_k(const int* __restrict__ idx, const int* __restrict__ batch,
                            int* __restrict__ cursor, int* __restrict__ mlist, int ni) {
  int i = blockIdx.x * 256 + threadIdx.x;
  if (i < ni) {
    int nd = idx[i];
    int p = atomicAdd(&cursor[batch[nd]], 1);
    mlist[p] = nd;
  }
}

// grid: (G*PSPLIT, 2). Each block: partial sum of graph g's member rows -> one atomic per col.
__global__ void pool_gather_k(const unsigned short* __restrict__ Hb,
                              const int* __restrict__ goff_p, const int* __restrict__ mlist_p,
                              const int* __restrict__ goff_i, const int* __restrict__ mlist_i,
                              float* __restrict__ psum, float* __restrict__ isum) {
  int g = blockIdx.x / PSPLIT, sub = blockIdx.x % PSPLIT;
  const int* goff  = blockIdx.y ? goff_i  : goff_p;
  const int* mlist = blockIdx.y ? mlist_i : mlist_p;
  float* out       = blockIdx.y ? isum    : psum;
  int part = threadIdx.x & 31, slot = threadIdx.x >> 5;  // 8 row slots
  int beg = goff[g], end = goff[g + 1];
  float4 acc = make_float4(0.f, 0.f, 0.f, 0.f);
  for (int j = beg + sub * 8 + slot; j < end; j += PSPLIT * 8) {
    u16x4 v = *(const u16x4*)(Hb + (size_t)mlist[j] * DF + part * 4);
    acc.x += bf2f(v[0]); acc.y += bf2f(v[1]); acc.z += bf2f(v[2]); acc.w += bf2f(v[3]);
  }
  __shared__ float4 sh[256];
  sh[threadIdx.x] = acc;
  __syncthreads();
  for (int ofs = 128; ofs >= 32; ofs >>= 1) {
    if (threadIdx.x < (unsigned)ofs) {
      float4 o = sh[threadIdx.x + ofs];
      float4 a = sh[threadIdx.x];
      a.x += o.x; a.y += o.y; a.z += o.z; a.w += o.w;
      sh[threadIdx.x] = a;
    }
    __syncthreads();
  }
  if (threadIdx.x < 32) {
    float4 a = sh[threadIdx.x];
    float* o = out + (size_t)g * DF + part * 4;
    atomicAdd(o + 0, a.x);
    atomicAdd(o + 1, a.y);
    atomicAdd(o + 2, a.z);
    atomicAdd(o + 3, a.w);
  }
}

// per-graph: build comb[512], two MLP layers -> hbuf[g][128]
__global__ void head1_k(const float* __restrict__ psum, const int* __restrict__ pcnt,
                        const float* __restrict__ isum, const int* __restrict__ icnt,
                        const float* __restrict__ ss,
                        const float* __restrict__ gf_w1, const float* __restrict__ gf_b1,
                        const float* __restrict__ gf_w2, const float* __restrict__ gf_b2,
                        float* __restrict__ hbuf) {
  int g = blockIdx.x, j = threadIdx.x;  // 128 threads
  __shared__ float comb[4 * DF];
  __shared__ float t1[DF];
  int pc = pcnt[g], ic = icnt[g];
  float sc = ss[j], sh = ss[DF + j];
  float pf = pc > 0 ? (psum[(size_t)g * DF + j] / (float)pc) * sc + sh : 0.f;
  float im = ic > 0 ? (isum[(size_t)g * DF + j] / (float)ic) * sc + sh : 0.f;
  comb[j] = pf;
  comb[DF + j] = im;
  comb[2 * DF + j] = pf - im;
  comb[3 * DF + j] = pf * im;
  __syncthreads();
  float acc = gf_b1[j];
#pragma unroll 4
  for (int k = 0; k < 4 * DF; ++k) acc = fmaf(comb[k], gf_w1[(size_t)k * DF + j], acc);
  t1[j] = LEAKY(acc);
  __syncthreads();
  acc = gf_b2[j];
#pragma unroll 4
  for (int k = 0; k < DF; ++k) acc = fmaf(t1[k], gf_w2[(size_t)k * DF + j], acc);
  hbuf[(size_t)g * DF + j] = acc;
}

// BN2 over G rows of hbuf -> scale2/shift2 (single block, 128 threads)
__global__ void bn2_k(const float* __restrict__ hbuf, const float* __restrict__ gamma,
                      const float* __restrict__ beta, float* __restrict__ ss2, int G) {
  int c = threadIdx.x;
  float s = 0.f, q = 0.f;
  for (int r = 0; r < G; ++r) {
    float v = hbuf[(size_t)r * DF + c];
    s += v; q += v * v;
  }
  float m = s / (float)G;
  float var = q / (float)G - m * m;
  if (var < 0.f) var = 0.f;
  float sc = gamma[c] / sqrtf(var + 1e-5f);
  ss2[c] = sc;
  ss2[DF + c] = beta[c] - m * sc;
}

// per-graph: BN2-apply, 128->64 leaky, 64->32, 32->2; write out + prob
__global__ void head2_k(const float* __restrict__ hbuf, const float* __restrict__ ss2,
                        const float* __restrict__ fl_w1, const float* __restrict__ fl_b1,
                        const float* __restrict__ fl_w2, const float* __restrict__ fl_b2,
                        const float* __restrict__ out_w, const float* __restrict__ out_b,
                        float* __restrict__ d_out, int G) {
  int g = blockIdx.x, t = threadIdx.x;  // 128 threads
  __shared__ float hb[DF], t1[64], ov[32];
  hb[t] = hbuf[(size_t)g * DF + t] * ss2[t] + ss2[DF + t];
  __syncthreads();
  if (t < 64) {
    float acc = fl_b1[t];
#pragma unroll 4
    for (int c = 0; c < DF; ++c) acc = fmaf(hb[c], fl_w1[(size_t)c * 64 + t], acc);
    t1[t] = LEAKY(acc);
  }
  __syncthreads();
  if (t < 32) {
    float acc = fl_b2[t];
#pragma unroll 4
    for (int j = 0; j < 64; ++j) acc = fmaf(t1[j], fl_w2[(size_t)j * 32 + t], acc);
    d_out[(size_t)g * 32 + t] = acc;
    ov[t] = acc;
  }
  __syncthreads();
  if (t < 2) {
    float acc = out_b[t];
#pragma unroll
    for (int o = 0; o < 32; ++o) acc = fmaf(ov[o], out_w[(size_t)o * 2 + t], acc);
    d_out[(size_t)G * 32 + (size_t)g * 2 + t] = acc;
  }
}

extern "C" void kernel_launch(void* const* d_in, const int* in_sizes, int n_in,
                              void* d_out, int out_size, void* d_ws, size_t ws_size,
                              hipStream_t stream) {
  const float* x         = (const float*)d_in[0];
  const float* W_gnn     = (const float*)d_in[1];
  const float* b_gnn     = (const float*)d_in[2];
  const float* hbn_gamma = (const float*)d_in[3];
  const float* hbn_beta  = (const float*)d_in[4];
  const float* gf_w1     = (const float*)d_in[5];
  const float* gf_b1     = (const float*)d_in[6];
  const float* gf_w2     = (const float*)d_in[7];
  const float* gf_b2     = (const float*)d_in[8];
  const float* bn2_gamma = (const float*)d_in[9];
  const float* bn2_beta  = (const float*)d_in[10];
  const float* fl_w1     = (const float*)d_in[11];
  const float* fl_b1     = (const float*)d_in[12];
  const float* fl_w2     = (const float*)d_in[13];
  const float* fl_b2     = (const float*)d_in[14];
  const float* out_w     = (const float*)d_in[15];
  const float* out_b     = (const float*)d_in[16];
  const int* edge_index  = (const int*)d_in[17];
  const int* post_idx    = (const int*)d_in[18];
  const int* image_idx   = (const int*)d_in[19];
  const int* batch_vec   = (const int*)d_in[20];

  const int N  = in_sizes[20];
  const int E  = in_sizes[17] / 2;
  const int NP = in_sizes[18];
  const int NI = in_sizes[19];
  const int G  = out_size / 34;           // out: G*32 + prob: G*2
  const int L  = in_sizes[1] / (DF * DF);
  const int* src  = edge_index;
  const int* dstp = edge_index + E;
  const int NB = (N + 1023) / 1024;       // scan blocks

  char* ws = (char*)d_ws;
  size_t off = 0;
  auto alloc = [&](size_t b) { size_t o = off; off += (b + 255) & ~(size_t)255; return o; };
  float* dis    = (float*)(ws + alloc((size_t)N * 4));
  int*   degc   = (int*)(ws + alloc((size_t)N * 4));
  int*   rowoff = (int*)(ws + alloc((size_t)(N + 1) * 4));
  int*   cursor = (int*)(ws + alloc((size_t)N * 4));
  int*   eidx   = (int*)(ws + alloc((size_t)E * 4));
  float* enorm  = (float*)(ws + alloc((size_t)E * 4));
  int*   bsum   = (int*)(ws + alloc((size_t)(NB + 1) * 4));
  int*   boff   = (int*)(ws + alloc((size_t)(NB + 1) * 4));
  unsigned short* Wb  = (unsigned short*)(ws + alloc((size_t)L * DF * DF * 2));
  unsigned short* xwb = (unsigned short*)(ws + alloc((size_t)N * DF * 2));
  unsigned short* Hb  = (unsigned short*)(ws + alloc((size_t)N * DF * 2));
  float* bns    = (float*)(ws + alloc(256 * 4));
  float* ss     = (float*)(ws + alloc(256 * 4));
  float* psum   = (float*)(ws + alloc((size_t)G * DF * 4));
  float* isum   = (float*)(ws + alloc((size_t)G * DF * 4));
  int*   pcnt   = (int*)(ws + alloc((size_t)G * 4));
  int*   icnt   = (int*)(ws + alloc((size_t)G * 4));
  int*   poff   = (int*)(ws + alloc((size_t)(G + 1) * 4));
  int*   ioff   = (int*)(ws + alloc((size_t)(G + 1) * 4));
  int*   pcur   = (int*)(ws + alloc((size_t)G * 4));
  int*   icur   = (int*)(ws + alloc((size_t)G * 4));
  int*   plist  = (int*)(ws + alloc((size_t)NP * 4));
  int*   ilist  = (int*)(ws + alloc((size_t)NI * 4));
  float* hbuf   = (float*)(ws + alloc((size_t)G * DF * 4));
  float* ss2    = (float*)(ws + alloc(256 * 4));

  // degree + dis + CSR build (reused across both layers)
  hipMemsetAsync(degc, 0, (size_t)N * 4, stream);
  deg_count_k<<<(E + 255) / 256, 256, 0, stream>>>(dstp, degc, E);
  make_dis_k<<<(N + 255) / 256, 256, 0, stream>>>(degc, dis, N);
  blk_sum_k<<<NB, 1024, 0, stream>>>(degc, bsum, N);
  scan_small_k<<<1, 1024, 0, stream>>>(bsum, boff, NB);
  blk_scan_k<<<NB, 1024, 0, stream>>>(degc, boff, rowoff, cursor, N);
  csr_fill_k<<<(E + 255) / 256, 256, 0, stream>>>(src, dstp, dis, cursor, eidx, enorm, E);
  castW_k<<<(L * DF * DF + 255) / 256, 256, 0, stream>>>(W_gnn, Wb, L * DF * DF);

  // pool index grouping (independent of H; do it early)
  hipMemsetAsync(pcnt, 0, (size_t)G * 4, stream);
  hipMemsetAsync(icnt, 0, (size_t)G * 4, stream);
  pool_cnt_k<<<(NP + 255) / 256, 256, 0, stream>>>(post_idx, batch_vec, pcnt, NP);
  pool_cnt_k<<<(NI + 255) / 256, 256, 0, stream>>>(image_idx, batch_vec, icnt, NI);
  scan_small2_k<<<1, 1024, 0, stream>>>(pcnt, poff, pcur, G);
  scan_small2_k<<<1, 1024, 0, stream>>>(icnt, ioff, icur, G);
  pool_fill_k<<<(NP + 255) / 256, 256, 0, stream>>>(post_idx, batch_vec, pcur, plist, NP);
  pool_fill_k<<<(NI + 255) / 256, 256, 0, stream>>>(image_idx, batch_vec, icur, ilist, NI);

  // GNN layers (bf16 MFMA gemm + bf16 gather reads, f32 accumulate)
  for (int l = 0; l < L; ++l) {
    if (l == 0)
      gemm_mfma_k<false><<<(N + 31) / 32, 256, 0, stream>>>(x, nullptr,
          Wb + (size_t)l * DF * DF, xwb, N);
    else
      gemm_mfma_k<true><<<(N + 31) / 32, 256, 0, stream>>>(nullptr, Hb,
          Wb + (size_t)l * DF * DF, xwb, N);
    gather_k<<<(N * 16 + 255) / 256, 256, 0, stream>>>(xwb, rowoff, eidx, enorm, dis,
                                                       b_gnn + (size_t)l * DF, Hb, N);
  }

  // BN over H (fold into affine scale/shift)
  hipMemsetAsync(bns, 0, 256 * 4, stream);
  bn_stats_k<<<256, 256, 0, stream>>>(Hb, bns, N);
  bn_final_k<<<1, 128, 0, stream>>>(bns, hbn_gamma, hbn_beta, ss, N);

  // pooled sums via grouped gather
  hipMemsetAsync(psum, 0, (size_t)G * DF * 4, stream);
  hipMemsetAsync(isum, 0, (size_t)G * DF * 4, stream);
  dim3 pg(G * PSPLIT, 2);
  pool_gather_k<<<pg, 256, 0, stream>>>(Hb, poff, plist, ioff, ilist, psum, isum);

  // head
  head1_k<<<G, 128, 0, stream>>>(psum, pcnt, isum, icnt, ss, gf_w1, gf_b1, gf_w2, gf_b2, hbuf);
  bn2_k<<<1, 128, 0, stream>>>(hbuf, bn2_gamma, bn2_beta, ss2, G);
  head2_k<<<G, 128, 0, stream>>>(hbuf, ss2, fl_w1, fl_b1, fl_w2, fl_b2, out_w, out_b,
                                 (float*)d_out, G);
}

// Round 7
// 384.472 us; speedup vs baseline: 8.6594x; 1.1009x over previous
//
#include <hip/hip_runtime.h>
#include <hip/hip_bf16.h>
#include <math.h>

#define DF 128
#define PSPLIT 4
#define LEAKY(x) ((x) > 0.f ? (x) : 0.01f * (x))

typedef __attribute__((ext_vector_type(8))) short short8v;   // 8 bf16 in 4 VGPRs
typedef __attribute__((ext_vector_type(4))) float f32x4;
typedef __attribute__((ext_vector_type(4))) unsigned short u16x4;
typedef __attribute__((ext_vector_type(8))) unsigned short u16x8;

static __device__ __forceinline__ unsigned short f2bf(float f) {
  unsigned u = __float_as_uint(f);
  unsigned r = u + 0x7fffu + ((u >> 16) & 1u);   // RNE
  return (unsigned short)(r >> 16);
}
static __device__ __forceinline__ float bf2f(unsigned short b) {
  return __uint_as_float(((unsigned)b) << 16);
}

__global__ void deg_count_k(const int* __restrict__ dst, int* __restrict__ cnt, int nE) {
  int e = blockIdx.x * 256 + threadIdx.x;
  if (e < nE) atomicAdd(&cnt[dst[e]], 1);
}

__global__ void make_dis_k(const int* __restrict__ cnt, float* __restrict__ dis, int n) {
  int i = blockIdx.x * 256 + threadIdx.x;
  if (i < n) dis[i] = 1.0f / sqrtf((float)cnt[i] + 1.0f);
}

// ---- parallel scan: per-1024-block sums -> exclusive block offsets -> per-element scan ----
__global__ void blk_sum_k(const int* __restrict__ cnt, int* __restrict__ bsum, int n) {
  __shared__ int sh[1024];
  int idx = blockIdx.x * 1024 + threadIdx.x;
  sh[threadIdx.x] = (idx < n) ? cnt[idx] : 0;
  __syncthreads();
  for (int ofs = 512; ofs > 0; ofs >>= 1) {
    if (threadIdx.x < (unsigned)ofs) sh[threadIdx.x] += sh[threadIdx.x + ofs];
    __syncthreads();
  }
  if (threadIdx.x == 0) bsum[blockIdx.x] = sh[0];
}

// one block: exclusive scan of in[0..n) -> out[0..n], out[n] = total (n <= 1024)
__global__ void scan_small_k(const int* __restrict__ in, int* __restrict__ out, int n) {
  __shared__ int sh[1024];
  int v = (threadIdx.x < (unsigned)n) ? in[threadIdx.x] : 0;
  sh[threadIdx.x] = v;
  __syncthreads();
  for (int ofs = 1; ofs < 1024; ofs <<= 1) {
    int t = (threadIdx.x >= (unsigned)ofs) ? sh[threadIdx.x - ofs] : 0;
    __syncthreads();
    sh[threadIdx.x] += t;
    __syncthreads();
  }
  if (threadIdx.x < (unsigned)n) out[threadIdx.x] = sh[threadIdx.x] - v;
  if (threadIdx.x == 0) out[n] = sh[1023];
}

// same but also writes a cursor copy
__global__ void scan_small2_k(const int* __restrict__ in, int* __restrict__ out,
                              int* __restrict__ cur, int n) {
  __shared__ int sh[1024];
  int v = (threadIdx.x < (unsigned)n) ? in[threadIdx.x] : 0;
  sh[threadIdx.x] = v;
  __syncthreads();
  for (int ofs = 1; ofs < 1024; ofs <<= 1) {
    int t = (threadIdx.x >= (unsigned)ofs) ? sh[threadIdx.x - ofs] : 0;
    __syncthreads();
    sh[threadIdx.x] += t;
    __syncthreads();
  }
  if (threadIdx.x < (unsigned)n) {
    int ex = sh[threadIdx.x] - v;
    out[threadIdx.x] = ex;
    cur[threadIdx.x] = ex;
  }
  if (threadIdx.x == 0) out[n] = sh[1023];
}

__global__ void blk_scan_k(const int* __restrict__ cnt, const int* __restrict__ boff,
                           int* __restrict__ rowoff, int* __restrict__ cursor, int n) {
  __shared__ int sh[1024];
  int idx = blockIdx.x * 1024 + threadIdx.x;
  int v = (idx < n) ? cnt[idx] : 0;
  sh[threadIdx.x] = v;
  __syncthreads();
  for (int ofs = 1; ofs < 1024; ofs <<= 1) {
    int t = (threadIdx.x >= (unsigned)ofs) ? sh[threadIdx.x - ofs] : 0;
    __syncthreads();
    sh[threadIdx.x] += t;
    __syncthreads();
  }
  if (idx < n) {
    int ex = boff[blockIdx.x] + sh[threadIdx.x] - v;
    rowoff[idx] = ex; cursor[idx] = ex;
    if (idx == n - 1) rowoff[n] = ex + v;
  }
}

// CSR fill: single packed 8B scatter per edge {src, enorm}
__global__ void csr_fill_k(const int* __restrict__ src, const int* __restrict__ dst,
                           const float* __restrict__ dis, int* __restrict__ cursor,
                           int2* __restrict__ epack, int nE) {
  int e = blockIdx.x * 256 + threadIdx.x;
  if (e < nE) {
    int s = src[e], d = dst[e];
    int p = atomicAdd(&cursor[d], 1);
    int2 v;
    v.x = s;
    v.y = __float_as_int(dis[s] * dis[d]);
    epack[p] = v;
  }
}

// W -> bf16 in MFMA-fragment order: per layer, o = (((wc*4+ct)*4+ks)*64 + l)*8 + j
// maps to row = ks*32 + (l>>4)*8 + j, col = wc*64 + ct*16 + (l&15).
__global__ void castW_k(const float* __restrict__ W, unsigned short* __restrict__ Wb, int total) {
  int i = blockIdx.x * 256 + threadIdx.x;
  if (i >= total) return;
  int layer = i >> 14, o = i & 16383;
  int j = o & 7, l = (o >> 3) & 63, ks = (o >> 9) & 3, ct = (o >> 11) & 3, wc = (o >> 13) & 1;
  int row = ks * 32 + (l >> 4) * 8 + j;
  int col = wc * 64 + ct * 16 + (l & 15);
  Wb[i] = f2bf(W[((size_t)layer << 14) + row * DF + col]);
}

// xwb[r][c] = bf16( sum_k A[r][k] * W[k][c] ); A from f32 (layer0) or bf16 Hb.
template<bool BF16A>
__global__ void __launch_bounds__(256) gemm_mfma_k(const float* __restrict__ A,
                                                   const unsigned short* __restrict__ Ab,
                                                   const unsigned short* __restrict__ Wb,
                                                   unsigned short* __restrict__ xwb, int n) {
  const int w = threadIdx.x >> 6, l = threadIdx.x & 63;
  const int wr = w & 1, wc = w >> 1;
  const int r0 = blockIdx.x * 32 + wr * 16;
  const int row = r0 + (l & 15);
  const int kg = l >> 4;                 // 0..3
  short8v bf[4][4];
  const unsigned short* wp = Wb + (size_t)wc * 8192 + (size_t)l * 8;
#pragma unroll
  for (int ct = 0; ct < 4; ++ct)
#pragma unroll
    for (int ks = 0; ks < 4; ++ks)
      bf[ct][ks] = *(const short8v*)(wp + ((ct * 4 + ks) << 9));
  const bool rok = row < n;
  short8v af[4];
  if constexpr (BF16A) {
    const unsigned short* ap = Ab + (size_t)row * DF + kg * 8;
#pragma unroll
    for (int ks = 0; ks < 4; ++ks)
      af[ks] = rok ? *(const short8v*)(ap + ks * 32) : (short8v)0;
  } else {
    const float* ap = A + (size_t)row * DF + kg * 8;
#pragma unroll
    for (int ks = 0; ks < 4; ++ks) {
      if (rok) {
        float4 lo = *(const float4*)(ap + ks * 32);
        float4 hi = *(const float4*)(ap + ks * 32 + 4);
        short8v t;
        t[0] = (short)f2bf(lo.x); t[1] = (short)f2bf(lo.y);
        t[2] = (short)f2bf(lo.z); t[3] = (short)f2bf(lo.w);
        t[4] = (short)f2bf(hi.x); t[5] = (short)f2bf(hi.y);
        t[6] = (short)f2bf(hi.z); t[7] = (short)f2bf(hi.w);
        af[ks] = t;
      } else af[ks] = (short8v)0;
    }
  }
  f32x4 acc[4];
#pragma unroll
  for (int ct = 0; ct < 4; ++ct) acc[ct] = (f32x4)(0.f);
#pragma unroll
  for (int ks = 0; ks < 4; ++ks)
#pragma unroll
    for (int ct = 0; ct < 4; ++ct)
      acc[ct] = __builtin_amdgcn_mfma_f32_16x16x32_bf16(af[ks], bf[ct][ks], acc[ct], 0, 0, 0);
#pragma unroll
  for (int ct = 0; ct < 4; ++ct) {
    int c = wc * 64 + ct * 16 + (l & 15);
#pragma unroll
    for (int rg = 0; rg < 4; ++rg) {
      int r = r0 + kg * 4 + rg;
      if (r < n) xwb[(size_t)r * DF + c] = f2bf(acc[ct][rg]);
    }
  }
}

// CSR gather + self-loop + bias + leaky. 16 lanes/node, u16x8 loads, edge loop unrolled x4.
__global__ void gather_k(const unsigned short* __restrict__ xwb, const int* __restrict__ rowoff,
                         const int2* __restrict__ epack, const float* __restrict__ dis,
                         const float* __restrict__ b, unsigned short* __restrict__ Hb, int n) {
  int gid = blockIdx.x * 256 + threadIdx.x;
  int node = gid >> 4;
  if (node >= n) return;
  int part = gid & 15;
  int beg = rowoff[node], end = rowoff[node + 1];
  float acc[8];
#pragma unroll
  for (int j = 0; j < 8; ++j) acc[j] = 0.f;
  int p = beg;
  for (; p + 3 < end; p += 4) {
    int2 q0 = epack[p], q1 = epack[p + 1], q2 = epack[p + 2], q3 = epack[p + 3];
    float e0 = __int_as_float(q0.y), e1 = __int_as_float(q1.y);
    float e2 = __int_as_float(q2.y), e3 = __int_as_float(q3.y);
    u16x8 v0 = *(const u16x8*)(xwb + (size_t)q0.x * DF + part * 8);
    u16x8 v1 = *(const u16x8*)(xwb + (size_t)q1.x * DF + part * 8);
    u16x8 v2 = *(const u16x8*)(xwb + (size_t)q2.x * DF + part * 8);
    u16x8 v3 = *(const u16x8*)(xwb + (size_t)q3.x * DF + part * 8);
#pragma unroll
    for (int j = 0; j < 8; ++j) {
      acc[j] = fmaf(bf2f(v0[j]), e0, acc[j]);
      acc[j] = fmaf(bf2f(v1[j]), e1, acc[j]);
      acc[j] = fmaf(bf2f(v2[j]), e2, acc[j]);
      acc[j] = fmaf(bf2f(v3[j]), e3, acc[j]);
    }
  }
  for (; p < end; ++p) {
    int2 q = epack[p];
    float e = __int_as_float(q.y);
    u16x8 v = *(const u16x8*)(xwb + (size_t)q.x * DF + part * 8);
#pragma unroll
    for (int j = 0; j < 8; ++j) acc[j] = fmaf(bf2f(v[j]), e, acc[j]);
  }
  float dd = dis[node], sn = dd * dd;
  u16x8 xv = *(const u16x8*)(xwb + (size_t)node * DF + part * 8);
  const float* bp = b + part * 8;
  u16x8 o;
#pragma unroll
  for (int j = 0; j < 8; ++j) {
    float r = fmaf(bf2f(xv[j]), sn, acc[j]) + bp[j];
    r = LEAKY(r);
    o[j] = f2bf(r);
  }
  *(u16x8*)(Hb + (size_t)node * DF + part * 8) = o;
}

// per-column sum and sumsq over n rows of bf16 H -> sums[0..127]=sum, sums[128..255]=sumsq
__global__ void bn_stats_k(const unsigned short* __restrict__ Hb, float* __restrict__ sums, int n) {
  int c = threadIdx.x & (DF - 1);
  int half = threadIdx.x >> 7;
  float s = 0.f, q = 0.f;
  for (int r = blockIdx.x * 2 + half; r < n; r += gridDim.x * 2) {
    float v = bf2f(Hb[(size_t)r * DF + c]);
    s += v; q += v * v;
  }
  __shared__ float ls[256], lq[256];
  ls[threadIdx.x] = s; lq[threadIdx.x] = q;
  __syncthreads();
  if (half == 0) {
    atomicAdd(&sums[c], ls[c] + ls[c + DF]);
    atomicAdd(&sums[DF + c], lq[c] + lq[c + DF]);
  }
}

__global__ void bn_final_k(const float* __restrict__ sums, const float* __restrict__ gamma,
                           const float* __restrict__ beta, float* __restrict__ ss, int n) {
  int c = threadIdx.x;  // 128 threads, 1 block
  float m = sums[c] / (float)n;
  float var = sums[DF + c] / (float)n - m * m;
  if (var < 0.f) var = 0.f;
  float sc = gamma[c] / sqrtf(var + 1e-5f);
  ss[c] = sc;
  ss[DF + c] = beta[c] - m * sc;
}

// ---- pooling: group indices by graph, then gather ----
__global__ void pool_cnt_k(const int* __restrict__ idx, const int* __restrict__ batch,
                           int* __restrict__ cnt, int ni) {
  int i = blockIdx.x * 256 + threadIdx.x;
  if (i < ni) atomicAdd(&cnt[batch[idx[i]]], 1);
}

__global__ void pool_fill_k(const int* __restrict__ idx, const int* __restrict__ batch,
                            int* __restrict__ cursor, int* __restrict__ mlist, int ni) {
  int i = blockIdx.x * 256 + threadIdx.x;
  if (i < ni) {
    int nd = idx[i];
    int p = atomicAdd(&cursor[batch[nd]], 1);
    mlist[p] = nd;
  }
}

// grid: (G*PSPLIT, 2). Each block: partial sum of graph g's member rows -> one atomic per col.
__global__ void pool_gather_k(const unsigned short* __restrict__ Hb,
                              const int* __restrict__ goff_p, const int* __restrict__ mlist_p,
                              const int* __restrict__ goff_i, const int* __restrict__ mlist_i,
                              float* __restrict__ psum, float* __restrict__ isum) {
  int g = blockIdx.x / PSPLIT, sub = blockIdx.x % PSPLIT;
  const int* goff  = blockIdx.y ? goff_i  : goff_p;
  const int* mlist = blockIdx.y ? mlist_i : mlist_p;
  float* out       = blockIdx.y ? isum    : psum;
  int part = threadIdx.x & 31, slot = threadIdx.x >> 5;  // 8 row slots
  int beg = goff[g], end = goff[g + 1];
  float4 acc = make_float4(0.f, 0.f, 0.f, 0.f);
  for (int j = beg + sub * 8 + slot; j < end; j += PSPLIT * 8) {
    u16x4 v = *(const u16x4*)(Hb + (size_t)mlist[j] * DF + part * 4);
    acc.x += bf2f(v[0]); acc.y += bf2f(v[1]); acc.z += bf2f(v[2]); acc.w += bf2f(v[3]);
  }
  __shared__ float4 sh[256];
  sh[threadIdx.x] = acc;
  __syncthreads();
  for (int ofs = 128; ofs >= 32; ofs >>= 1) {
    if (threadIdx.x < (unsigned)ofs) {
      float4 o = sh[threadIdx.x + ofs];
      float4 a = sh[threadIdx.x];
      a.x += o.x; a.y += o.y; a.z += o.z; a.w += o.w;
      sh[threadIdx.x] = a;
    }
    __syncthreads();
  }
  if (threadIdx.x < 32) {
    float4 a = sh[threadIdx.x];
    float* o = out + (size_t)g * DF + part * 4;
    atomicAdd(o + 0, a.x);
    atomicAdd(o + 1, a.y);
    atomicAdd(o + 2, a.z);
    atomicAdd(o + 3, a.w);
  }
}

// per-graph head layer 1: 512 threads, 4-way split-K. comb[512] -> t1[128] -> hbuf[128]
__global__ void __launch_bounds__(512) head1_k(const float* __restrict__ psum,
                        const int* __restrict__ pcnt,
                        const float* __restrict__ isum, const int* __restrict__ icnt,
                        const float* __restrict__ ss,
                        const float* __restrict__ gf_w1, const float* __restrict__ gf_b1,
                        const float* __restrict__ gf_w2, const float* __restrict__ gf_b2,
                        float* __restrict__ hbuf) {
  int g = blockIdx.x;
  int j = threadIdx.x & 127, kq = threadIdx.x >> 7;  // 4 K-quarters
  __shared__ float comb[4 * DF];
  __shared__ float part[512];
  __shared__ float t1[DF];
  if (kq == 0) {
    int pc = pcnt[g], ic = icnt[g];
    float sc = ss[j], sh = ss[DF + j];
    float pf = pc > 0 ? (psum[(size_t)g * DF + j] / (float)pc) * sc + sh : 0.f;
    float im = ic > 0 ? (isum[(size_t)g * DF + j] / (float)ic) * sc + sh : 0.f;
    comb[j] = pf;
    comb[DF + j] = im;
    comb[2 * DF + j] = pf - im;
    comb[3 * DF + j] = pf * im;
  }
  __syncthreads();
  float acc = 0.f;
  const float* w1 = gf_w1 + (size_t)kq * 128 * DF + j;
#pragma unroll 8
  for (int kk = 0; kk < 128; ++kk)
    acc = fmaf(comb[kq * 128 + kk], w1[(size_t)kk * DF], acc);
  part[threadIdx.x] = acc;
  __syncthreads();
  if (kq == 0)
    t1[j] = LEAKY(gf_b1[j] + part[j] + part[128 + j] + part[256 + j] + part[384 + j]);
  __syncthreads();
  acc = 0.f;
  const float* w2 = gf_w2 + (size_t)kq * 32 * DF + j;
#pragma unroll 8
  for (int kk = 0; kk < 32; ++kk)
    acc = fmaf(t1[kq * 32 + kk], w2[(size_t)kk * DF], acc);
  part[threadIdx.x] = acc;
  __syncthreads();
  if (kq == 0)
    hbuf[(size_t)g * DF + j] = gf_b2[j] + part[j] + part[128 + j] + part[256 + j] + part[384 + j];
}

// BN2 over G rows of hbuf -> scale2/shift2 (single block, 128 threads)
__global__ void bn2_k(const float* __restrict__ hbuf, const float* __restrict__ gamma,
                      const float* __restrict__ beta, float* __restrict__ ss2, int G) {
  int c = threadIdx.x;
  float s = 0.f, q = 0.f;
  for (int r = 0; r < G; ++r) {
    float v = hbuf[(size_t)r * DF + c];
    s += v; q += v * v;
  }
  float m = s / (float)G;
  float var = q / (float)G - m * m;
  if (var < 0.f) var = 0.f;
  float sc = gamma[c] / sqrtf(var + 1e-5f);
  ss2[c] = sc;
  ss2[DF + c] = beta[c] - m * sc;
}

// per-graph: BN2-apply, 128->64 leaky, 64->32, 32->2; write out + prob
__global__ void head2_k(const float* __restrict__ hbuf, const float* __restrict__ ss2,
                        const float* __restrict__ fl_w1, const float* __restrict__ fl_b1,
                        const float* __restrict__ fl_w2, const float* __restrict__ fl_b2,
                        const float* __restrict__ out_w, const float* __restrict__ out_b,
                        float* __restrict__ d_out, int G) {
  int g = blockIdx.x, t = threadIdx.x;  // 128 threads
  __shared__ float hb[DF], t1[64], ov[32];
  hb[t] = hbuf[(size_t)g * DF + t] * ss2[t] + ss2[DF + t];
  __syncthreads();
  if (t < 64) {
    float acc = fl_b1[t];
#pragma unroll 4
    for (int c = 0; c < DF; ++c) acc = fmaf(hb[c], fl_w1[(size_t)c * 64 + t], acc);
    t1[t] = LEAKY(acc);
  }
  __syncthreads();
  if (t < 32) {
    float acc = fl_b2[t];
#pragma unroll 4
    for (int j = 0; j < 64; ++j) acc = fmaf(t1[j], fl_w2[(size_t)j * 32 + t], acc);
    d_out[(size_t)g * 32 + t] = acc;
    ov[t] = acc;
  }
  __syncthreads();
  if (t < 2) {
    float acc = out_b[t];
#pragma unroll
    for (int o = 0; o < 32; ++o) acc = fmaf(ov[o], out_w[(size_t)o * 2 + t], acc);
    d_out[(size_t)G * 32 + (size_t)g * 2 + t] = acc;
  }
}

extern "C" void kernel_launch(void* const* d_in, const int* in_sizes, int n_in,
                              void* d_out, int out_size, void* d_ws, size_t ws_size,
                              hipStream_t stream) {
  const float* x         = (const float*)d_in[0];
  const float* W_gnn     = (const float*)d_in[1];
  const float* b_gnn     = (const float*)d_in[2];
  const float* hbn_gamma = (const float*)d_in[3];
  const float* hbn_beta  = (const float*)d_in[4];
  const float* gf_w1     = (const float*)d_in[5];
  const float* gf_b1     = (const float*)d_in[6];
  const float* gf_w2     = (const float*)d_in[7];
  const float* gf_b2     = (const float*)d_in[8];
  const float* bn2_gamma = (const float*)d_in[9];
  const float* bn2_beta  = (const float*)d_in[10];
  const float* fl_w1     = (const float*)d_in[11];
  const float* fl_b1     = (const float*)d_in[12];
  const float* fl_w2     = (const float*)d_in[13];
  const float* fl_b2     = (const float*)d_in[14];
  const float* out_w     = (const float*)d_in[15];
  const float* out_b     = (const float*)d_in[16];
  const int* edge_index  = (const int*)d_in[17];
  const int* post_idx    = (const int*)d_in[18];
  const int* image_idx   = (const int*)d_in[19];
  const int* batch_vec   = (const int*)d_in[20];

  const int N  = in_sizes[20];
  const int E  = in_sizes[17] / 2;
  const int NP = in_sizes[18];
  const int NI = in_sizes[19];
  const int G  = out_size / 34;           // out: G*32 + prob: G*2
  const int L  = in_sizes[1] / (DF * DF);
  const int* src  = edge_index;
  const int* dstp = edge_index + E;
  const int NB = (N + 1023) / 1024;       // scan blocks

  char* ws = (char*)d_ws;
  size_t off = 0;
  auto alloc = [&](size_t b) { size_t o = off; off += (b + 255) & ~(size_t)255; return o; };
  float* dis    = (float*)(ws + alloc((size_t)N * 4));
  int*   degc   = (int*)(ws + alloc((size_t)N * 4));
  int*   rowoff = (int*)(ws + alloc((size_t)(N + 1) * 4));
  int*   cursor = (int*)(ws + alloc((size_t)N * 4));
  int2*  epack  = (int2*)(ws + alloc((size_t)E * 8));
  int*   bsum   = (int*)(ws + alloc((size_t)(NB + 1) * 4));
  int*   boff   = (int*)(ws + alloc((size_t)(NB + 1) * 4));
  unsigned short* Wb  = (unsigned short*)(ws + alloc((size_t)L * DF * DF * 2));
  unsigned short* xwb = (unsigned short*)(ws + alloc((size_t)N * DF * 2));
  unsigned short* Hb  = (unsigned short*)(ws + alloc((size_t)N * DF * 2));
  float* bns    = (float*)(ws + alloc(256 * 4));
  float* ss     = (float*)(ws + alloc(256 * 4));
  float* psum   = (float*)(ws + alloc((size_t)G * DF * 4));
  float* isum   = (float*)(ws + alloc((size_t)G * DF * 4));
  int*   pcnt   = (int*)(ws + alloc((size_t)G * 4));
  int*   icnt   = (int*)(ws + alloc((size_t)G * 4));
  int*   poff   = (int*)(ws + alloc((size_t)(G + 1) * 4));
  int*   ioff   = (int*)(ws + alloc((size_t)(G + 1) * 4));
  int*   pcur   = (int*)(ws + alloc((size_t)G * 4));
  int*   icur   = (int*)(ws + alloc((size_t)G * 4));
  int*   plist  = (int*)(ws + alloc((size_t)NP * 4));
  int*   ilist  = (int*)(ws + alloc((size_t)NI * 4));
  float* hbuf   = (float*)(ws + alloc((size_t)G * DF * 4));
  float* ss2    = (float*)(ws + alloc(256 * 4));

  // degree + dis + CSR build (reused across both layers)
  hipMemsetAsync(degc, 0, (size_t)N * 4, stream);
  deg_count_k<<<(E + 255) / 256, 256, 0, stream>>>(dstp, degc, E);
  make_dis_k<<<(N + 255) / 256, 256, 0, stream>>>(degc, dis, N);
  blk_sum_k<<<NB, 1024, 0, stream>>>(degc, bsum, N);
  scan_small_k<<<1, 1024, 0, stream>>>(bsum, boff, NB);
  blk_scan_k<<<NB, 1024, 0, stream>>>(degc, boff, rowoff, cursor, N);
  csr_fill_k<<<(E + 255) / 256, 256, 0, stream>>>(src, dstp, dis, cursor, epack, E);
  castW_k<<<(L * DF * DF + 255) / 256, 256, 0, stream>>>(W_gnn, Wb, L * DF * DF);

  // pool index grouping (independent of H; do it early)
  hipMemsetAsync(pcnt, 0, (size_t)G * 4, stream);
  hipMemsetAsync(icnt, 0, (size_t)G * 4, stream);
  pool_cnt_k<<<(NP + 255) / 256, 256, 0, stream>>>(post_idx, batch_vec, pcnt, NP);
  pool_cnt_k<<<(NI + 255) / 256, 256, 0, stream>>>(image_idx, batch_vec, icnt, NI);
  scan_small2_k<<<1, 1024, 0, stream>>>(pcnt, poff, pcur, G);
  scan_small2_k<<<1, 1024, 0, stream>>>(icnt, ioff, icur, G);
  pool_fill_k<<<(NP + 255) / 256, 256, 0, stream>>>(post_idx, batch_vec, pcur, plist, NP);
  pool_fill_k<<<(NI + 255) / 256, 256, 0, stream>>>(image_idx, batch_vec, icur, ilist, NI);

  // GNN layers (bf16 MFMA gemm + bf16 gather reads, f32 accumulate)
  for (int l = 0; l < L; ++l) {
    if (l == 0)
      gemm_mfma_k<false><<<(N + 31) / 32, 256, 0, stream>>>(x, nullptr,
          Wb + (size_t)l * DF * DF, xwb, N);
    else
      gemm_mfma_k<true><<<(N + 31) / 32, 256, 0, stream>>>(nullptr, Hb,
          Wb + (size_t)l * DF * DF, xwb, N);
    gather_k<<<(N * 16 + 255) / 256, 256, 0, stream>>>(xwb, rowoff, epack, dis,
                                                       b_gnn + (size_t)l * DF, Hb, N);
  }

  // BN over H (fold into affine scale/shift)
  hipMemsetAsync(bns, 0, 256 * 4, stream);
  bn_stats_k<<<256, 256, 0, stream>>>(Hb, bns, N);
  bn_final_k<<<1, 128, 0, stream>>>(bns, hbn_gamma, hbn_beta, ss, N);

  // pooled sums via grouped gather
  hipMemsetAsync(psum, 0, (size_t)G * DF * 4, stream);
  hipMemsetAsync(isum, 0, (size_t)G * DF * 4, stream);
  dim3 pg(G * PSPLIT, 2);
  pool_gather_k<<<pg, 256, 0, stream>>>(Hb, poff, plist, ioff, ilist, psum, isum);

  // head
  head1_k<<<G, 512, 0, stream>>>(psum, pcnt, isum, icnt, ss, gf_w1, gf_b1, gf_w2, gf_b2, hbuf);
  bn2_k<<<1, 128, 0, stream>>>(hbuf, bn2_gamma, bn2_beta, ss2, G);
  head2_k<<<G, 128, 0, stream>>>(hbuf, ss2, fl_w1, fl_b1, fl_w2, fl_b2, out_w, out_b,
                                 (float*)d_out, G);
}

// Round 8
// 330.230 us; speedup vs baseline: 10.0817x; 1.1643x over previous
//
#include <hip/hip_runtime.h>
#include <hip/hip_bf16.h>
#include <math.h>

#define DF 128
#define PSPLIT 4
#define CHUNK 8192
#define NBK 256
#define LEAKY(x) ((x) > 0.f ? (x) : 0.01f * (x))

typedef __attribute__((ext_vector_type(8))) short short8v;   // 8 bf16 in 4 VGPRs
typedef __attribute__((ext_vector_type(4))) float f32x4;
typedef __attribute__((ext_vector_type(4))) unsigned short u16x4;
typedef __attribute__((ext_vector_type(8))) unsigned short u16x8;

static __device__ __forceinline__ unsigned short f2bf(float f) {
  unsigned u = __float_as_uint(f);
  unsigned r = u + 0x7fffu + ((u >> 16) & 1u);   // RNE
  return (unsigned short)(r >> 16);
}
static __device__ __forceinline__ float bf2f(unsigned short b) {
  return __uint_as_float(((unsigned)b) << 16);
}

// degree count (global atomics) + 256-node-bucket histogram (LDS -> global)
__global__ void deg_bucket_k(const int* __restrict__ dst, int* __restrict__ degc,
                             int* __restrict__ bhist, int nE) {
  __shared__ int lh[NBK];
  for (int i = threadIdx.x; i < NBK; i += 256) lh[i] = 0;
  __syncthreads();
  for (int i = blockIdx.x * 256 + threadIdx.x; i < nE; i += gridDim.x * 256) {
    int d = dst[i];
    atomicAdd(&degc[d], 1);
    atomicAdd(&lh[d >> 8], 1);
  }
  __syncthreads();
  for (int i = threadIdx.x; i < NBK; i += 256)
    if (lh[i]) atomicAdd(&bhist[i], lh[i]);
}

__global__ void make_dis_k(const int* __restrict__ cnt, float* __restrict__ dis, int n) {
  int i = blockIdx.x * 256 + threadIdx.x;
  if (i < n) dis[i] = 1.0f / sqrtf((float)cnt[i] + 1.0f);
}

// ---- parallel scan: per-1024-block sums -> exclusive block offsets -> per-element scan ----
__global__ void blk_sum_k(const int* __restrict__ cnt, int* __restrict__ bsum, int n) {
  __shared__ int sh[1024];
  int idx = blockIdx.x * 1024 + threadIdx.x;
  sh[threadIdx.x] = (idx < n) ? cnt[idx] : 0;
  __syncthreads();
  for (int ofs = 512; ofs > 0; ofs >>= 1) {
    if (threadIdx.x < (unsigned)ofs) sh[threadIdx.x] += sh[threadIdx.x + ofs];
    __syncthreads();
  }
  if (threadIdx.x == 0) bsum[blockIdx.x] = sh[0];
}

// one block: exclusive scan of in[0..n) -> out[0..n], out[n] = total (n <= 1024)
__global__ void scan_small_k(const int* __restrict__ in, int* __restrict__ out, int n) {
  __shared__ int sh[1024];
  int v = (threadIdx.x < (unsigned)n) ? in[threadIdx.x] : 0;
  sh[threadIdx.x] = v;
  __syncthreads();
  for (int ofs = 1; ofs < 1024; ofs <<= 1) {
    int t = (threadIdx.x >= (unsigned)ofs) ? sh[threadIdx.x - ofs] : 0;
    __syncthreads();
    sh[threadIdx.x] += t;
    __syncthreads();
  }
  if (threadIdx.x < (unsigned)n) out[threadIdx.x] = sh[threadIdx.x] - v;
  if (threadIdx.x == 0) out[n] = sh[1023];
}

// same but also writes a cursor copy
__global__ void scan_small2_k(const int* __restrict__ in, int* __restrict__ out,
                              int* __restrict__ cur, int n) {
  __shared__ int sh[1024];
  int v = (threadIdx.x < (unsigned)n) ? in[threadIdx.x] : 0;
  sh[threadIdx.x] = v;
  __syncthreads();
  for (int ofs = 1; ofs < 1024; ofs <<= 1) {
    int t = (threadIdx.x >= (unsigned)ofs) ? sh[threadIdx.x - ofs] : 0;
    __syncthreads();
    sh[threadIdx.x] += t;
    __syncthreads();
  }
  if (threadIdx.x < (unsigned)n) {
    int ex = sh[threadIdx.x] - v;
    out[threadIdx.x] = ex;
    cur[threadIdx.x] = ex;
  }
  if (threadIdx.x == 0) out[n] = sh[1023];
}

// dual scan for pool groups: blockIdx 0 -> p, 1 -> i
__global__ void pool_scan2_k(const int* __restrict__ pcnt, const int* __restrict__ icnt,
                             int* __restrict__ poff, int* __restrict__ ioff,
                             int* __restrict__ pcur, int* __restrict__ icur, int n) {
  const int* in = blockIdx.x ? icnt : pcnt;
  int* out = blockIdx.x ? ioff : poff;
  int* cur = blockIdx.x ? icur : pcur;
  __shared__ int sh[1024];
  int v = (threadIdx.x < (unsigned)n) ? in[threadIdx.x] : 0;
  sh[threadIdx.x] = v;
  __syncthreads();
  for (int ofs = 1; ofs < 1024; ofs <<= 1) {
    int t = (threadIdx.x >= (unsigned)ofs) ? sh[threadIdx.x - ofs] : 0;
    __syncthreads();
    sh[threadIdx.x] += t;
    __syncthreads();
  }
  if (threadIdx.x < (unsigned)n) {
    int ex = sh[threadIdx.x] - v;
    out[threadIdx.x] = ex;
    cur[threadIdx.x] = ex;
  }
  if (threadIdx.x == 0) out[n] = sh[1023];
}

__global__ void blk_scan_k(const int* __restrict__ cnt, const int* __restrict__ boff,
                           int* __restrict__ rowoff, int* __restrict__ cursor, int n) {
  __shared__ int sh[1024];
  int idx = blockIdx.x * 1024 + threadIdx.x;
  int v = (idx < n) ? cnt[idx] : 0;
  sh[threadIdx.x] = v;
  __syncthreads();
  for (int ofs = 1; ofs < 1024; ofs <<= 1) {
    int t = (threadIdx.x >= (unsigned)ofs) ? sh[threadIdx.x - ofs] : 0;
    __syncthreads();
    sh[threadIdx.x] += t;
    __syncthreads();
  }
  if (idx < n) {
    int ex = boff[blockIdx.x] + sh[threadIdx.x] - v;
    rowoff[idx] = ex; cursor[idx] = ex;
    if (idx == n - 1) rowoff[n] = ex + v;
  }
}

// pass B: LDS counting-sort of an 8192-edge chunk into dst-buckets, burst-write bucket-major
__global__ void __launch_bounds__(256) bucket_fill_k(const int* __restrict__ src,
                                                     const int* __restrict__ dst,
                                                     int* __restrict__ bcur,
                                                     int* __restrict__ ebuck, int nE) {
  __shared__ int hist[NBK];
  __shared__ int base[NBK];
  __shared__ int gbase[NBK];
  __shared__ int lpack[CHUNK];
  __shared__ unsigned char lbk[CHUNK];
  int e0 = blockIdx.x * CHUNK;
  int cnt = nE - e0; if (cnt > CHUNK) cnt = CHUNK;
  for (int i = threadIdx.x; i < NBK; i += 256) hist[i] = 0;
  __syncthreads();
  for (int i = threadIdx.x; i < cnt; i += 256)
    atomicAdd(&hist[dst[e0 + i] >> 8], 1);
  __syncthreads();
  // inclusive scan of hist (256 entries, 256 threads)
  int t = threadIdx.x;
  base[t] = hist[t];
  __syncthreads();
  for (int ofs = 1; ofs < NBK; ofs <<= 1) {
    int tv = (t >= ofs) ? base[t - ofs] : 0;
    __syncthreads();
    base[t] += tv;
    __syncthreads();
  }
  int excl = base[t] - hist[t];
  __syncthreads();
  base[t] = excl;          // exclusive base
  hist[t] = 0;             // reuse as local cursor
  __syncthreads();
  for (int i = threadIdx.x; i < cnt; i += 256) {
    int d = dst[e0 + i], s = src[e0 + i];
    int bk = d >> 8;
    int pos = base[bk] + atomicAdd(&hist[bk], 1);
    lpack[pos] = (s << 8) | (d & 255);
    lbk[pos] = (unsigned char)bk;
  }
  __syncthreads();
  int c = hist[t];
  gbase[t] = c > 0 ? atomicAdd(&bcur[t], c) : 0;
  __syncthreads();
  for (int i = threadIdx.x; i < cnt; i += 256) {
    int bk = lbk[i];
    ebuck[gbase[bk] + (i - base[bk])] = lpack[i];
  }
}

// pass C: one block owns one bucket's CSR region -> exclusive-XCD fine scatter
__global__ void __launch_bounds__(512) csr_fine_k(const int* __restrict__ boff2,
                                                  const int* __restrict__ ebuck,
                                                  const float* __restrict__ dis,
                                                  int* __restrict__ cursor,
                                                  int2* __restrict__ epack) {
  int b = blockIdx.x;
  int beg = boff2[b], end = boff2[b + 1];
  int node0 = b << 8;
  for (int i = beg + threadIdx.x; i < end; i += 512) {
    int v = ebuck[i];
    int s = v >> 8, d = node0 + (v & 255);
    int p = atomicAdd(&cursor[d], 1);
    int2 w; w.x = s; w.y = __float_as_int(dis[s] * dis[d]);
    epack[p] = w;
  }
}

// W -> bf16 in MFMA-fragment order
__global__ void castW_k(const float* __restrict__ W, unsigned short* __restrict__ Wb, int total) {
  int i = blockIdx.x * 256 + threadIdx.x;
  if (i >= total) return;
  int layer = i >> 14, o = i & 16383;
  int j = o & 7, l = (o >> 3) & 63, ks = (o >> 9) & 3, ct = (o >> 11) & 3, wc = (o >> 13) & 1;
  int row = ks * 32 + (l >> 4) * 8 + j;
  int col = wc * 64 + ct * 16 + (l & 15);
  Wb[i] = f2bf(W[((size_t)layer << 14) + row * DF + col]);
}

// xwb[r][c] = bf16( sum_k A[r][k] * W[k][c] ); A from f32 (layer0) or bf16 Hb.
template<bool BF16A>
__global__ void __launch_bounds__(256) gemm_mfma_k(const float* __restrict__ A,
                                                   const unsigned short* __restrict__ Ab,
                                                   const unsigned short* __restrict__ Wb,
                                                   unsigned short* __restrict__ xwb, int n) {
  const int w = threadIdx.x >> 6, l = threadIdx.x & 63;
  const int wr = w & 1, wc = w >> 1;
  const int r0 = blockIdx.x * 32 + wr * 16;
  const int row = r0 + (l & 15);
  const int kg = l >> 4;                 // 0..3
  short8v bf[4][4];
  const unsigned short* wp = Wb + (size_t)wc * 8192 + (size_t)l * 8;
#pragma unroll
  for (int ct = 0; ct < 4; ++ct)
#pragma unroll
    for (int ks = 0; ks < 4; ++ks)
      bf[ct][ks] = *(const short8v*)(wp + ((ct * 4 + ks) << 9));
  const bool rok = row < n;
  short8v af[4];
  if constexpr (BF16A) {
    const unsigned short* ap = Ab + (size_t)row * DF + kg * 8;
#pragma unroll
    for (int ks = 0; ks < 4; ++ks)
      af[ks] = rok ? *(const short8v*)(ap + ks * 32) : (short8v)0;
  } else {
    const float* ap = A + (size_t)row * DF + kg * 8;
#pragma unroll
    for (int ks = 0; ks < 4; ++ks) {
      if (rok) {
        float4 lo = *(const float4*)(ap + ks * 32);
        float4 hi = *(const float4*)(ap + ks * 32 + 4);
        short8v t;
        t[0] = (short)f2bf(lo.x); t[1] = (short)f2bf(lo.y);
        t[2] = (short)f2bf(lo.z); t[3] = (short)f2bf(lo.w);
        t[4] = (short)f2bf(hi.x); t[5] = (short)f2bf(hi.y);
        t[6] = (short)f2bf(hi.z); t[7] = (short)f2bf(hi.w);
        af[ks] = t;
      } else af[ks] = (short8v)0;
    }
  }
  f32x4 acc[4];
#pragma unroll
  for (int ct = 0; ct < 4; ++ct) acc[ct] = (f32x4)(0.f);
#pragma unroll
  for (int ks = 0; ks < 4; ++ks)
#pragma unroll
    for (int ct = 0; ct < 4; ++ct)
      acc[ct] = __builtin_amdgcn_mfma_f32_16x16x32_bf16(af[ks], bf[ct][ks], acc[ct], 0, 0, 0);
#pragma unroll
  for (int ct = 0; ct < 4; ++ct) {
    int c = wc * 64 + ct * 16 + (l & 15);
#pragma unroll
    for (int rg = 0; rg < 4; ++rg) {
      int r = r0 + kg * 4 + rg;
      if (r < n) xwb[(size_t)r * DF + c] = f2bf(acc[ct][rg]);
    }
  }
}

// CSR gather + self-loop + bias + leaky. 16 lanes/node, u16x8 loads, edge loop unrolled x4.
__global__ void gather_k(const unsigned short* __restrict__ xwb, const int* __restrict__ rowoff,
                         const int2* __restrict__ epack, const float* __restrict__ dis,
                         const float* __restrict__ b, unsigned short* __restrict__ Hb, int n) {
  int gid = blockIdx.x * 256 + threadIdx.x;
  int node = gid >> 4;
  if (node >= n) return;
  int part = gid & 15;
  int beg = rowoff[node], end = rowoff[node + 1];
  float acc[8];
#pragma unroll
  for (int j = 0; j < 8; ++j) acc[j] = 0.f;
  int p = beg;
  for (; p + 3 < end; p += 4) {
    int2 q0 = epack[p], q1 = epack[p + 1], q2 = epack[p + 2], q3 = epack[p + 3];
    float e0 = __int_as_float(q0.y), e1 = __int_as_float(q1.y);
    float e2 = __int_as_float(q2.y), e3 = __int_as_float(q3.y);
    u16x8 v0 = *(const u16x8*)(xwb + (size_t)q0.x * DF + part * 8);
    u16x8 v1 = *(const u16x8*)(xwb + (size_t)q1.x * DF + part * 8);
    u16x8 v2 = *(const u16x8*)(xwb + (size_t)q2.x * DF + part * 8);
    u16x8 v3 = *(const u16x8*)(xwb + (size_t)q3.x * DF + part * 8);
#pragma unroll
    for (int j = 0; j < 8; ++j) {
      acc[j] = fmaf(bf2f(v0[j]), e0, acc[j]);
      acc[j] = fmaf(bf2f(v1[j]), e1, acc[j]);
      acc[j] = fmaf(bf2f(v2[j]), e2, acc[j]);
      acc[j] = fmaf(bf2f(v3[j]), e3, acc[j]);
    }
  }
  for (; p < end; ++p) {
    int2 q = epack[p];
    float e = __int_as_float(q.y);
    u16x8 v = *(const u16x8*)(xwb + (size_t)q.x * DF + part * 8);
#pragma unroll
    for (int j = 0; j < 8; ++j) acc[j] = fmaf(bf2f(v[j]), e, acc[j]);
  }
  float dd = dis[node], sn = dd * dd;
  u16x8 xv = *(const u16x8*)(xwb + (size_t)node * DF + part * 8);
  const float* bp = b + part * 8;
  u16x8 o;
#pragma unroll
  for (int j = 0; j < 8; ++j) {
    float r = fmaf(bf2f(xv[j]), sn, acc[j]) + bp[j];
    r = LEAKY(r);
    o[j] = f2bf(r);
  }
  *(u16x8*)(Hb + (size_t)node * DF + part * 8) = o;
}

// per-column sum and sumsq over n rows of bf16 H
__global__ void bn_stats_k(const unsigned short* __restrict__ Hb, float* __restrict__ sums, int n) {
  int c = threadIdx.x & (DF - 1);
  int half = threadIdx.x >> 7;
  float s = 0.f, q = 0.f;
  for (int r = blockIdx.x * 2 + half; r < n; r += gridDim.x * 2) {
    float v = bf2f(Hb[(size_t)r * DF + c]);
    s += v; q += v * v;
  }
  __shared__ float ls[256], lq[256];
  ls[threadIdx.x] = s; lq[threadIdx.x] = q;
  __syncthreads();
  if (half == 0) {
    atomicAdd(&sums[c], ls[c] + ls[c + DF]);
    atomicAdd(&sums[DF + c], lq[c] + lq[c + DF]);
  }
}

// ---- pooling: group indices by graph (fused post+image), then gather ----
__global__ void pool_cnt_k(const int* __restrict__ post_idx, const int* __restrict__ image_idx,
                           const int* __restrict__ batch, int* __restrict__ pcnt,
                           int* __restrict__ icnt, int NP, int NI) {
  int i = blockIdx.x * 256 + threadIdx.x;
  if (i < NP) atomicAdd(&pcnt[batch[post_idx[i]]], 1);
  else if (i < NP + NI) atomicAdd(&icnt[batch[image_idx[i - NP]]], 1);
}

__global__ void pool_fill_k(const int* __restrict__ post_idx, const int* __restrict__ image_idx,
                            const int* __restrict__ batch, int* __restrict__ pcur,
                            int* __restrict__ icur, int* __restrict__ plist,
                            int* __restrict__ ilist, int NP, int NI) {
  int i = blockIdx.x * 256 + threadIdx.x;
  if (i < NP) {
    int nd = post_idx[i];
    int p = atomicAdd(&pcur[batch[nd]], 1);
    plist[p] = nd;
  } else if (i < NP + NI) {
    int nd = image_idx[i - NP];
    int p = atomicAdd(&icur[batch[nd]], 1);
    ilist[p] = nd;
  }
}

// grid: (G*PSPLIT, 2). Each block: partial sum of graph g's member rows -> one atomic per col.
__global__ void pool_gather_k(const unsigned short* __restrict__ Hb,
                              const int* __restrict__ goff_p, const int* __restrict__ mlist_p,
                              const int* __restrict__ goff_i, const int* __restrict__ mlist_i,
                              float* __restrict__ psum, float* __restrict__ isum) {
  int g = blockIdx.x / PSPLIT, sub = blockIdx.x % PSPLIT;
  const int* goff  = blockIdx.y ? goff_i  : goff_p;
  const int* mlist = blockIdx.y ? mlist_i : mlist_p;
  float* out       = blockIdx.y ? isum    : psum;
  int part = threadIdx.x & 31, slot = threadIdx.x >> 5;  // 8 row slots
  int beg = goff[g], end = goff[g + 1];
  float4 acc = make_float4(0.f, 0.f, 0.f, 0.f);
  for (int j = beg + sub * 8 + slot; j < end; j += PSPLIT * 8) {
    u16x4 v = *(const u16x4*)(Hb + (size_t)mlist[j] * DF + part * 4);
    acc.x += bf2f(v[0]); acc.y += bf2f(v[1]); acc.z += bf2f(v[2]); acc.w += bf2f(v[3]);
  }
  __shared__ float4 sh[256];
  sh[threadIdx.x] = acc;
  __syncthreads();
  for (int ofs = 128; ofs >= 32; ofs >>= 1) {
    if (threadIdx.x < (unsigned)ofs) {
      float4 o = sh[threadIdx.x + ofs];
      float4 a = sh[threadIdx.x];
      a.x += o.x; a.y += o.y; a.z += o.z; a.w += o.w;
      sh[threadIdx.x] = a;
    }
    __syncthreads();
  }
  if (threadIdx.x < 32) {
    float4 a = sh[threadIdx.x];
    float* o = out + (size_t)g * DF + part * 4;
    atomicAdd(o + 0, a.x);
    atomicAdd(o + 1, a.y);
    atomicAdd(o + 2, a.z);
    atomicAdd(o + 3, a.w);
  }
}

// head layer 1 (folds bn_final): 512 threads, 4-way split-K
__global__ void __launch_bounds__(512) head1_k(const float* __restrict__ psum,
                        const int* __restrict__ pcnt,
                        const float* __restrict__ isum, const int* __restrict__ icnt,
                        const float* __restrict__ bns, const float* __restrict__ hbn_gamma,
                        const float* __restrict__ hbn_beta, int nN,
                        const float* __restrict__ gf_w1, const float* __restrict__ gf_b1,
                        const float* __restrict__ gf_w2, const float* __restrict__ gf_b2,
                        float* __restrict__ hbuf) {
  int g = blockIdx.x;
  int j = threadIdx.x & 127, kq = threadIdx.x >> 7;  // 4 K-quarters
  __shared__ float comb[4 * DF];
  __shared__ float part[512];
  __shared__ float t1[DF];
  if (kq == 0) {
    float m = bns[j] / (float)nN;
    float var = bns[DF + j] / (float)nN - m * m;
    if (var < 0.f) var = 0.f;
    float sc = hbn_gamma[j] / sqrtf(var + 1e-5f);
    float sh = hbn_beta[j] - m * sc;
    int pc = pcnt[g], ic = icnt[g];
    float pf = pc > 0 ? (psum[(size_t)g * DF + j] / (float)pc) * sc + sh : 0.f;
    float im = ic > 0 ? (isum[(size_t)g * DF + j] / (float)ic) * sc + sh : 0.f;
    comb[j] = pf;
    comb[DF + j] = im;
    comb[2 * DF + j] = pf - im;
    comb[3 * DF + j] = pf * im;
  }
  __syncthreads();
  float acc = 0.f;
  const float* w1 = gf_w1 + (size_t)kq * 128 * DF + j;
#pragma unroll 8
  for (int kk = 0; kk < 128; ++kk)
    acc = fmaf(comb[kq * 128 + kk], w1[(size_t)kk * DF], acc);
  part[threadIdx.x] = acc;
  __syncthreads();
  if (kq == 0)
    t1[j] = LEAKY(gf_b1[j] + part[j] + part[128 + j] + part[256 + j] + part[384 + j]);
  __syncthreads();
  acc = 0.f;
  const float* w2 = gf_w2 + (size_t)kq * 32 * DF + j;
#pragma unroll 8
  for (int kk = 0; kk < 32; ++kk)
    acc = fmaf(t1[kq * 32 + kk], w2[(size_t)kk * DF], acc);
  part[threadIdx.x] = acc;
  __syncthreads();
  if (kq == 0)
    hbuf[(size_t)g * DF + j] = gf_b2[j] + part[j] + part[128 + j] + part[256 + j] + part[384 + j];
}

// head2 (folds bn2): per-block redundant BN2 stats (L2-hot), then MLP chain
__global__ void head2_k(const float* __restrict__ hbuf,
                        const float* __restrict__ bn2_gamma, const float* __restrict__ bn2_beta,
                        const float* __restrict__ fl_w1, const float* __restrict__ fl_b1,
                        const float* __restrict__ fl_w2, const float* __restrict__ fl_b2,
                        const float* __restrict__ out_w, const float* __restrict__ out_b,
                        float* __restrict__ d_out, int G) {
  int g = blockIdx.x, t = threadIdx.x;  // 128 threads
  __shared__ float hb[DF], t1[64], ov[32];
  float s = 0.f, q = 0.f;
  for (int r = 0; r < G; ++r) {
    float v = hbuf[(size_t)r * DF + t];
    s += v; q += v * v;
  }
  float m = s / (float)G;
  float var = q / (float)G - m * m;
  if (var < 0.f) var = 0.f;
  float sc = bn2_gamma[t] / sqrtf(var + 1e-5f);
  float sh = bn2_beta[t] - m * sc;
  hb[t] = hbuf[(size_t)g * DF + t] * sc + sh;
  __syncthreads();
  if (t < 64) {
    float acc = fl_b1[t];
#pragma unroll 4
    for (int c = 0; c < DF; ++c) acc = fmaf(hb[c], fl_w1[(size_t)c * 64 + t], acc);
    t1[t] = LEAKY(acc);
  }
  __syncthreads();
  if (t < 32) {
    float acc = fl_b2[t];
#pragma unroll 4
    for (int j = 0; j < 64; ++j) acc = fmaf(t1[j], fl_w2[(size_t)j * 32 + t], acc);
    d_out[(size_t)g * 32 + t] = acc;
    ov[t] = acc;
  }
  __syncthreads();
  if (t < 2) {
    float acc = out_b[t];
#pragma unroll
    for (int o = 0; o < 32; ++o) acc = fmaf(ov[o], out_w[(size_t)o * 2 + t], acc);
    d_out[(size_t)G * 32 + (size_t)g * 2 + t] = acc;
  }
}

extern "C" void kernel_launch(void* const* d_in, const int* in_sizes, int n_in,
                              void* d_out, int out_size, void* d_ws, size_t ws_size,
                              hipStream_t stream) {
  const float* x         = (const float*)d_in[0];
  const float* W_gnn     = (const float*)d_in[1];
  const float* b_gnn     = (const float*)d_in[2];
  const float* hbn_gamma = (const float*)d_in[3];
  const float* hbn_beta  = (const float*)d_in[4];
  const float* gf_w1     = (const float*)d_in[5];
  const float* gf_b1     = (const float*)d_in[6];
  const float* gf_w2     = (const float*)d_in[7];
  const float* gf_b2     = (const float*)d_in[8];
  const float* bn2_gamma = (const float*)d_in[9];
  const float* bn2_beta  = (const float*)d_in[10];
  const float* fl_w1     = (const float*)d_in[11];
  const float* fl_b1     = (const float*)d_in[12];
  const float* fl_w2     = (const float*)d_in[13];
  const float* fl_b2     = (const float*)d_in[14];
  const float* out_w     = (const float*)d_in[15];
  const float* out_b     = (const float*)d_in[16];
  const int* edge_index  = (const int*)d_in[17];
  const int* post_idx    = (const int*)d_in[18];
  const int* image_idx   = (const int*)d_in[19];
  const int* batch_vec   = (const int*)d_in[20];

  const int N  = in_sizes[20];
  const int E  = in_sizes[17] / 2;
  const int NP = in_sizes[18];
  const int NI = in_sizes[19];
  const int G  = out_size / 34;           // out: G*32 + prob: G*2
  const int L  = in_sizes[1] / (DF * DF);
  const int* src  = edge_index;
  const int* dstp = edge_index + E;
  const int NB = (N + 1023) / 1024;       // node scan blocks
  const int NBUCK = (N + 255) >> 8;       // 256-node buckets

  char* ws = (char*)d_ws;
  size_t off = 0;
  auto alloc = [&](size_t b) { size_t o = off; off += (b + 255) & ~(size_t)255; return o; };
  // ---- zero-initialized region (single memset) ----
  size_t zero_beg = off;
  int*   degc   = (int*)(ws + alloc((size_t)N * 4));
  int*   bhist  = (int*)(ws + alloc((size_t)NBK * 4));
  float* bns    = (float*)(ws + alloc(256 * 4));
  float* psum   = (float*)(ws + alloc((size_t)G * DF * 4));
  float* isum   = (float*)(ws + alloc((size_t)G * DF * 4));
  int*   pcnt   = (int*)(ws + alloc((size_t)G * 4));
  int*   icnt   = (int*)(ws + alloc((size_t)G * 4));
  size_t zero_bytes = off - zero_beg;
  // ---- rest ----
  float* dis    = (float*)(ws + alloc((size_t)N * 4));
  int*   rowoff = (int*)(ws + alloc((size_t)(N + 1) * 4));
  int*   cursor = (int*)(ws + alloc((size_t)N * 4));
  int2*  epack  = (int2*)(ws + alloc((size_t)E * 8));
  int*   ebuck  = (int*)(ws + alloc((size_t)E * 4));
  int*   boff2  = (int*)(ws + alloc((size_t)(NBK + 1) * 4));
  int*   bcur   = (int*)(ws + alloc((size_t)NBK * 4));
  int*   bsum   = (int*)(ws + alloc((size_t)(NB + 1) * 4));
  int*   boff   = (int*)(ws + alloc((size_t)(NB + 1) * 4));
  unsigned short* Wb  = (unsigned short*)(ws + alloc((size_t)L * DF * DF * 2));
  unsigned short* xwb = (unsigned short*)(ws + alloc((size_t)N * DF * 2));
  unsigned short* Hb  = (unsigned short*)(ws + alloc((size_t)N * DF * 2));
  int*   poff   = (int*)(ws + alloc((size_t)(G + 1) * 4));
  int*   ioff   = (int*)(ws + alloc((size_t)(G + 1) * 4));
  int*   pcur   = (int*)(ws + alloc((size_t)G * 4));
  int*   icur   = (int*)(ws + alloc((size_t)G * 4));
  int*   plist  = (int*)(ws + alloc((size_t)NP * 4));
  int*   ilist  = (int*)(ws + alloc((size_t)NI * 4));
  float* hbuf   = (float*)(ws + alloc((size_t)G * DF * 4));

  hipMemsetAsync(ws + zero_beg, 0, zero_bytes, stream);

  // degree + bucket hist + dis + node scan
  deg_bucket_k<<<256, 256, 0, stream>>>(dstp, degc, bhist, E);
  make_dis_k<<<(N + 255) / 256, 256, 0, stream>>>(degc, dis, N);
  blk_sum_k<<<NB, 1024, 0, stream>>>(degc, bsum, N);
  scan_small_k<<<1, 1024, 0, stream>>>(bsum, boff, NB);
  blk_scan_k<<<NB, 1024, 0, stream>>>(degc, boff, rowoff, cursor, N);
  // bucket scan + binned CSR build
  scan_small2_k<<<1, 1024, 0, stream>>>(bhist, boff2, bcur, NBUCK);
  bucket_fill_k<<<(E + CHUNK - 1) / CHUNK, 256, 0, stream>>>(src, dstp, bcur, ebuck, E);
  csr_fine_k<<<NBUCK, 512, 0, stream>>>(boff2, ebuck, dis, cursor, epack);
  castW_k<<<(L * DF * DF + 255) / 256, 256, 0, stream>>>(W_gnn, Wb, L * DF * DF);

  // pool index grouping (fused post+image)
  pool_cnt_k<<<(NP + NI + 255) / 256, 256, 0, stream>>>(post_idx, image_idx, batch_vec,
                                                        pcnt, icnt, NP, NI);
  pool_scan2_k<<<2, 1024, 0, stream>>>(pcnt, icnt, poff, ioff, pcur, icur, G);
  pool_fill_k<<<(NP + NI + 255) / 256, 256, 0, stream>>>(post_idx, image_idx, batch_vec,
                                                         pcur, icur, plist, ilist, NP, NI);

  // GNN layers (bf16 MFMA gemm + bf16 gather reads, f32 accumulate)
  for (int l = 0; l < L; ++l) {
    if (l == 0)
      gemm_mfma_k<false><<<(N + 31) / 32, 256, 0, stream>>>(x, nullptr,
          Wb + (size_t)l * DF * DF, xwb, N);
    else
      gemm_mfma_k<true><<<(N + 31) / 32, 256, 0, stream>>>(nullptr, Hb,
          Wb + (size_t)l * DF * DF, xwb, N);
    gather_k<<<(N * 16 + 255) / 256, 256, 0, stream>>>(xwb, rowoff, epack, dis,
                                                       b_gnn + (size_t)l * DF, Hb, N);
  }

  // BN stats over H
  bn_stats_k<<<256, 256, 0, stream>>>(Hb, bns, N);

  // pooled sums via grouped gather
  dim3 pg(G * PSPLIT, 2);
  pool_gather_k<<<pg, 256, 0, stream>>>(Hb, poff, plist, ioff, ilist, psum, isum);

  // head (bn_final folded into head1, bn2 folded into head2)
  head1_k<<<G, 512, 0, stream>>>(psum, pcnt, isum, icnt, bns, hbn_gamma, hbn_beta, N,
                                 gf_w1, gf_b1, gf_w2, gf_b2, hbuf);
  head2_k<<<G, 128, 0, stream>>>(hbuf, bn2_gamma, bn2_beta, fl_w1, fl_b1, fl_w2, fl_b2,
                                 out_w, out_b, (float*)d_out, G);
}

// Round 9
// 297.399 us; speedup vs baseline: 11.1947x; 1.1104x over previous
//
#include <hip/hip_runtime.h>
#include <hip/hip_bf16.h>
#include <math.h>

#define DF 128
#define PSPLIT 4
#define CHUNK 8192
#define NBK 256
#define LEAKY(x) ((x) > 0.f ? (x) : 0.01f * (x))

typedef __attribute__((ext_vector_type(8))) short short8v;   // 8 bf16 in 4 VGPRs
typedef __attribute__((ext_vector_type(4))) float f32x4;
typedef __attribute__((ext_vector_type(4))) unsigned short u16x4;
typedef __attribute__((ext_vector_type(8))) unsigned short u16x8;

static __device__ __forceinline__ unsigned short f2bf(float f) {
  unsigned u = __float_as_uint(f);
  unsigned r = u + 0x7fffu + ((u >> 16) & 1u);   // RNE
  return (unsigned short)(r >> 16);
}
static __device__ __forceinline__ float bf2f(unsigned short b) {
  return __uint_as_float(((unsigned)b) << 16);
}

// degree count (global atomics) + 256-node-bucket histogram (LDS -> global)
__global__ void deg_bucket_k(const int* __restrict__ dst, int* __restrict__ degc,
                             int* __restrict__ bhist, int nE) {
  __shared__ int lh[NBK];
  for (int i = threadIdx.x; i < NBK; i += 256) lh[i] = 0;
  __syncthreads();
  for (int i = blockIdx.x * 256 + threadIdx.x; i < nE; i += gridDim.x * 256) {
    int d = dst[i];
    atomicAdd(&degc[d], 1);
    atomicAdd(&lh[d >> 8], 1);
  }
  __syncthreads();
  for (int i = threadIdx.x; i < NBK; i += 256)
    if (lh[i]) atomicAdd(&bhist[i], lh[i]);
}

__global__ void make_dis_k(const int* __restrict__ cnt, float* __restrict__ dis, int n) {
  int i = blockIdx.x * 256 + threadIdx.x;
  if (i < n) dis[i] = 1.0f / sqrtf((float)cnt[i] + 1.0f);
}

// ---- parallel scan: per-1024-block sums -> exclusive block offsets -> per-element scan ----
__global__ void blk_sum_k(const int* __restrict__ cnt, int* __restrict__ bsum, int n) {
  __shared__ int sh[1024];
  int idx = blockIdx.x * 1024 + threadIdx.x;
  sh[threadIdx.x] = (idx < n) ? cnt[idx] : 0;
  __syncthreads();
  for (int ofs = 512; ofs > 0; ofs >>= 1) {
    if (threadIdx.x < (unsigned)ofs) sh[threadIdx.x] += sh[threadIdx.x + ofs];
    __syncthreads();
  }
  if (threadIdx.x == 0) bsum[blockIdx.x] = sh[0];
}

// one block: exclusive scan of in[0..n) -> out[0..n], out[n] = total (n <= 1024)
__global__ void scan_small_k(const int* __restrict__ in, int* __restrict__ out, int n) {
  __shared__ int sh[1024];
  int v = (threadIdx.x < (unsigned)n) ? in[threadIdx.x] : 0;
  sh[threadIdx.x] = v;
  __syncthreads();
  for (int ofs = 1; ofs < 1024; ofs <<= 1) {
    int t = (threadIdx.x >= (unsigned)ofs) ? sh[threadIdx.x - ofs] : 0;
    __syncthreads();
    sh[threadIdx.x] += t;
    __syncthreads();
  }
  if (threadIdx.x < (unsigned)n) out[threadIdx.x] = sh[threadIdx.x] - v;
  if (threadIdx.x == 0) out[n] = sh[1023];
}

// same but also writes a cursor copy
__global__ void scan_small2_k(const int* __restrict__ in, int* __restrict__ out,
                              int* __restrict__ cur, int n) {
  __shared__ int sh[1024];
  int v = (threadIdx.x < (unsigned)n) ? in[threadIdx.x] : 0;
  sh[threadIdx.x] = v;
  __syncthreads();
  for (int ofs = 1; ofs < 1024; ofs <<= 1) {
    int t = (threadIdx.x >= (unsigned)ofs) ? sh[threadIdx.x - ofs] : 0;
    __syncthreads();
    sh[threadIdx.x] += t;
    __syncthreads();
  }
  if (threadIdx.x < (unsigned)n) {
    int ex = sh[threadIdx.x] - v;
    out[threadIdx.x] = ex;
    cur[threadIdx.x] = ex;
  }
  if (threadIdx.x == 0) out[n] = sh[1023];
}

// dual scan for pool groups: blockIdx 0 -> p, 1 -> i
__global__ void pool_scan2_k(const int* __restrict__ pcnt, const int* __restrict__ icnt,
                             int* __restrict__ poff, int* __restrict__ ioff,
                             int* __restrict__ pcur, int* __restrict__ icur, int n) {
  const int* in = blockIdx.x ? icnt : pcnt;
  int* out = blockIdx.x ? ioff : poff;
  int* cur = blockIdx.x ? icur : pcur;
  __shared__ int sh[1024];
  int v = (threadIdx.x < (unsigned)n) ? in[threadIdx.x] : 0;
  sh[threadIdx.x] = v;
  __syncthreads();
  for (int ofs = 1; ofs < 1024; ofs <<= 1) {
    int t = (threadIdx.x >= (unsigned)ofs) ? sh[threadIdx.x - ofs] : 0;
    __syncthreads();
    sh[threadIdx.x] += t;
    __syncthreads();
  }
  if (threadIdx.x < (unsigned)n) {
    int ex = sh[threadIdx.x] - v;
    out[threadIdx.x] = ex;
    cur[threadIdx.x] = ex;
  }
  if (threadIdx.x == 0) out[n] = sh[1023];
}

__global__ void blk_scan_k(const int* __restrict__ cnt, const int* __restrict__ boff,
                           int* __restrict__ rowoff, int* __restrict__ cursor, int n) {
  __shared__ int sh[1024];
  int idx = blockIdx.x * 1024 + threadIdx.x;
  int v = (idx < n) ? cnt[idx] : 0;
  sh[threadIdx.x] = v;
  __syncthreads();
  for (int ofs = 1; ofs < 1024; ofs <<= 1) {
    int t = (threadIdx.x >= (unsigned)ofs) ? sh[threadIdx.x - ofs] : 0;
    __syncthreads();
    sh[threadIdx.x] += t;
    __syncthreads();
  }
  if (idx < n) {
    int ex = boff[blockIdx.x] + sh[threadIdx.x] - v;
    rowoff[idx] = ex; cursor[idx] = ex;
    if (idx == n - 1) rowoff[n] = ex + v;
  }
}

// pass B: LDS counting-sort of an 8192-edge chunk into dst-buckets, burst-write bucket-major
__global__ void __launch_bounds__(256) bucket_fill_k(const int* __restrict__ src,
                                                     const int* __restrict__ dst,
                                                     int* __restrict__ bcur,
                                                     int* __restrict__ ebuck, int nE) {
  __shared__ int hist[NBK];
  __shared__ int base[NBK];
  __shared__ int gbase[NBK];
  __shared__ int lpack[CHUNK];
  __shared__ unsigned char lbk[CHUNK];
  int e0 = blockIdx.x * CHUNK;
  int cnt = nE - e0; if (cnt > CHUNK) cnt = CHUNK;
  for (int i = threadIdx.x; i < NBK; i += 256) hist[i] = 0;
  __syncthreads();
  for (int i = threadIdx.x; i < cnt; i += 256)
    atomicAdd(&hist[dst[e0 + i] >> 8], 1);
  __syncthreads();
  int t = threadIdx.x;
  base[t] = hist[t];
  __syncthreads();
  for (int ofs = 1; ofs < NBK; ofs <<= 1) {
    int tv = (t >= ofs) ? base[t - ofs] : 0;
    __syncthreads();
    base[t] += tv;
    __syncthreads();
  }
  int excl = base[t] - hist[t];
  __syncthreads();
  base[t] = excl;
  hist[t] = 0;
  __syncthreads();
  for (int i = threadIdx.x; i < cnt; i += 256) {
    int d = dst[e0 + i], s = src[e0 + i];
    int bk = d >> 8;
    int pos = base[bk] + atomicAdd(&hist[bk], 1);
    lpack[pos] = (s << 8) | (d & 255);
    lbk[pos] = (unsigned char)bk;
  }
  __syncthreads();
  int c = hist[t];
  gbase[t] = c > 0 ? atomicAdd(&bcur[t], c) : 0;
  __syncthreads();
  for (int i = threadIdx.x; i < cnt; i += 256) {
    int bk = lbk[i];
    ebuck[gbase[bk] + (i - base[bk])] = lpack[i];
  }
}

// pass C: one block owns one bucket's CSR region -> exclusive-XCD fine scatter
__global__ void __launch_bounds__(512) csr_fine_k(const int* __restrict__ boff2,
                                                  const int* __restrict__ ebuck,
                                                  const float* __restrict__ dis,
                                                  int* __restrict__ cursor,
                                                  int2* __restrict__ epack) {
  int b = blockIdx.x;
  int beg = boff2[b], end = boff2[b + 1];
  int node0 = b << 8;
  for (int i = beg + threadIdx.x; i < end; i += 512) {
    int v = ebuck[i];
    int s = v >> 8, d = node0 + (v & 255);
    int p = atomicAdd(&cursor[d], 1);
    int2 w; w.x = s; w.y = __float_as_int(dis[s] * dis[d]);
    epack[p] = w;
  }
}

// W -> bf16 in MFMA-fragment order
__global__ void castW_k(const float* __restrict__ W, unsigned short* __restrict__ Wb, int total) {
  int i = blockIdx.x * 256 + threadIdx.x;
  if (i >= total) return;
  int layer = i >> 14, o = i & 16383;
  int j = o & 7, l = (o >> 3) & 63, ks = (o >> 9) & 3, ct = (o >> 11) & 3, wc = (o >> 13) & 1;
  int row = ks * 32 + (l >> 4) * 8 + j;
  int col = wc * 64 + ct * 16 + (l & 15);
  Wb[i] = f2bf(W[((size_t)layer << 14) + row * DF + col]);
}

// xwb[r][c] = bf16( sum_k A[r][k] * W[k][c] ); A from f32 (layer0) or bf16 Hb.
template<bool BF16A>
__global__ void __launch_bounds__(256) gemm_mfma_k(const float* __restrict__ A,
                                                   const unsigned short* __restrict__ Ab,
                                                   const unsigned short* __restrict__ Wb,
                                                   unsigned short* __restrict__ xwb, int n) {
  const int w = threadIdx.x >> 6, l = threadIdx.x & 63;
  const int wr = w & 1, wc = w >> 1;
  const int r0 = blockIdx.x * 32 + wr * 16;
  const int row = r0 + (l & 15);
  const int kg = l >> 4;                 // 0..3
  short8v bf[4][4];
  const unsigned short* wp = Wb + (size_t)wc * 8192 + (size_t)l * 8;
#pragma unroll
  for (int ct = 0; ct < 4; ++ct)
#pragma unroll
    for (int ks = 0; ks < 4; ++ks)
      bf[ct][ks] = *(const short8v*)(wp + ((ct * 4 + ks) << 9));
  const bool rok = row < n;
  short8v af[4];
  if constexpr (BF16A) {
    const unsigned short* ap = Ab + (size_t)row * DF + kg * 8;
#pragma unroll
    for (int ks = 0; ks < 4; ++ks)
      af[ks] = rok ? *(const short8v*)(ap + ks * 32) : (short8v)0;
  } else {
    const float* ap = A + (size_t)row * DF + kg * 8;
#pragma unroll
    for (int ks = 0; ks < 4; ++ks) {
      if (rok) {
        float4 lo = *(const float4*)(ap + ks * 32);
        float4 hi = *(const float4*)(ap + ks * 32 + 4);
        short8v t;
        t[0] = (short)f2bf(lo.x); t[1] = (short)f2bf(lo.y);
        t[2] = (short)f2bf(lo.z); t[3] = (short)f2bf(lo.w);
        t[4] = (short)f2bf(hi.x); t[5] = (short)f2bf(hi.y);
        t[6] = (short)f2bf(hi.z); t[7] = (short)f2bf(hi.w);
        af[ks] = t;
      } else af[ks] = (short8v)0;
    }
  }
  f32x4 acc[4];
#pragma unroll
  for (int ct = 0; ct < 4; ++ct) acc[ct] = (f32x4)(0.f);
#pragma unroll
  for (int ks = 0; ks < 4; ++ks)
#pragma unroll
    for (int ct = 0; ct < 4; ++ct)
      acc[ct] = __builtin_amdgcn_mfma_f32_16x16x32_bf16(af[ks], bf[ct][ks], acc[ct], 0, 0, 0);
#pragma unroll
  for (int ct = 0; ct < 4; ++ct) {
    int c = wc * 64 + ct * 16 + (l & 15);
#pragma unroll
    for (int rg = 0; rg < 4; ++rg) {
      int r = r0 + kg * 4 + rg;
      if (r < n) xwb[(size_t)r * DF + c] = f2bf(acc[ct][rg]);
    }
  }
}

// CSR gather + self-loop + bias + leaky. 16 lanes/node, u16x8 loads, edge loop unrolled x4.
__global__ void gather_k(const unsigned short* __restrict__ xwb, const int* __restrict__ rowoff,
                         const int2* __restrict__ epack, const float* __restrict__ dis,
                         const float* __restrict__ b, unsigned short* __restrict__ Hb, int n) {
  int gid = blockIdx.x * 256 + threadIdx.x;
  int node = gid >> 4;
  if (node >= n) return;
  int part = gid & 15;
  int beg = rowoff[node], end = rowoff[node + 1];
  float acc[8];
#pragma unroll
  for (int j = 0; j < 8; ++j) acc[j] = 0.f;
  int p = beg;
  for (; p + 3 < end; p += 4) {
    int2 q0 = epack[p], q1 = epack[p + 1], q2 = epack[p + 2], q3 = epack[p + 3];
    float e0 = __int_as_float(q0.y), e1 = __int_as_float(q1.y);
    float e2 = __int_as_float(q2.y), e3 = __int_as_float(q3.y);
    u16x8 v0 = *(const u16x8*)(xwb + (size_t)q0.x * DF + part * 8);
    u16x8 v1 = *(const u16x8*)(xwb + (size_t)q1.x * DF + part * 8);
    u16x8 v2 = *(const u16x8*)(xwb + (size_t)q2.x * DF + part * 8);
    u16x8 v3 = *(const u16x8*)(xwb + (size_t)q3.x * DF + part * 8);
#pragma unroll
    for (int j = 0; j < 8; ++j) {
      acc[j] = fmaf(bf2f(v0[j]), e0, acc[j]);
      acc[j] = fmaf(bf2f(v1[j]), e1, acc[j]);
      acc[j] = fmaf(bf2f(v2[j]), e2, acc[j]);
      acc[j] = fmaf(bf2f(v3[j]), e3, acc[j]);
    }
  }
  for (; p < end; ++p) {
    int2 q = epack[p];
    float e = __int_as_float(q.y);
    u16x8 v = *(const u16x8*)(xwb + (size_t)q.x * DF + part * 8);
#pragma unroll
    for (int j = 0; j < 8; ++j) acc[j] = fmaf(bf2f(v[j]), e, acc[j]);
  }
  float dd = dis[node], sn = dd * dd;
  u16x8 xv = *(const u16x8*)(xwb + (size_t)node * DF + part * 8);
  const float* bp = b + part * 8;
  u16x8 o;
#pragma unroll
  for (int j = 0; j < 8; ++j) {
    float r = fmaf(bf2f(xv[j]), sn, acc[j]) + bp[j];
    r = LEAKY(r);
    o[j] = f2bf(r);
  }
  *(u16x8*)(Hb + (size_t)node * DF + part * 8) = o;
}

// per-column sum and sumsq over n rows of bf16 H
__global__ void bn_stats_k(const unsigned short* __restrict__ Hb, float* __restrict__ sums, int n) {
  int c = threadIdx.x & (DF - 1);
  int half = threadIdx.x >> 7;
  float s = 0.f, q = 0.f;
  for (int r = blockIdx.x * 2 + half; r < n; r += gridDim.x * 2) {
    float v = bf2f(Hb[(size_t)r * DF + c]);
    s += v; q += v * v;
  }
  __shared__ float ls[256], lq[256];
  ls[threadIdx.x] = s; lq[threadIdx.x] = q;
  __syncthreads();
  if (half == 0) {
    atomicAdd(&sums[c], ls[c] + ls[c + DF]);
    atomicAdd(&sums[DF + c], lq[c] + lq[c + DF]);
  }
}

// ---- pooling: group indices by graph (fused post+image), then gather ----
__global__ void pool_cnt_k(const int* __restrict__ post_idx, const int* __restrict__ image_idx,
                           const int* __restrict__ batch, int* __restrict__ pcnt,
                           int* __restrict__ icnt, int NP, int NI) {
  int i = blockIdx.x * 256 + threadIdx.x;
  if (i < NP) atomicAdd(&pcnt[batch[post_idx[i]]], 1);
  else if (i < NP + NI) atomicAdd(&icnt[batch[image_idx[i - NP]]], 1);
}

__global__ void pool_fill_k(const int* __restrict__ post_idx, const int* __restrict__ image_idx,
                            const int* __restrict__ batch, int* __restrict__ pcur,
                            int* __restrict__ icur, int* __restrict__ plist,
                            int* __restrict__ ilist, int NP, int NI) {
  int i = blockIdx.x * 256 + threadIdx.x;
  if (i < NP) {
    int nd = post_idx[i];
    int p = atomicAdd(&pcur[batch[nd]], 1);
    plist[p] = nd;
  } else if (i < NP + NI) {
    int nd = image_idx[i - NP];
    int p = atomicAdd(&icur[batch[nd]], 1);
    ilist[p] = nd;
  }
}

// grid: (G*PSPLIT, 2). Each block: partial sum of graph g's member rows -> one atomic per col.
__global__ void pool_gather_k(const unsigned short* __restrict__ Hb,
                              const int* __restrict__ goff_p, const int* __restrict__ mlist_p,
                              const int* __restrict__ goff_i, const int* __restrict__ mlist_i,
                              float* __restrict__ psum, float* __restrict__ isum) {
  int g = blockIdx.x / PSPLIT, sub = blockIdx.x % PSPLIT;
  const int* goff  = blockIdx.y ? goff_i  : goff_p;
  const int* mlist = blockIdx.y ? mlist_i : mlist_p;
  float* out       = blockIdx.y ? isum    : psum;
  int part = threadIdx.x & 31, slot = threadIdx.x >> 5;  // 8 row slots
  int beg = goff[g], end = goff[g + 1];
  float4 acc = make_float4(0.f, 0.f, 0.f, 0.f);
  for (int j = beg + sub * 8 + slot; j < end; j += PSPLIT * 8) {
    u16x4 v = *(const u16x4*)(Hb + (size_t)mlist[j] * DF + part * 4);
    acc.x += bf2f(v[0]); acc.y += bf2f(v[1]); acc.z += bf2f(v[2]); acc.w += bf2f(v[3]);
  }
  __shared__ float4 sh[256];
  sh[threadIdx.x] = acc;
  __syncthreads();
  for (int ofs = 128; ofs >= 32; ofs >>= 1) {
    if (threadIdx.x < (unsigned)ofs) {
      float4 o = sh[threadIdx.x + ofs];
      float4 a = sh[threadIdx.x];
      a.x += o.x; a.y += o.y; a.z += o.z; a.w += o.w;
      sh[threadIdx.x] = a;
    }
    __syncthreads();
  }
  if (threadIdx.x < 32) {
    float4 a = sh[threadIdx.x];
    float* o = out + (size_t)g * DF + part * 4;
    atomicAdd(o + 0, a.x);
    atomicAdd(o + 1, a.y);
    atomicAdd(o + 2, a.z);
    atomicAdd(o + 3, a.w);
  }
}

// head layer 1 (folds bn_final): 512 threads, 4-way split-K
__global__ void __launch_bounds__(512) head1_k(const float* __restrict__ psum,
                        const int* __restrict__ pcnt,
                        const float* __restrict__ isum, const int* __restrict__ icnt,
                        const float* __restrict__ bns, const float* __restrict__ hbn_gamma,
                        const float* __restrict__ hbn_beta, int nN,
                        const float* __restrict__ gf_w1, const float* __restrict__ gf_b1,
                        const float* __restrict__ gf_w2, const float* __restrict__ gf_b2,
                        float* __restrict__ hbuf) {
  int g = blockIdx.x;
  int j = threadIdx.x & 127, kq = threadIdx.x >> 7;  // 4 K-quarters
  __shared__ float comb[4 * DF];
  __shared__ float part[512];
  __shared__ float t1[DF];
  if (kq == 0) {
    float m = bns[j] / (float)nN;
    float var = bns[DF + j] / (float)nN - m * m;
    if (var < 0.f) var = 0.f;
    float sc = hbn_gamma[j] / sqrtf(var + 1e-5f);
    float sh = hbn_beta[j] - m * sc;
    int pc = pcnt[g], ic = icnt[g];
    float pf = pc > 0 ? (psum[(size_t)g * DF + j] / (float)pc) * sc + sh : 0.f;
    float im = ic > 0 ? (isum[(size_t)g * DF + j] / (float)ic) * sc + sh : 0.f;
    comb[j] = pf;
    comb[DF + j] = im;
    comb[2 * DF + j] = pf - im;
    comb[3 * DF + j] = pf * im;
  }
  __syncthreads();
  float acc = 0.f;
  const float* w1 = gf_w1 + (size_t)kq * 128 * DF + j;
#pragma unroll 8
  for (int kk = 0; kk < 128; ++kk)
    acc = fmaf(comb[kq * 128 + kk], w1[(size_t)kk * DF], acc);
  part[threadIdx.x] = acc;
  __syncthreads();
  if (kq == 0)
    t1[j] = LEAKY(gf_b1[j] + part[j] + part[128 + j] + part[256 + j] + part[384 + j]);
  __syncthreads();
  acc = 0.f;
  const float* w2 = gf_w2 + (size_t)kq * 32 * DF + j;
#pragma unroll 8
  for (int kk = 0; kk < 32; ++kk)
    acc = fmaf(t1[kq * 32 + kk], w2[(size_t)kk * DF], acc);
  part[threadIdx.x] = acc;
  __syncthreads();
  if (kq == 0)
    hbuf[(size_t)g * DF + j] = gf_b2[j] + part[j] + part[128 + j] + part[256 + j] + part[384 + j];
}

// BN2 stats: one block, 1024 threads = 8 row-slots x 128 cols -> ss2 scale/shift
__global__ void __launch_bounds__(1024) bn2_k(const float* __restrict__ hbuf,
                      const float* __restrict__ gamma, const float* __restrict__ beta,
                      float* __restrict__ ss2, int G) {
  int c = threadIdx.x & 127, slot = threadIdx.x >> 7;  // 8 slots
  float s = 0.f, q = 0.f;
  for (int r = slot; r < G; r += 8) {
    float v = hbuf[(size_t)r * DF + c];
    s += v; q += v * v;
  }
  __shared__ float ls[1024], lq[1024];
  ls[threadIdx.x] = s; lq[threadIdx.x] = q;
  __syncthreads();
  for (int ofs = 512; ofs >= 128; ofs >>= 1) {
    if (threadIdx.x < (unsigned)ofs) {
      ls[threadIdx.x] += ls[threadIdx.x + ofs];
      lq[threadIdx.x] += lq[threadIdx.x + ofs];
    }
    __syncthreads();
  }
  if (threadIdx.x < 128) {
    float m = ls[c] / (float)G;
    float var = lq[c] / (float)G - m * m;
    if (var < 0.f) var = 0.f;
    float sc = gamma[c] / sqrtf(var + 1e-5f);
    ss2[c] = sc;
    ss2[DF + c] = beta[c] - m * sc;
  }
}

// head2: 512 threads, split-K at every stage. BN2-apply, 128->64, 64->32, 32->2.
__global__ void __launch_bounds__(512) head2_k(const float* __restrict__ hbuf,
                        const float* __restrict__ ss2,
                        const float* __restrict__ fl_w1, const float* __restrict__ fl_b1,
                        const float* __restrict__ fl_w2, const float* __restrict__ fl_b2,
                        const float* __restrict__ out_w, const float* __restrict__ out_b,
                        float* __restrict__ d_out, int G) {
  int g = blockIdx.x, t = threadIdx.x;
  __shared__ float hb[DF], part[512], t1[64], ov[32];
  if (t < DF) hb[t] = hbuf[(size_t)g * DF + t] * ss2[t] + ss2[DF + t];
  __syncthreads();
  // layer1: 64 outs x 8 K-chunks of 16
  {
    int j = t & 63, kq = t >> 6;
    float acc = 0.f;
    const float* w = fl_w1 + (size_t)kq * 16 * 64 + j;
#pragma unroll
    for (int kk = 0; kk < 16; ++kk)
      acc = fmaf(hb[kq * 16 + kk], w[(size_t)kk * 64], acc);
    part[t] = acc;
  }
  __syncthreads();
  if (t < 64) {
    float s = fl_b1[t];
#pragma unroll
    for (int i = 0; i < 8; ++i) s += part[i * 64 + t];
    t1[t] = LEAKY(s);
  }
  __syncthreads();
  // layer2: 32 outs x 16 K-chunks of 4
  {
    int j = t & 31, kq = t >> 5;
    float acc = 0.f;
    const float* w = fl_w2 + (size_t)kq * 4 * 32 + j;
#pragma unroll
    for (int kk = 0; kk < 4; ++kk)
      acc = fmaf(t1[kq * 4 + kk], w[(size_t)kk * 32], acc);
    part[t] = acc;
  }
  __syncthreads();
  if (t < 32) {
    float s = fl_b2[t];
#pragma unroll
    for (int i = 0; i < 16; ++i) s += part[i * 32 + t];
    d_out[(size_t)g * 32 + t] = s;
    ov[t] = s;
  }
  __syncthreads();
  // layer3: 2 outs x 32 K-chunks of 1 (64 threads)
  if (t < 64) {
    int j = t & 1, kq = t >> 1;
    part[t] = ov[kq] * out_w[(size_t)kq * 2 + j];
  }
  __syncthreads();
  if (t < 2) {
    float s = out_b[t];
#pragma unroll
    for (int i = 0; i < 32; ++i) s += part[i * 2 + t];
    d_out[(size_t)G * 32 + (size_t)g * 2 + t] = s;
  }
}

extern "C" void kernel_launch(void* const* d_in, const int* in_sizes, int n_in,
                              void* d_out, int out_size, void* d_ws, size_t ws_size,
                              hipStream_t stream) {
  const float* x         = (const float*)d_in[0];
  const float* W_gnn     = (const float*)d_in[1];
  const float* b_gnn     = (const float*)d_in[2];
  const float* hbn_gamma = (const float*)d_in[3];
  const float* hbn_beta  = (const float*)d_in[4];
  const float* gf_w1     = (const float*)d_in[5];
  const float* gf_b1     = (const float*)d_in[6];
  const float* gf_w2     = (const float*)d_in[7];
  const float* gf_b2     = (const float*)d_in[8];
  const float* bn2_gamma = (const float*)d_in[9];
  const float* bn2_beta  = (const float*)d_in[10];
  const float* fl_w1     = (const float*)d_in[11];
  const float* fl_b1     = (const float*)d_in[12];
  const float* fl_w2     = (const float*)d_in[13];
  const float* fl_b2     = (const float*)d_in[14];
  const float* out_w     = (const float*)d_in[15];
  const float* out_b     = (const float*)d_in[16];
  const int* edge_index  = (const int*)d_in[17];
  const int* post_idx    = (const int*)d_in[18];
  const int* image_idx   = (const int*)d_in[19];
  const int* batch_vec   = (const int*)d_in[20];

  const int N  = in_sizes[20];
  const int E  = in_sizes[17] / 2;
  const int NP = in_sizes[18];
  const int NI = in_sizes[19];
  const int G  = out_size / 34;           // out: G*32 + prob: G*2
  const int L  = in_sizes[1] / (DF * DF);
  const int* src  = edge_index;
  const int* dstp = edge_index + E;
  const int NB = (N + 1023) / 1024;       // node scan blocks
  const int NBUCK = (N + 255) >> 8;       // 256-node buckets

  char* ws = (char*)d_ws;
  size_t off = 0;
  auto alloc = [&](size_t b) { size_t o = off; off += (b + 255) & ~(size_t)255; return o; };
  // ---- zero-initialized region (single memset) ----
  size_t zero_beg = off;
  int*   degc   = (int*)(ws + alloc((size_t)N * 4));
  int*   bhist  = (int*)(ws + alloc((size_t)NBK * 4));
  float* bns    = (float*)(ws + alloc(256 * 4));
  float* psum   = (float*)(ws + alloc((size_t)G * DF * 4));
  float* isum   = (float*)(ws + alloc((size_t)G * DF * 4));
  int*   pcnt   = (int*)(ws + alloc((size_t)G * 4));
  int*   icnt   = (int*)(ws + alloc((size_t)G * 4));
  size_t zero_bytes = off - zero_beg;
  // ---- rest ----
  float* dis    = (float*)(ws + alloc((size_t)N * 4));
  int*   rowoff = (int*)(ws + alloc((size_t)(N + 1) * 4));
  int*   cursor = (int*)(ws + alloc((size_t)N * 4));
  int2*  epack  = (int2*)(ws + alloc((size_t)E * 8));
  int*   ebuck  = (int*)(ws + alloc((size_t)E * 4));
  int*   boff2  = (int*)(ws + alloc((size_t)(NBK + 1) * 4));
  int*   bcur   = (int*)(ws + alloc((size_t)NBK * 4));
  int*   bsum   = (int*)(ws + alloc((size_t)(NB + 1) * 4));
  int*   boff   = (int*)(ws + alloc((size_t)(NB + 1) * 4));
  unsigned short* Wb  = (unsigned short*)(ws + alloc((size_t)L * DF * DF * 2));
  unsigned short* xwb = (unsigned short*)(ws + alloc((size_t)N * DF * 2));
  unsigned short* Hb  = (unsigned short*)(ws + alloc((size_t)N * DF * 2));
  int*   poff   = (int*)(ws + alloc((size_t)(G + 1) * 4));
  int*   ioff   = (int*)(ws + alloc((size_t)(G + 1) * 4));
  int*   pcur   = (int*)(ws + alloc((size_t)G * 4));
  int*   icur   = (int*)(ws + alloc((size_t)G * 4));
  int*   plist  = (int*)(ws + alloc((size_t)NP * 4));
  int*   ilist  = (int*)(ws + alloc((size_t)NI * 4));
  float* hbuf   = (float*)(ws + alloc((size_t)G * DF * 4));
  float* ss2    = (float*)(ws + alloc(256 * 4));

  hipMemsetAsync(ws + zero_beg, 0, zero_bytes, stream);

  // degree + bucket hist + dis + node scan
  deg_bucket_k<<<256, 256, 0, stream>>>(dstp, degc, bhist, E);
  make_dis_k<<<(N + 255) / 256, 256, 0, stream>>>(degc, dis, N);
  blk_sum_k<<<NB, 1024, 0, stream>>>(degc, bsum, N);
  scan_small_k<<<1, 1024, 0, stream>>>(bsum, boff, NB);
  blk_scan_k<<<NB, 1024, 0, stream>>>(degc, boff, rowoff, cursor, N);
  // bucket scan + binned CSR build
  scan_small2_k<<<1, 1024, 0, stream>>>(bhist, boff2, bcur, NBUCK);
  bucket_fill_k<<<(E + CHUNK - 1) / CHUNK, 256, 0, stream>>>(src, dstp, bcur, ebuck, E);
  csr_fine_k<<<NBUCK, 512, 0, stream>>>(boff2, ebuck, dis, cursor, epack);
  castW_k<<<(L * DF * DF + 255) / 256, 256, 0, stream>>>(W_gnn, Wb, L * DF * DF);

  // pool index grouping (fused post+image)
  pool_cnt_k<<<(NP + NI + 255) / 256, 256, 0, stream>>>(post_idx, image_idx, batch_vec,
                                                        pcnt, icnt, NP, NI);
  pool_scan2_k<<<2, 1024, 0, stream>>>(pcnt, icnt, poff, ioff, pcur, icur, G);
  pool_fill_k<<<(NP + NI + 255) / 256, 256, 0, stream>>>(post_idx, image_idx, batch_vec,
                                                         pcur, icur, plist, ilist, NP, NI);

  // GNN layers (bf16 MFMA gemm + bf16 gather reads, f32 accumulate)
  for (int l = 0; l < L; ++l) {
    if (l == 0)
      gemm_mfma_k<false><<<(N + 31) / 32, 256, 0, stream>>>(x, nullptr,
          Wb + (size_t)l * DF * DF, xwb, N);
    else
      gemm_mfma_k<true><<<(N + 31) / 32, 256, 0, stream>>>(nullptr, Hb,
          Wb + (size_t)l * DF * DF, xwb, N);
    gather_k<<<(N * 16 + 255) / 256, 256, 0, stream>>>(xwb, rowoff, epack, dis,
                                                       b_gnn + (size_t)l * DF, Hb, N);
  }

  // BN stats over H
  bn_stats_k<<<256, 256, 0, stream>>>(Hb, bns, N);

  // pooled sums via grouped gather
  dim3 pg(G * PSPLIT, 2);
  pool_gather_k<<<pg, 256, 0, stream>>>(Hb, poff, plist, ioff, ilist, psum, isum);

  // head
  head1_k<<<G, 512, 0, stream>>>(psum, pcnt, isum, icnt, bns, hbn_gamma, hbn_beta, N,
                                 gf_w1, gf_b1, gf_w2, gf_b2, hbuf);
  bn2_k<<<1, 1024, 0, stream>>>(hbuf, bn2_gamma, bn2_beta, ss2, G);
  head2_k<<<G, 512, 0, stream>>>(hbuf, ss2, fl_w1, fl_b1, fl_w2, fl_b2, out_w, out_b,
                                 (float*)d_out, G);
}

// Round 10
// 272.829 us; speedup vs baseline: 12.2028x; 1.0901x over previous
//
#include <hip/hip_runtime.h>
#include <hip/hip_bf16.h>
#include <math.h>

#define DF 128
#define PSPLIT 4
#define CHUNK 8192
#define NBK 256
#define LEAKY(x) ((x) > 0.f ? (x) : 0.01f * (x))

typedef __attribute__((ext_vector_type(8))) short short8v;   // 8 bf16 in 4 VGPRs
typedef __attribute__((ext_vector_type(4))) float f32x4;
typedef __attribute__((ext_vector_type(4))) unsigned short u16x4;
typedef __attribute__((ext_vector_type(8))) unsigned short u16x8;

static __device__ __forceinline__ unsigned short f2bf(float f) {
  unsigned u = __float_as_uint(f);
  unsigned r = u + 0x7fffu + ((u >> 16) & 1u);   // RNE
  return (unsigned short)(r >> 16);
}
static __device__ __forceinline__ float bf2f(unsigned short b) {
  return __uint_as_float(((unsigned)b) << 16);
}

// fused: [0,EB) deg+bucket hist; [EB,EB+PB) pool counts; [EB+PB,..) castW
__global__ void fused_pre_k(const int* __restrict__ dst, int* __restrict__ degc,
                            int* __restrict__ bhist,
                            const int* __restrict__ post_idx, const int* __restrict__ image_idx,
                            const int* __restrict__ batch, int* __restrict__ pcnt,
                            int* __restrict__ icnt,
                            const float* __restrict__ W, unsigned short* __restrict__ Wb,
                            int nE, int NP, int NI, int wTotal, int EB, int PB) {
  int b = blockIdx.x;
  if (b < EB) {
    __shared__ int lh[NBK];
    for (int i = threadIdx.x; i < NBK; i += 256) lh[i] = 0;
    __syncthreads();
    for (int i = b * 256 + threadIdx.x; i < nE; i += EB * 256) {
      int d = dst[i];
      atomicAdd(&degc[d], 1);
      atomicAdd(&lh[d >> 8], 1);
    }
    __syncthreads();
    for (int i = threadIdx.x; i < NBK; i += 256)
      if (lh[i]) atomicAdd(&bhist[i], lh[i]);
  } else if (b < EB + PB) {
    int i = (b - EB) * 256 + threadIdx.x;
    if (i < NP) atomicAdd(&pcnt[batch[post_idx[i]]], 1);
    else if (i < NP + NI) atomicAdd(&icnt[batch[image_idx[i - NP]]], 1);
  } else {
    int i = (b - EB - PB) * 256 + threadIdx.x;
    if (i < wTotal) {
      int layer = i >> 14, o = i & 16383;
      int j = o & 7, l = (o >> 3) & 63, ks = (o >> 9) & 3, ct = (o >> 11) & 3, wc = (o >> 13) & 1;
      int row = ks * 32 + (l >> 4) * 8 + j;
      int col = wc * 64 + ct * 16 + (l & 15);
      Wb[i] = f2bf(W[((size_t)layer << 14) + row * DF + col]);
    }
  }
}

// per-1024-block sums of degc
__global__ void blk_sum_k(const int* __restrict__ cnt, int* __restrict__ bsum, int n) {
  __shared__ int sh[1024];
  int idx = blockIdx.x * 1024 + threadIdx.x;
  sh[threadIdx.x] = (idx < n) ? cnt[idx] : 0;
  __syncthreads();
  for (int ofs = 512; ofs > 0; ofs >>= 1) {
    if (threadIdx.x < (unsigned)ofs) sh[threadIdx.x] += sh[threadIdx.x + ofs];
    __syncthreads();
  }
  if (threadIdx.x == 0) bsum[blockIdx.x] = sh[0];
}

// 4 independent small exclusive scans in one launch (block 0..3)
__global__ void __launch_bounds__(1024) scan4_k(
    const int* __restrict__ bsum, int* __restrict__ boff, int NB,
    const int* __restrict__ bhist, int* __restrict__ boff2, int* __restrict__ bcur, int NBUCK,
    const int* __restrict__ pcnt, int* __restrict__ poff, int* __restrict__ pcur,
    const int* __restrict__ icnt, int* __restrict__ ioff, int* __restrict__ icur, int G) {
  const int* in; int* out; int* cur; int n;
  if (blockIdx.x == 0)      { in = bsum;  out = boff;  cur = nullptr; n = NB; }
  else if (blockIdx.x == 1) { in = bhist; out = boff2; cur = bcur;    n = NBUCK; }
  else if (blockIdx.x == 2) { in = pcnt;  out = poff;  cur = pcur;    n = G; }
  else                      { in = icnt;  out = ioff;  cur = icur;    n = G; }
  __shared__ int sh[1024];
  int v = (threadIdx.x < (unsigned)n) ? in[threadIdx.x] : 0;
  sh[threadIdx.x] = v;
  __syncthreads();
  for (int ofs = 1; ofs < 1024; ofs <<= 1) {
    int t = (threadIdx.x >= (unsigned)ofs) ? sh[threadIdx.x - ofs] : 0;
    __syncthreads();
    sh[threadIdx.x] += t;
    __syncthreads();
  }
  if (threadIdx.x < (unsigned)n) {
    int ex = sh[threadIdx.x] - v;
    out[threadIdx.x] = ex;
    if (cur) cur[threadIdx.x] = ex;
  }
  if (threadIdx.x == 0) out[n] = sh[1023];
}

// node-level scan (rowoff/cursor) + dis computation folded in
__global__ void blk_scan_dis_k(const int* __restrict__ cnt, const int* __restrict__ boff,
                               int* __restrict__ rowoff, int* __restrict__ cursor,
                               float* __restrict__ dis, int n) {
  __shared__ int sh[1024];
  int idx = blockIdx.x * 1024 + threadIdx.x;
  int v = (idx < n) ? cnt[idx] : 0;
  sh[threadIdx.x] = v;
  __syncthreads();
  for (int ofs = 1; ofs < 1024; ofs <<= 1) {
    int t = (threadIdx.x >= (unsigned)ofs) ? sh[threadIdx.x - ofs] : 0;
    __syncthreads();
    sh[threadIdx.x] += t;
    __syncthreads();
  }
  if (idx < n) {
    int ex = boff[blockIdx.x] + sh[threadIdx.x] - v;
    rowoff[idx] = ex; cursor[idx] = ex;
    dis[idx] = 1.0f / sqrtf((float)v + 1.0f);
    if (idx == n - 1) rowoff[n] = ex + v;
  }
}

// pass B: LDS counting-sort of an 8192-edge chunk into dst-buckets, burst-write bucket-major
__global__ void __launch_bounds__(256) bucket_fill_k(const int* __restrict__ src,
                                                     const int* __restrict__ dst,
                                                     int* __restrict__ bcur,
                                                     int* __restrict__ ebuck, int nE) {
  __shared__ int hist[NBK];
  __shared__ int base[NBK];
  __shared__ int gbase[NBK];
  __shared__ int lpack[CHUNK];
  __shared__ unsigned char lbk[CHUNK];
  int e0 = blockIdx.x * CHUNK;
  int cnt = nE - e0; if (cnt > CHUNK) cnt = CHUNK;
  for (int i = threadIdx.x; i < NBK; i += 256) hist[i] = 0;
  __syncthreads();
  for (int i = threadIdx.x; i < cnt; i += 256)
    atomicAdd(&hist[dst[e0 + i] >> 8], 1);
  __syncthreads();
  int t = threadIdx.x;
  base[t] = hist[t];
  __syncthreads();
  for (int ofs = 1; ofs < NBK; ofs <<= 1) {
    int tv = (t >= ofs) ? base[t - ofs] : 0;
    __syncthreads();
    base[t] += tv;
    __syncthreads();
  }
  int excl = base[t] - hist[t];
  __syncthreads();
  base[t] = excl;
  hist[t] = 0;
  __syncthreads();
  for (int i = threadIdx.x; i < cnt; i += 256) {
    int d = dst[e0 + i], s = src[e0 + i];
    int bk = d >> 8;
    int pos = base[bk] + atomicAdd(&hist[bk], 1);
    lpack[pos] = (s << 8) | (d & 255);
    lbk[pos] = (unsigned char)bk;
  }
  __syncthreads();
  int c = hist[t];
  gbase[t] = c > 0 ? atomicAdd(&bcur[t], c) : 0;
  __syncthreads();
  for (int i = threadIdx.x; i < cnt; i += 256) {
    int bk = lbk[i];
    ebuck[gbase[bk] + (i - base[bk])] = lpack[i];
  }
}

// pass C: one block owns one bucket's CSR region -> exclusive fine scatter
__global__ void __launch_bounds__(512) csr_fine_k(const int* __restrict__ boff2,
                                                  const int* __restrict__ ebuck,
                                                  const float* __restrict__ dis,
                                                  int* __restrict__ cursor,
                                                  int2* __restrict__ epack) {
  int b = blockIdx.x;
  int beg = boff2[b], end = boff2[b + 1];
  int node0 = b << 8;
  for (int i = beg + threadIdx.x; i < end; i += 512) {
    int v = ebuck[i];
    int s = v >> 8, d = node0 + (v & 255);
    int p = atomicAdd(&cursor[d], 1);
    int2 w; w.x = s; w.y = __float_as_int(dis[s] * dis[d]);
    epack[p] = w;
  }
}

__global__ void pool_fill_k(const int* __restrict__ post_idx, const int* __restrict__ image_idx,
                            const int* __restrict__ batch, int* __restrict__ pcur,
                            int* __restrict__ icur, int* __restrict__ plist,
                            int* __restrict__ ilist, int NP, int NI) {
  int i = blockIdx.x * 256 + threadIdx.x;
  if (i < NP) {
    int nd = post_idx[i];
    int p = atomicAdd(&pcur[batch[nd]], 1);
    plist[p] = nd;
  } else if (i < NP + NI) {
    int nd = image_idx[i - NP];
    int p = atomicAdd(&icur[batch[nd]], 1);
    ilist[p] = nd;
  }
}

// xwb[r][c] = bf16( sum_k A[r][k] * W[k][c] ); A from f32 (layer0) or bf16 Hb.
template<bool BF16A>
__global__ void __launch_bounds__(256) gemm_mfma_k(const float* __restrict__ A,
                                                   const unsigned short* __restrict__ Ab,
                                                   const unsigned short* __restrict__ Wb,
                                                   unsigned short* __restrict__ xwb, int n) {
  const int w = threadIdx.x >> 6, l = threadIdx.x & 63;
  const int wr = w & 1, wc = w >> 1;
  const int r0 = blockIdx.x * 32 + wr * 16;
  const int row = r0 + (l & 15);
  const int kg = l >> 4;                 // 0..3
  short8v bf[4][4];
  const unsigned short* wp = Wb + (size_t)wc * 8192 + (size_t)l * 8;
#pragma unroll
  for (int ct = 0; ct < 4; ++ct)
#pragma unroll
    for (int ks = 0; ks < 4; ++ks)
      bf[ct][ks] = *(const short8v*)(wp + ((ct * 4 + ks) << 9));
  const bool rok = row < n;
  short8v af[4];
  if constexpr (BF16A) {
    const unsigned short* ap = Ab + (size_t)row * DF + kg * 8;
#pragma unroll
    for (int ks = 0; ks < 4; ++ks)
      af[ks] = rok ? *(const short8v*)(ap + ks * 32) : (short8v)0;
  } else {
    const float* ap = A + (size_t)row * DF + kg * 8;
#pragma unroll
    for (int ks = 0; ks < 4; ++ks) {
      if (rok) {
        float4 lo = *(const float4*)(ap + ks * 32);
        float4 hi = *(const float4*)(ap + ks * 32 + 4);
        short8v t;
        t[0] = (short)f2bf(lo.x); t[1] = (short)f2bf(lo.y);
        t[2] = (short)f2bf(lo.z); t[3] = (short)f2bf(lo.w);
        t[4] = (short)f2bf(hi.x); t[5] = (short)f2bf(hi.y);
        t[6] = (short)f2bf(hi.z); t[7] = (short)f2bf(hi.w);
        af[ks] = t;
      } else af[ks] = (short8v)0;
    }
  }
  f32x4 acc[4];
#pragma unroll
  for (int ct = 0; ct < 4; ++ct) acc[ct] = (f32x4)(0.f);
#pragma unroll
  for (int ks = 0; ks < 4; ++ks)
#pragma unroll
    for (int ct = 0; ct < 4; ++ct)
      acc[ct] = __builtin_amdgcn_mfma_f32_16x16x32_bf16(af[ks], bf[ct][ks], acc[ct], 0, 0, 0);
#pragma unroll
  for (int ct = 0; ct < 4; ++ct) {
    int c = wc * 64 + ct * 16 + (l & 15);
#pragma unroll
    for (int rg = 0; rg < 4; ++rg) {
      int r = r0 + kg * 4 + rg;
      if (r < n) xwb[(size_t)r * DF + c] = f2bf(acc[ct][rg]);
    }
  }
}

// CSR gather: 32 lanes/node = 2 teams x 16 lanes; teams split edges, shfl combine.
__global__ void gather_k(const unsigned short* __restrict__ xwb, const int* __restrict__ rowoff,
                         const int2* __restrict__ epack, const float* __restrict__ dis,
                         const float* __restrict__ b, unsigned short* __restrict__ Hb, int n) {
  int gid = blockIdx.x * 256 + threadIdx.x;
  int node = gid >> 5;
  if (node >= n) return;
  int part = gid & 15;
  int team = (gid >> 4) & 1;
  int beg = rowoff[node], end = rowoff[node + 1];
  float acc[8];
#pragma unroll
  for (int j = 0; j < 8; ++j) acc[j] = 0.f;
  int p = beg + team;
  for (; p + 6 < end; p += 8) {
    int2 q0 = epack[p], q1 = epack[p + 2], q2 = epack[p + 4], q3 = epack[p + 6];
    float e0 = __int_as_float(q0.y), e1 = __int_as_float(q1.y);
    float e2 = __int_as_float(q2.y), e3 = __int_as_float(q3.y);
    u16x8 v0 = *(const u16x8*)(xwb + (size_t)q0.x * DF + part * 8);
    u16x8 v1 = *(const u16x8*)(xwb + (size_t)q1.x * DF + part * 8);
    u16x8 v2 = *(const u16x8*)(xwb + (size_t)q2.x * DF + part * 8);
    u16x8 v3 = *(const u16x8*)(xwb + (size_t)q3.x * DF + part * 8);
#pragma unroll
    for (int j = 0; j < 8; ++j) {
      acc[j] = fmaf(bf2f(v0[j]), e0, acc[j]);
      acc[j] = fmaf(bf2f(v1[j]), e1, acc[j]);
      acc[j] = fmaf(bf2f(v2[j]), e2, acc[j]);
      acc[j] = fmaf(bf2f(v3[j]), e3, acc[j]);
    }
  }
  for (; p < end; p += 2) {
    int2 q = epack[p];
    float e = __int_as_float(q.y);
    u16x8 v = *(const u16x8*)(xwb + (size_t)q.x * DF + part * 8);
#pragma unroll
    for (int j = 0; j < 8; ++j) acc[j] = fmaf(bf2f(v[j]), e, acc[j]);
  }
  // combine the two teams (lane L += lane L+16 within the 32-lane group)
#pragma unroll
  for (int j = 0; j < 8; ++j) acc[j] += __shfl_down(acc[j], 16, 32);
  if (team == 0) {
    float dd = dis[node], sn = dd * dd;
    u16x8 xv = *(const u16x8*)(xwb + (size_t)node * DF + part * 8);
    const float* bp = b + part * 8;
    u16x8 o;
#pragma unroll
    for (int j = 0; j < 8; ++j) {
      float r = fmaf(bf2f(xv[j]), sn, acc[j]) + bp[j];
      r = LEAKY(r);
      o[j] = f2bf(r);
    }
    *(u16x8*)(Hb + (size_t)node * DF + part * 8) = o;
  }
}

// fused post pass: blocks [0,PGB) psum, [PGB,2*PGB) isum, [2*PGB,2*PGB+SB) bn_stats
__global__ void post_k(const unsigned short* __restrict__ Hb,
                       const int* __restrict__ goff_p, const int* __restrict__ mlist_p,
                       const int* __restrict__ goff_i, const int* __restrict__ mlist_i,
                       float* __restrict__ psum, float* __restrict__ isum,
                       float* __restrict__ bns, int n, int PGB, int SB) {
  int b = blockIdx.x;
  if (b < 2 * PGB) {
    int which = b >= PGB;
    int bb = which ? b - PGB : b;
    const int* goff  = which ? goff_i  : goff_p;
    const int* mlist = which ? mlist_i : mlist_p;
    float* out       = which ? isum    : psum;
    int g = bb / PSPLIT, sub = bb % PSPLIT;
    int part = threadIdx.x & 31, slot = threadIdx.x >> 5;
    int beg = goff[g], end = goff[g + 1];
    float4 acc = make_float4(0.f, 0.f, 0.f, 0.f);
    for (int j = beg + sub * 8 + slot; j < end; j += PSPLIT * 8) {
      u16x4 v = *(const u16x4*)(Hb + (size_t)mlist[j] * DF + part * 4);
      acc.x += bf2f(v[0]); acc.y += bf2f(v[1]); acc.z += bf2f(v[2]); acc.w += bf2f(v[3]);
    }
    __shared__ float4 sh[256];
    sh[threadIdx.x] = acc;
    __syncthreads();
    for (int ofs = 128; ofs >= 32; ofs >>= 1) {
      if (threadIdx.x < (unsigned)ofs) {
        float4 o = sh[threadIdx.x + ofs];
        float4 a = sh[threadIdx.x];
        a.x += o.x; a.y += o.y; a.z += o.z; a.w += o.w;
        sh[threadIdx.x] = a;
      }
      __syncthreads();
    }
    if (threadIdx.x < 32) {
      float4 a = sh[threadIdx.x];
      float* o = out + (size_t)g * DF + part * 4;
      atomicAdd(o + 0, a.x);
      atomicAdd(o + 1, a.y);
      atomicAdd(o + 2, a.z);
      atomicAdd(o + 3, a.w);
    }
  } else {
    int sb = b - 2 * PGB;
    int c = threadIdx.x & (DF - 1);
    int half = threadIdx.x >> 7;
    float s = 0.f, q = 0.f;
    for (int r = sb * 2 + half; r < n; r += SB * 2) {
      float v = bf2f(Hb[(size_t)r * DF + c]);
      s += v; q += v * v;
    }
    __shared__ float ls[256], lq[256];
    ls[threadIdx.x] = s; lq[threadIdx.x] = q;
    __syncthreads();
    if (half == 0) {
      atomicAdd(&bns[c], ls[c] + ls[c + DF]);
      atomicAdd(&bns[DF + c], lq[c] + lq[c + DF]);
    }
  }
}

// head layer 1 (folds bn_final): 512 threads, 4-way split-K
__global__ void __launch_bounds__(512) head1_k(const float* __restrict__ psum,
                        const int* __restrict__ pcnt,
                        const float* __restrict__ isum, const int* __restrict__ icnt,
                        const float* __restrict__ bns, const float* __restrict__ hbn_gamma,
                        const float* __restrict__ hbn_beta, int nN,
                        const float* __restrict__ gf_w1, const float* __restrict__ gf_b1,
                        const float* __restrict__ gf_w2, const float* __restrict__ gf_b2,
                        float* __restrict__ hbuf) {
  int g = blockIdx.x;
  int j = threadIdx.x & 127, kq = threadIdx.x >> 7;  // 4 K-quarters
  __shared__ float comb[4 * DF];
  __shared__ float part[512];
  __shared__ float t1[DF];
  if (kq == 0) {
    float m = bns[j] / (float)nN;
    float var = bns[DF + j] / (float)nN - m * m;
    if (var < 0.f) var = 0.f;
    float sc = hbn_gamma[j] / sqrtf(var + 1e-5f);
    float sh = hbn_beta[j] - m * sc;
    int pc = pcnt[g], ic = icnt[g];
    float pf = pc > 0 ? (psum[(size_t)g * DF + j] / (float)pc) * sc + sh : 0.f;
    float im = ic > 0 ? (isum[(size_t)g * DF + j] / (float)ic) * sc + sh : 0.f;
    comb[j] = pf;
    comb[DF + j] = im;
    comb[2 * DF + j] = pf - im;
    comb[3 * DF + j] = pf * im;
  }
  __syncthreads();
  float acc = 0.f;
  const float* w1 = gf_w1 + (size_t)kq * 128 * DF + j;
#pragma unroll 8
  for (int kk = 0; kk < 128; ++kk)
    acc = fmaf(comb[kq * 128 + kk], w1[(size_t)kk * DF], acc);
  part[threadIdx.x] = acc;
  __syncthreads();
  if (kq == 0)
    t1[j] = LEAKY(gf_b1[j] + part[j] + part[128 + j] + part[256 + j] + part[384 + j]);
  __syncthreads();
  acc = 0.f;
  const float* w2 = gf_w2 + (size_t)kq * 32 * DF + j;
#pragma unroll 8
  for (int kk = 0; kk < 32; ++kk)
    acc = fmaf(t1[kq * 32 + kk], w2[(size_t)kk * DF], acc);
  part[threadIdx.x] = acc;
  __syncthreads();
  if (kq == 0)
    hbuf[(size_t)g * DF + j] = gf_b2[j] + part[j] + part[128 + j] + part[256 + j] + part[384 + j];
}

// BN2 stats: one block, 1024 threads = 8 row-slots x 128 cols -> ss2 scale/shift
__global__ void __launch_bounds__(1024) bn2_k(const float* __restrict__ hbuf,
                      const float* __restrict__ gamma, const float* __restrict__ beta,
                      float* __restrict__ ss2, int G) {
  int c = threadIdx.x & 127, slot = threadIdx.x >> 7;  // 8 slots
  float s = 0.f, q = 0.f;
  for (int r = slot; r < G; r += 8) {
    float v = hbuf[(size_t)r * DF + c];
    s += v; q += v * v;
  }
  __shared__ float ls[1024], lq[1024];
  ls[threadIdx.x] = s; lq[threadIdx.x] = q;
  __syncthreads();
  for (int ofs = 512; ofs >= 128; ofs >>= 1) {
    if (threadIdx.x < (unsigned)ofs) {
      ls[threadIdx.x] += ls[threadIdx.x + ofs];
      lq[threadIdx.x] += lq[threadIdx.x + ofs];
    }
    __syncthreads();
  }
  if (threadIdx.x < 128) {
    float m = ls[c] / (float)G;
    float var = lq[c] / (float)G - m * m;
    if (var < 0.f) var = 0.f;
    float sc = gamma[c] / sqrtf(var + 1e-5f);
    ss2[c] = sc;
    ss2[DF + c] = beta[c] - m * sc;
  }
}

// head2: 512 threads, split-K at every stage. BN2-apply, 128->64, 64->32, 32->2.
__global__ void __launch_bounds__(512) head2_k(const float* __restrict__ hbuf,
                        const float* __restrict__ ss2,
                        const float* __restrict__ fl_w1, const float* __restrict__ fl_b1,
                        const float* __restrict__ fl_w2, const float* __restrict__ fl_b2,
                        const float* __restrict__ out_w, const float* __restrict__ out_b,
                        float* __restrict__ d_out, int G) {
  int g = blockIdx.x, t = threadIdx.x;
  __shared__ float hb[DF], part[512], t1[64], ov[32];
  if (t < DF) hb[t] = hbuf[(size_t)g * DF + t] * ss2[t] + ss2[DF + t];
  __syncthreads();
  {
    int j = t & 63, kq = t >> 6;
    float acc = 0.f;
    const float* w = fl_w1 + (size_t)kq * 16 * 64 + j;
#pragma unroll
    for (int kk = 0; kk < 16; ++kk)
      acc = fmaf(hb[kq * 16 + kk], w[(size_t)kk * 64], acc);
    part[t] = acc;
  }
  __syncthreads();
  if (t < 64) {
    float s = fl_b1[t];
#pragma unroll
    for (int i = 0; i < 8; ++i) s += part[i * 64 + t];
    t1[t] = LEAKY(s);
  }
  __syncthreads();
  {
    int j = t & 31, kq = t >> 5;
    float acc = 0.f;
    const float* w = fl_w2 + (size_t)kq * 4 * 32 + j;
#pragma unroll
    for (int kk = 0; kk < 4; ++kk)
      acc = fmaf(t1[kq * 4 + kk], w[(size_t)kk * 32], acc);
    part[t] = acc;
  }
  __syncthreads();
  if (t < 32) {
    float s = fl_b2[t];
#pragma unroll
    for (int i = 0; i < 16; ++i) s += part[i * 32 + t];
    d_out[(size_t)g * 32 + t] = s;
    ov[t] = s;
  }
  __syncthreads();
  if (t < 64) {
    int j = t & 1, kq = t >> 1;
    part[t] = ov[kq] * out_w[(size_t)kq * 2 + j];
  }
  __syncthreads();
  if (t < 2) {
    float s = out_b[t];
#pragma unroll
    for (int i = 0; i < 32; ++i) s += part[i * 2 + t];
    d_out[(size_t)G * 32 + (size_t)g * 2 + t] = s;
  }
}

extern "C" void kernel_launch(void* const* d_in, const int* in_sizes, int n_in,
                              void* d_out, int out_size, void* d_ws, size_t ws_size,
                              hipStream_t stream) {
  const float* x         = (const float*)d_in[0];
  const float* W_gnn     = (const float*)d_in[1];
  const float* b_gnn     = (const float*)d_in[2];
  const float* hbn_gamma = (const float*)d_in[3];
  const float* hbn_beta  = (const float*)d_in[4];
  const float* gf_w1     = (const float*)d_in[5];
  const float* gf_b1     = (const float*)d_in[6];
  const float* gf_w2     = (const float*)d_in[7];
  const float* gf_b2     = (const float*)d_in[8];
  const float* bn2_gamma = (const float*)d_in[9];
  const float* bn2_beta  = (const float*)d_in[10];
  const float* fl_w1     = (const float*)d_in[11];
  const float* fl_b1     = (const float*)d_in[12];
  const float* fl_w2     = (const float*)d_in[13];
  const float* fl_b2     = (const float*)d_in[14];
  const float* out_w     = (const float*)d_in[15];
  const float* out_b     = (const float*)d_in[16];
  const int* edge_index  = (const int*)d_in[17];
  const int* post_idx    = (const int*)d_in[18];
  const int* image_idx   = (const int*)d_in[19];
  const int* batch_vec   = (const int*)d_in[20];

  const int N  = in_sizes[20];
  const int E  = in_sizes[17] / 2;
  const int NP = in_sizes[18];
  const int NI = in_sizes[19];
  const int G  = out_size / 34;           // out: G*32 + prob: G*2
  const int L  = in_sizes[1] / (DF * DF);
  const int* src  = edge_index;
  const int* dstp = edge_index + E;
  const int NB = (N + 1023) / 1024;       // node scan blocks
  const int NBUCK = (N + 255) >> 8;       // 256-node buckets
  const int EB = 256;
  const int PB = (NP + NI + 255) / 256;
  const int WT = L * DF * DF;
  const int WB = (WT + 255) / 256;
  const int PGB = G * PSPLIT;
  const int SB = 256;                     // bn_stats blocks

  char* ws = (char*)d_ws;
  size_t off = 0;
  auto alloc = [&](size_t b) { size_t o = off; off += (b + 255) & ~(size_t)255; return o; };
  // ---- zero-initialized region (single memset) ----
  size_t zero_beg = off;
  int*   degc   = (int*)(ws + alloc((size_t)N * 4));
  int*   bhist  = (int*)(ws + alloc((size_t)NBK * 4));
  float* bns    = (float*)(ws + alloc(256 * 4));
  float* psum   = (float*)(ws + alloc((size_t)G * DF * 4));
  float* isum   = (float*)(ws + alloc((size_t)G * DF * 4));
  int*   pcnt   = (int*)(ws + alloc((size_t)G * 4));
  int*   icnt   = (int*)(ws + alloc((size_t)G * 4));
  size_t zero_bytes = off - zero_beg;
  // ---- rest ----
  float* dis    = (float*)(ws + alloc((size_t)N * 4));
  int*   rowoff = (int*)(ws + alloc((size_t)(N + 1) * 4));
  int*   cursor = (int*)(ws + alloc((size_t)N * 4));
  int2*  epack  = (int2*)(ws + alloc((size_t)E * 8));
  int*   ebuck  = (int*)(ws + alloc((size_t)E * 4));
  int*   boff2  = (int*)(ws + alloc((size_t)(NBK + 1) * 4));
  int*   bcur   = (int*)(ws + alloc((size_t)NBK * 4));
  int*   bsum   = (int*)(ws + alloc((size_t)(NB + 1) * 4));
  int*   boff   = (int*)(ws + alloc((size_t)(NB + 1) * 4));
  unsigned short* Wb  = (unsigned short*)(ws + alloc((size_t)WT * 2));
  unsigned short* xwb = (unsigned short*)(ws + alloc((size_t)N * DF * 2));
  unsigned short* Hb  = (unsigned short*)(ws + alloc((size_t)N * DF * 2));
  int*   poff   = (int*)(ws + alloc((size_t)(G + 1) * 4));
  int*   ioff   = (int*)(ws + alloc((size_t)(G + 1) * 4));
  int*   pcur   = (int*)(ws + alloc((size_t)G * 4));
  int*   icur   = (int*)(ws + alloc((size_t)G * 4));
  int*   plist  = (int*)(ws + alloc((size_t)NP * 4));
  int*   ilist  = (int*)(ws + alloc((size_t)NI * 4));
  float* hbuf   = (float*)(ws + alloc((size_t)G * DF * 4));
  float* ss2    = (float*)(ws + alloc(256 * 4));

  hipMemsetAsync(ws + zero_beg, 0, zero_bytes, stream);

  // fused: degree+bucket hist / pool counts / castW
  fused_pre_k<<<EB + PB + WB, 256, 0, stream>>>(dstp, degc, bhist, post_idx, image_idx,
                                                batch_vec, pcnt, icnt, W_gnn, Wb,
                                                E, NP, NI, WT, EB, PB);
  blk_sum_k<<<NB, 1024, 0, stream>>>(degc, bsum, N);
  scan4_k<<<4, 1024, 0, stream>>>(bsum, boff, NB, bhist, boff2, bcur, NBUCK,
                                  pcnt, poff, pcur, icnt, ioff, icur, G);
  blk_scan_dis_k<<<NB, 1024, 0, stream>>>(degc, boff, rowoff, cursor, dis, N);
  bucket_fill_k<<<(E + CHUNK - 1) / CHUNK, 256, 0, stream>>>(src, dstp, bcur, ebuck, E);
  csr_fine_k<<<NBUCK, 512, 0, stream>>>(boff2, ebuck, dis, cursor, epack);
  pool_fill_k<<<(NP + NI + 255) / 256, 256, 0, stream>>>(post_idx, image_idx, batch_vec,
                                                         pcur, icur, plist, ilist, NP, NI);

  // GNN layers (bf16 MFMA gemm + bf16 gather reads, f32 accumulate)
  for (int l = 0; l < L; ++l) {
    if (l == 0)
      gemm_mfma_k<false><<<(N + 31) / 32, 256, 0, stream>>>(x, nullptr,
          Wb + (size_t)l * DF * DF, xwb, N);
    else
      gemm_mfma_k<true><<<(N + 31) / 32, 256, 0, stream>>>(nullptr, Hb,
          Wb + (size_t)l * DF * DF, xwb, N);
    gather_k<<<(N * 32 + 255) / 256, 256, 0, stream>>>(xwb, rowoff, epack, dis,
                                                       b_gnn + (size_t)l * DF, Hb, N);
  }

  // fused post: pooled sums + BN stats
  post_k<<<2 * PGB + SB, 256, 0, stream>>>(Hb, poff, plist, ioff, ilist,
                                           psum, isum, bns, N, PGB, SB);

  // head
  head1_k<<<G, 512, 0, stream>>>(psum, pcnt, isum, icnt, bns, hbn_gamma, hbn_beta, N,
                                 gf_w1, gf_b1, gf_w2, gf_b2, hbuf);
  bn2_k<<<1, 1024, 0, stream>>>(hbuf, bn2_gamma, bn2_beta, ss2, G);
  head2_k<<<G, 512, 0, stream>>>(hbuf, ss2, fl_w1, fl_b1, fl_w2, fl_b2, out_w, out_b,
                                 (float*)d_out, G);
}

// Round 11
// 236.954 us; speedup vs baseline: 14.0503x; 1.1514x over previous
//
#include <hip/hip_runtime.h>
#include <hip/hip_bf16.h>
#include <math.h>

#define DF 128
#define PSPLIT 4
#define CHUNK 8192
#define NBK 256
#define LEAKY(x) ((x) > 0.f ? (x) : 0.01f * (x))

typedef __attribute__((ext_vector_type(8))) short short8v;   // 8 bf16 in 4 VGPRs
typedef __attribute__((ext_vector_type(4))) float f32x4;
typedef __attribute__((ext_vector_type(4))) unsigned short u16x4;
typedef __attribute__((ext_vector_type(8))) unsigned short u16x8;

static __device__ __forceinline__ unsigned short f2bf(float f) {
  unsigned u = __float_as_uint(f);
  unsigned r = u + 0x7fffu + ((u >> 16) & 1u);   // RNE
  return (unsigned short)(r >> 16);
}
static __device__ __forceinline__ float bf2f(unsigned short b) {
  return __uint_as_float(((unsigned)b) << 16);
}

// fused: [0,EB) bucket hist (LDS only); [EB,EB+PB) pool counts; [EB+PB,..) castW
__global__ void fused_pre_k(const int* __restrict__ dst, int* __restrict__ bhist,
                            const int* __restrict__ post_idx, const int* __restrict__ image_idx,
                            const int* __restrict__ batch, int* __restrict__ pcnt,
                            int* __restrict__ icnt,
                            const float* __restrict__ W, unsigned short* __restrict__ Wb,
                            int nE, int NP, int NI, int wTotal, int EB, int PB) {
  int b = blockIdx.x;
  if (b < EB) {
    __shared__ int lh[NBK];
    lh[threadIdx.x] = 0;
    __syncthreads();
    for (int i = b * 256 + threadIdx.x; i < nE; i += EB * 256)
      atomicAdd(&lh[dst[i] >> 8], 1);
    __syncthreads();
    if (lh[threadIdx.x]) atomicAdd(&bhist[threadIdx.x], lh[threadIdx.x]);
  } else if (b < EB + PB) {
    int i = (b - EB) * 256 + threadIdx.x;
    if (i < NP) atomicAdd(&pcnt[batch[post_idx[i]]], 1);
    else if (i < NP + NI) atomicAdd(&icnt[batch[image_idx[i - NP]]], 1);
  } else {
    int i = (b - EB - PB) * 256 + threadIdx.x;
    if (i < wTotal) {
      int layer = i >> 14, o = i & 16383;
      int j = o & 7, l = (o >> 3) & 63, ks = (o >> 9) & 3, ct = (o >> 11) & 3, wc = (o >> 13) & 1;
      int row = ks * 32 + (l >> 4) * 8 + j;
      int col = wc * 64 + ct * 16 + (l & 15);
      Wb[i] = f2bf(W[((size_t)layer << 14) + row * DF + col]);
    }
  }
}

// 3 independent small exclusive scans in one launch (block 0..2)
__global__ void __launch_bounds__(1024) scan3_k(
    const int* __restrict__ bhist, int* __restrict__ boff2, int* __restrict__ bcur, int NBUCK,
    const int* __restrict__ pcnt, int* __restrict__ poff, int* __restrict__ pcur,
    const int* __restrict__ icnt, int* __restrict__ ioff, int* __restrict__ icur, int G) {
  const int* in; int* out; int* cur; int n;
  if (blockIdx.x == 0)      { in = bhist; out = boff2; cur = bcur; n = NBUCK; }
  else if (blockIdx.x == 1) { in = pcnt;  out = poff;  cur = pcur; n = G; }
  else                      { in = icnt;  out = ioff;  cur = icur; n = G; }
  __shared__ int sh[1024];
  int v = (threadIdx.x < (unsigned)n) ? in[threadIdx.x] : 0;
  sh[threadIdx.x] = v;
  __syncthreads();
  for (int ofs = 1; ofs < 1024; ofs <<= 1) {
    int t = (threadIdx.x >= (unsigned)ofs) ? sh[threadIdx.x - ofs] : 0;
    __syncthreads();
    sh[threadIdx.x] += t;
    __syncthreads();
  }
  if (threadIdx.x < (unsigned)n) {
    int ex = sh[threadIdx.x] - v;
    out[threadIdx.x] = ex;
    cur[threadIdx.x] = ex;
  }
  if (threadIdx.x == 0) out[n] = sh[1023];
}

// pass B: LDS counting-sort of an 8192-edge chunk into dst-buckets, burst-write bucket-major
__global__ void __launch_bounds__(256) bucket_fill_k(const int* __restrict__ src,
                                                     const int* __restrict__ dst,
                                                     int* __restrict__ bcur,
                                                     int* __restrict__ ebuck, int nE) {
  __shared__ int hist[NBK];
  __shared__ int base[NBK];
  __shared__ int gbase[NBK];
  __shared__ int lpack[CHUNK];
  __shared__ unsigned char lbk[CHUNK];
  int e0 = blockIdx.x * CHUNK;
  int cnt = nE - e0; if (cnt > CHUNK) cnt = CHUNK;
  hist[threadIdx.x] = 0;
  __syncthreads();
  for (int i = threadIdx.x; i < cnt; i += 256)
    atomicAdd(&hist[dst[e0 + i] >> 8], 1);
  __syncthreads();
  int t = threadIdx.x;
  base[t] = hist[t];
  __syncthreads();
  for (int ofs = 1; ofs < NBK; ofs <<= 1) {
    int tv = (t >= ofs) ? base[t - ofs] : 0;
    __syncthreads();
    base[t] += tv;
    __syncthreads();
  }
  int excl = base[t] - hist[t];
  __syncthreads();
  base[t] = excl;
  hist[t] = 0;
  __syncthreads();
  for (int i = threadIdx.x; i < cnt; i += 256) {
    int d = dst[e0 + i], s = src[e0 + i];
    int bk = d >> 8;
    int pos = base[bk] + atomicAdd(&hist[bk], 1);
    lpack[pos] = (s << 8) | (d & 255);
    lbk[pos] = (unsigned char)bk;
  }
  __syncthreads();
  int c = hist[t];
  gbase[t] = c > 0 ? atomicAdd(&bcur[t], c) : 0;
  __syncthreads();
  for (int i = threadIdx.x; i < cnt; i += 256) {
    int bk = lbk[i];
    ebuck[gbase[bk] + (i - base[bk])] = lpack[i];
  }
}

// pass C: per bucket: local hist -> rowoff + dis + fine-sorted epack={src,dst}, LDS-only atomics
__global__ void __launch_bounds__(256) csr_build_k(const int* __restrict__ boff2,
                                                   const int* __restrict__ ebuck,
                                                   int* __restrict__ rowoff,
                                                   float* __restrict__ dis,
                                                   int2* __restrict__ epack,
                                                   int N, int NBUCK) {
  int b = blockIdx.x;
  int beg = boff2[b], end = boff2[b + 1];
  int node0 = b << 8;
  __shared__ int hist[NBK];
  __shared__ int lbase[NBK];
  int t = threadIdx.x;
  hist[t] = 0;
  __syncthreads();
  for (int i = beg + t; i < end; i += 256)
    atomicAdd(&hist[ebuck[i] & 255], 1);
  __syncthreads();
  int v = hist[t];
  lbase[t] = v;
  __syncthreads();
  for (int ofs = 1; ofs < NBK; ofs <<= 1) {
    int tv = (t >= ofs) ? lbase[t - ofs] : 0;
    __syncthreads();
    lbase[t] += tv;
    __syncthreads();
  }
  int excl = lbase[t] - v;
  __syncthreads();
  lbase[t] = excl;
  hist[t] = 0;  // reuse as local cursor
  int node = node0 + t;
  if (node < N) {
    rowoff[node] = beg + excl;
    dis[node] = 1.0f / sqrtf((float)v + 1.0f);
  }
  if (b == NBUCK - 1 && t == 0) rowoff[N] = end;
  __syncthreads();
  for (int i = beg + t; i < end; i += 256) {
    int e = ebuck[i];
    int loc = e & 255;
    int pos = beg + lbase[loc] + atomicAdd(&hist[loc], 1);
    int2 w; w.x = e >> 8; w.y = node0 + loc;
    epack[pos] = w;
  }
}

// pass D: epack.y: dst -> enorm (coalesced rewrite; dis is L2-hot)
__global__ void enorm_k(int2* __restrict__ epack, const float* __restrict__ dis, int E) {
  int i = blockIdx.x * 256 + threadIdx.x;
  if (i < E) {
    int2 w = epack[i];
    epack[i].y = __float_as_int(dis[w.x] * dis[w.y]);
  }
}

__global__ void pool_fill_k(const int* __restrict__ post_idx, const int* __restrict__ image_idx,
                            const int* __restrict__ batch, int* __restrict__ pcur,
                            int* __restrict__ icur, int* __restrict__ plist,
                            int* __restrict__ ilist, int NP, int NI) {
  int i = blockIdx.x * 256 + threadIdx.x;
  if (i < NP) {
    int nd = post_idx[i];
    int p = atomicAdd(&pcur[batch[nd]], 1);
    plist[p] = nd;
  } else if (i < NP + NI) {
    int nd = image_idx[i - NP];
    int p = atomicAdd(&icur[batch[nd]], 1);
    ilist[p] = nd;
  }
}

// xwb[r][c] = bf16( sum_k A[r][k] * W[k][c] ); A from f32 (layer0) or bf16 Hb.
template<bool BF16A>
__global__ void __launch_bounds__(256) gemm_mfma_k(const float* __restrict__ A,
                                                   const unsigned short* __restrict__ Ab,
                                                   const unsigned short* __restrict__ Wb,
                                                   unsigned short* __restrict__ xwb, int n) {
  const int w = threadIdx.x >> 6, l = threadIdx.x & 63;
  const int wr = w & 1, wc = w >> 1;
  const int r0 = blockIdx.x * 32 + wr * 16;
  const int row = r0 + (l & 15);
  const int kg = l >> 4;                 // 0..3
  short8v bf[4][4];
  const unsigned short* wp = Wb + (size_t)wc * 8192 + (size_t)l * 8;
#pragma unroll
  for (int ct = 0; ct < 4; ++ct)
#pragma unroll
    for (int ks = 0; ks < 4; ++ks)
      bf[ct][ks] = *(const short8v*)(wp + ((ct * 4 + ks) << 9));
  const bool rok = row < n;
  short8v af[4];
  if constexpr (BF16A) {
    const unsigned short* ap = Ab + (size_t)row * DF + kg * 8;
#pragma unroll
    for (int ks = 0; ks < 4; ++ks)
      af[ks] = rok ? *(const short8v*)(ap + ks * 32) : (short8v)0;
  } else {
    const float* ap = A + (size_t)row * DF + kg * 8;
#pragma unroll
    for (int ks = 0; ks < 4; ++ks) {
      if (rok) {
        float4 lo = *(const float4*)(ap + ks * 32);
        float4 hi = *(const float4*)(ap + ks * 32 + 4);
        short8v t;
        t[0] = (short)f2bf(lo.x); t[1] = (short)f2bf(lo.y);
        t[2] = (short)f2bf(lo.z); t[3] = (short)f2bf(lo.w);
        t[4] = (short)f2bf(hi.x); t[5] = (short)f2bf(hi.y);
        t[6] = (short)f2bf(hi.z); t[7] = (short)f2bf(hi.w);
        af[ks] = t;
      } else af[ks] = (short8v)0;
    }
  }
  f32x4 acc[4];
#pragma unroll
  for (int ct = 0; ct < 4; ++ct) acc[ct] = (f32x4)(0.f);
#pragma unroll
  for (int ks = 0; ks < 4; ++ks)
#pragma unroll
    for (int ct = 0; ct < 4; ++ct)
      acc[ct] = __builtin_amdgcn_mfma_f32_16x16x32_bf16(af[ks], bf[ct][ks], acc[ct], 0, 0, 0);
#pragma unroll
  for (int ct = 0; ct < 4; ++ct) {
    int c = wc * 64 + ct * 16 + (l & 15);
#pragma unroll
    for (int rg = 0; rg < 4; ++rg) {
      int r = r0 + kg * 4 + rg;
      if (r < n) xwb[(size_t)r * DF + c] = f2bf(acc[ct][rg]);
    }
  }
}

// CSR gather: 32 lanes/node = 2 teams x 16 lanes; teams split edges, shfl combine.
__global__ void gather_k(const unsigned short* __restrict__ xwb, const int* __restrict__ rowoff,
                         const int2* __restrict__ epack, const float* __restrict__ dis,
                         const float* __restrict__ b, unsigned short* __restrict__ Hb, int n) {
  int gid = blockIdx.x * 256 + threadIdx.x;
  int node = gid >> 5;
  if (node >= n) return;
  int part = gid & 15;
  int team = (gid >> 4) & 1;
  int beg = rowoff[node], end = rowoff[node + 1];
  float acc[8];
#pragma unroll
  for (int j = 0; j < 8; ++j) acc[j] = 0.f;
  int p = beg + team;
  for (; p + 6 < end; p += 8) {
    int2 q0 = epack[p], q1 = epack[p + 2], q2 = epack[p + 4], q3 = epack[p + 6];
    float e0 = __int_as_float(q0.y), e1 = __int_as_float(q1.y);
    float e2 = __int_as_float(q2.y), e3 = __int_as_float(q3.y);
    u16x8 v0 = *(const u16x8*)(xwb + (size_t)q0.x * DF + part * 8);
    u16x8 v1 = *(const u16x8*)(xwb + (size_t)q1.x * DF + part * 8);
    u16x8 v2 = *(const u16x8*)(xwb + (size_t)q2.x * DF + part * 8);
    u16x8 v3 = *(const u16x8*)(xwb + (size_t)q3.x * DF + part * 8);
#pragma unroll
    for (int j = 0; j < 8; ++j) {
      acc[j] = fmaf(bf2f(v0[j]), e0, acc[j]);
      acc[j] = fmaf(bf2f(v1[j]), e1, acc[j]);
      acc[j] = fmaf(bf2f(v2[j]), e2, acc[j]);
      acc[j] = fmaf(bf2f(v3[j]), e3, acc[j]);
    }
  }
  for (; p < end; p += 2) {
    int2 q = epack[p];
    float e = __int_as_float(q.y);
    u16x8 v = *(const u16x8*)(xwb + (size_t)q.x * DF + part * 8);
#pragma unroll
    for (int j = 0; j < 8; ++j) acc[j] = fmaf(bf2f(v[j]), e, acc[j]);
  }
#pragma unroll
  for (int j = 0; j < 8; ++j) acc[j] += __shfl_down(acc[j], 16, 32);
  if (team == 0) {
    float dd = dis[node], sn = dd * dd;
    u16x8 xv = *(const u16x8*)(xwb + (size_t)node * DF + part * 8);
    const float* bp = b + part * 8;
    u16x8 o;
#pragma unroll
    for (int j = 0; j < 8; ++j) {
      float r = fmaf(bf2f(xv[j]), sn, acc[j]) + bp[j];
      r = LEAKY(r);
      o[j] = f2bf(r);
    }
    *(u16x8*)(Hb + (size_t)node * DF + part * 8) = o;
  }
}

// fused post pass: blocks [0,PGB) psum, [PGB,2*PGB) isum, [2*PGB,2*PGB+SB) bn_stats
__global__ void post_k(const unsigned short* __restrict__ Hb,
                       const int* __restrict__ goff_p, const int* __restrict__ mlist_p,
                       const int* __restrict__ goff_i, const int* __restrict__ mlist_i,
                       float* __restrict__ psum, float* __restrict__ isum,
                       float* __restrict__ bns, int n, int PGB, int SB) {
  int b = blockIdx.x;
  if (b < 2 * PGB) {
    int which = b >= PGB;
    int bb = which ? b - PGB : b;
    const int* goff  = which ? goff_i  : goff_p;
    const int* mlist = which ? mlist_i : mlist_p;
    float* out       = which ? isum    : psum;
    int g = bb / PSPLIT, sub = bb % PSPLIT;
    int part = threadIdx.x & 31, slot = threadIdx.x >> 5;
    int beg = goff[g], end = goff[g + 1];
    float4 acc = make_float4(0.f, 0.f, 0.f, 0.f);
    for (int j = beg + sub * 8 + slot; j < end; j += PSPLIT * 8) {
      u16x4 v = *(const u16x4*)(Hb + (size_t)mlist[j] * DF + part * 4);
      acc.x += bf2f(v[0]); acc.y += bf2f(v[1]); acc.z += bf2f(v[2]); acc.w += bf2f(v[3]);
    }
    __shared__ float4 sh[256];
    sh[threadIdx.x] = acc;
    __syncthreads();
    for (int ofs = 128; ofs >= 32; ofs >>= 1) {
      if (threadIdx.x < (unsigned)ofs) {
        float4 o = sh[threadIdx.x + ofs];
        float4 a = sh[threadIdx.x];
        a.x += o.x; a.y += o.y; a.z += o.z; a.w += o.w;
        sh[threadIdx.x] = a;
      }
      __syncthreads();
    }
    if (threadIdx.x < 32) {
      float4 a = sh[threadIdx.x];
      float* o = out + (size_t)g * DF + part * 4;
      atomicAdd(o + 0, a.x);
      atomicAdd(o + 1, a.y);
      atomicAdd(o + 2, a.z);
      atomicAdd(o + 3, a.w);
    }
  } else {
    int sb = b - 2 * PGB;
    int c = threadIdx.x & (DF - 1);
    int half = threadIdx.x >> 7;
    float s = 0.f, q = 0.f;
    for (int r = sb * 2 + half; r < n; r += SB * 2) {
      float v = bf2f(Hb[(size_t)r * DF + c]);
      s += v; q += v * v;
    }
    __shared__ float ls[256], lq[256];
    ls[threadIdx.x] = s; lq[threadIdx.x] = q;
    __syncthreads();
    if (half == 0) {
      atomicAdd(&bns[c], ls[c] + ls[c + DF]);
      atomicAdd(&bns[DF + c], lq[c] + lq[c + DF]);
    }
  }
}

// head layer 1 (folds bn_final): 512 threads, 4-way split-K
__global__ void __launch_bounds__(512) head1_k(const float* __restrict__ psum,
                        const int* __restrict__ pcnt,
                        const float* __restrict__ isum, const int* __restrict__ icnt,
                        const float* __restrict__ bns, const float* __restrict__ hbn_gamma,
                        const float* __restrict__ hbn_beta, int nN,
                        const float* __restrict__ gf_w1, const float* __restrict__ gf_b1,
                        const float* __restrict__ gf_w2, const float* __restrict__ gf_b2,
                        float* __restrict__ hbuf) {
  int g = blockIdx.x;
  int j = threadIdx.x & 127, kq = threadIdx.x >> 7;  // 4 K-quarters
  __shared__ float comb[4 * DF];
  __shared__ float part[512];
  __shared__ float t1[DF];
  if (kq == 0) {
    float m = bns[j] / (float)nN;
    float var = bns[DF + j] / (float)nN - m * m;
    if (var < 0.f) var = 0.f;
    float sc = hbn_gamma[j] / sqrtf(var + 1e-5f);
    float sh = hbn_beta[j] - m * sc;
    int pc = pcnt[g], ic = icnt[g];
    float pf = pc > 0 ? (psum[(size_t)g * DF + j] / (float)pc) * sc + sh : 0.f;
    float im = ic > 0 ? (isum[(size_t)g * DF + j] / (float)ic) * sc + sh : 0.f;
    comb[j] = pf;
    comb[DF + j] = im;
    comb[2 * DF + j] = pf - im;
    comb[3 * DF + j] = pf * im;
  }
  __syncthreads();
  float acc = 0.f;
  const float* w1 = gf_w1 + (size_t)kq * 128 * DF + j;
#pragma unroll 8
  for (int kk = 0; kk < 128; ++kk)
    acc = fmaf(comb[kq * 128 + kk], w1[(size_t)kk * DF], acc);
  part[threadIdx.x] = acc;
  __syncthreads();
  if (kq == 0)
    t1[j] = LEAKY(gf_b1[j] + part[j] + part[128 + j] + part[256 + j] + part[384 + j]);
  __syncthreads();
  acc = 0.f;
  const float* w2 = gf_w2 + (size_t)kq * 32 * DF + j;
#pragma unroll 8
  for (int kk = 0; kk < 32; ++kk)
    acc = fmaf(t1[kq * 32 + kk], w2[(size_t)kk * DF], acc);
  part[threadIdx.x] = acc;
  __syncthreads();
  if (kq == 0)
    hbuf[(size_t)g * DF + j] = gf_b2[j] + part[j] + part[128 + j] + part[256 + j] + part[384 + j];
}

// BN2 stats: one block, 1024 threads = 8 row-slots x 128 cols -> ss2 scale/shift
__global__ void __launch_bounds__(1024) bn2_k(const float* __restrict__ hbuf,
                      const float* __restrict__ gamma, const float* __restrict__ beta,
                      float* __restrict__ ss2, int G) {
  int c = threadIdx.x & 127, slot = threadIdx.x >> 7;  // 8 slots
  float s = 0.f, q = 0.f;
  for (int r = slot; r < G; r += 8) {
    float v = hbuf[(size_t)r * DF + c];
    s += v; q += v * v;
  }
  __shared__ float ls[1024], lq[1024];
  ls[threadIdx.x] = s; lq[threadIdx.x] = q;
  __syncthreads();
  for (int ofs = 512; ofs >= 128; ofs >>= 1) {
    if (threadIdx.x < (unsigned)ofs) {
      ls[threadIdx.x] += ls[threadIdx.x + ofs];
      lq[threadIdx.x] += lq[threadIdx.x + ofs];
    }
    __syncthreads();
  }
  if (threadIdx.x < 128) {
    float m = ls[c] / (float)G;
    float var = lq[c] / (float)G - m * m;
    if (var < 0.f) var = 0.f;
    float sc = gamma[c] / sqrtf(var + 1e-5f);
    ss2[c] = sc;
    ss2[DF + c] = beta[c] - m * sc;
  }
}

// head2: 512 threads, split-K at every stage. BN2-apply, 128->64, 64->32, 32->2.
__global__ void __launch_bounds__(512) head2_k(const float* __restrict__ hbuf,
                        const float* __restrict__ ss2,
                        const float* __restrict__ fl_w1, const float* __restrict__ fl_b1,
                        const float* __restrict__ fl_w2, const float* __restrict__ fl_b2,
                        const float* __restrict__ out_w, const float* __restrict__ out_b,
                        float* __restrict__ d_out, int G) {
  int g = blockIdx.x, t = threadIdx.x;
  __shared__ float hb[DF], part[512], t1[64], ov[32];
  if (t < DF) hb[t] = hbuf[(size_t)g * DF + t] * ss2[t] + ss2[DF + t];
  __syncthreads();
  {
    int j = t & 63, kq = t >> 6;
    float acc = 0.f;
    const float* w = fl_w1 + (size_t)kq * 16 * 64 + j;
#pragma unroll
    for (int kk = 0; kk < 16; ++kk)
      acc = fmaf(hb[kq * 16 + kk], w[(size_t)kk * 64], acc);
    part[t] = acc;
  }
  __syncthreads();
  if (t < 64) {
    float s = fl_b1[t];
#pragma unroll
    for (int i = 0; i < 8; ++i) s += part[i * 64 + t];
    t1[t] = LEAKY(s);
  }
  __syncthreads();
  {
    int j = t & 31, kq = t >> 5;
    float acc = 0.f;
    const float* w = fl_w2 + (size_t)kq * 4 * 32 + j;
#pragma unroll
    for (int kk = 0; kk < 4; ++kk)
      acc = fmaf(t1[kq * 4 + kk], w[(size_t)kk * 32], acc);
    part[t] = acc;
  }
  __syncthreads();
  if (t < 32) {
    float s = fl_b2[t];
#pragma unroll
    for (int i = 0; i < 16; ++i) s += part[i * 32 + t];
    d_out[(size_t)g * 32 + t] = s;
    ov[t] = s;
  }
  __syncthreads();
  if (t < 64) {
    int j = t & 1, kq = t >> 1;
    part[t] = ov[kq] * out_w[(size_t)kq * 2 + j];
  }
  __syncthreads();
  if (t < 2) {
    float s = out_b[t];
#pragma unroll
    for (int i = 0; i < 32; ++i) s += part[i * 2 + t];
    d_out[(size_t)G * 32 + (size_t)g * 2 + t] = s;
  }
}

extern "C" void kernel_launch(void* const* d_in, const int* in_sizes, int n_in,
                              void* d_out, int out_size, void* d_ws, size_t ws_size,
                              hipStream_t stream) {
  const float* x         = (const float*)d_in[0];
  const float* W_gnn     = (const float*)d_in[1];
  const float* b_gnn     = (const float*)d_in[2];
  const float* hbn_gamma = (const float*)d_in[3];
  const float* hbn_beta  = (const float*)d_in[4];
  const float* gf_w1     = (const float*)d_in[5];
  const float* gf_b1     = (const float*)d_in[6];
  const float* gf_w2     = (const float*)d_in[7];
  const float* gf_b2     = (const float*)d_in[8];
  const float* bn2_gamma = (const float*)d_in[9];
  const float* bn2_beta  = (const float*)d_in[10];
  const float* fl_w1     = (const float*)d_in[11];
  const float* fl_b1     = (const float*)d_in[12];
  const float* fl_w2     = (const float*)d_in[13];
  const float* fl_b2     = (const float*)d_in[14];
  const float* out_w     = (const float*)d_in[15];
  const float* out_b     = (const float*)d_in[16];
  const int* edge_index  = (const int*)d_in[17];
  const int* post_idx    = (const int*)d_in[18];
  const int* image_idx   = (const int*)d_in[19];
  const int* batch_vec   = (const int*)d_in[20];

  const int N  = in_sizes[20];
  const int E  = in_sizes[17] / 2;
  const int NP = in_sizes[18];
  const int NI = in_sizes[19];
  const int G  = out_size / 34;           // out: G*32 + prob: G*2
  const int L  = in_sizes[1] / (DF * DF);
  const int* src  = edge_index;
  const int* dstp = edge_index + E;
  const int NBUCK = (N + 255) >> 8;       // 256-node buckets
  const int EB = 256;
  const int PB = (NP + NI + 255) / 256;
  const int WT = L * DF * DF;
  const int WB = (WT + 255) / 256;
  const int PGB = G * PSPLIT;
  const int SB = 256;                     // bn_stats blocks

  char* ws = (char*)d_ws;
  size_t off = 0;
  auto alloc = [&](size_t b) { size_t o = off; off += (b + 255) & ~(size_t)255; return o; };
  // ---- zero-initialized region (single memset) ----
  size_t zero_beg = off;
  int*   bhist  = (int*)(ws + alloc((size_t)NBK * 4));
  float* bns    = (float*)(ws + alloc(256 * 4));
  float* psum   = (float*)(ws + alloc((size_t)G * DF * 4));
  float* isum   = (float*)(ws + alloc((size_t)G * DF * 4));
  int*   pcnt   = (int*)(ws + alloc((size_t)G * 4));
  int*   icnt   = (int*)(ws + alloc((size_t)G * 4));
  size_t zero_bytes = off - zero_beg;
  // ---- rest ----
  float* dis    = (float*)(ws + alloc((size_t)N * 4));
  int*   rowoff = (int*)(ws + alloc((size_t)(N + 1) * 4));
  int2*  epack  = (int2*)(ws + alloc((size_t)E * 8));
  int*   ebuck  = (int*)(ws + alloc((size_t)E * 4));
  int*   boff2  = (int*)(ws + alloc((size_t)(NBK + 1) * 4));
  int*   bcur   = (int*)(ws + alloc((size_t)NBK * 4));
  unsigned short* Wb  = (unsigned short*)(ws + alloc((size_t)WT * 2));
  unsigned short* xwb = (unsigned short*)(ws + alloc((size_t)N * DF * 2));
  unsigned short* Hb  = (unsigned short*)(ws + alloc((size_t)N * DF * 2));
  int*   poff   = (int*)(ws + alloc((size_t)(G + 1) * 4));
  int*   ioff   = (int*)(ws + alloc((size_t)(G + 1) * 4));
  int*   pcur   = (int*)(ws + alloc((size_t)G * 4));
  int*   icur   = (int*)(ws + alloc((size_t)G * 4));
  int*   plist  = (int*)(ws + alloc((size_t)NP * 4));
  int*   ilist  = (int*)(ws + alloc((size_t)NI * 4));
  float* hbuf   = (float*)(ws + alloc((size_t)G * DF * 4));
  float* ss2    = (float*)(ws + alloc(256 * 4));

  hipMemsetAsync(ws + zero_beg, 0, zero_bytes, stream);

  // fused: bucket hist (LDS-only) / pool counts / castW
  fused_pre_k<<<EB + PB + WB, 256, 0, stream>>>(dstp, bhist, post_idx, image_idx,
                                                batch_vec, pcnt, icnt, W_gnn, Wb,
                                                E, NP, NI, WT, EB, PB);
  scan3_k<<<3, 1024, 0, stream>>>(bhist, boff2, bcur, NBUCK,
                                  pcnt, poff, pcur, icnt, ioff, icur, G);
  bucket_fill_k<<<(E + CHUNK - 1) / CHUNK, 256, 0, stream>>>(src, dstp, bcur, ebuck, E);
  csr_build_k<<<NBUCK, 256, 0, stream>>>(boff2, ebuck, rowoff, dis, epack, N, NBUCK);
  enorm_k<<<(E + 255) / 256, 256, 0, stream>>>(epack, dis, E);
  pool_fill_k<<<(NP + NI + 255) / 256, 256, 0, stream>>>(post_idx, image_idx, batch_vec,
                                                         pcur, icur, plist, ilist, NP, NI);

  // GNN layers (bf16 MFMA gemm + bf16 gather reads, f32 accumulate)
  for (int l = 0; l < L; ++l) {
    if (l == 0)
      gemm_mfma_k<false><<<(N + 31) / 32, 256, 0, stream>>>(x, nullptr,
          Wb + (size_t)l * DF * DF, xwb, N);
    else
      gemm_mfma_k<true><<<(N + 31) / 32, 256, 0, stream>>>(nullptr, Hb,
          Wb + (size_t)l * DF * DF, xwb, N);
    gather_k<<<(N * 32 + 255) / 256, 256, 0, stream>>>(xwb, rowoff, epack, dis,
                                                       b_gnn + (size_t)l * DF, Hb, N);
  }

  // fused post: pooled sums + BN stats
  post_k<<<2 * PGB + SB, 256, 0, stream>>>(Hb, poff, plist, ioff, ilist,
                                           psum, isum, bns, N, PGB, SB);

  // head
  head1_k<<<G, 512, 0, stream>>>(psum, pcnt, isum, icnt, bns, hbn_gamma, hbn_beta, N,
                                 gf_w1, gf_b1, gf_w2, gf_b2, hbuf);
  bn2_k<<<1, 1024, 0, stream>>>(hbuf, bn2_gamma, bn2_beta, ss2, G);
  head2_k<<<G, 512, 0, stream>>>(hbuf, ss2, fl_w1, fl_b1, fl_w2, fl_b2, out_w, out_b,
                                 (float*)d_out, G);
}